// Round 2
// baseline (1378.136 us; speedup 1.0000x reference)
//
#include <hip/hip_runtime.h>
#include <hip/hip_fp16.h>

constexpr int Nn = 100000;
constexpr int Ne = 1600000;
constexpr float BN_EPS = 1e-5f;

constexpr int SCAN_TILE = 1024;                          // elements per block
constexpr int SCAN_NB = (Nn + SCAN_TILE - 1) / SCAN_TILE; // 98

constexpr float FIX_SCALE = 16777216.f;       // 2^24
constexpr float FIX_INV = 1.f / 16777216.f;

// ---------- small utility kernels ----------

__global__ void fill_kernel(float* __restrict__ p, float v, int n) {
  int i = blockIdx.x * blockDim.x + threadIdx.x;
  if (i < n) p[i] = v;
}

__global__ void izero_kernel(int* __restrict__ p, int n) {
  int i = blockIdx.x * blockDim.x + threadIdx.x;
  if (i < n) p[i] = 0;
}

// fused: one u64 atomic per edge packs {cnt:1 << 40 | fix24(w)}
__global__ __launch_bounds__(256)
void deg_pack_kernel(const int* __restrict__ row, const float* __restrict__ w,
                     unsigned long long* __restrict__ pk) {
  int e = (blockIdx.x * blockDim.x + threadIdx.x) * 4;
  if (e + 4 <= Ne) {
    int4 r4 = *(const int4*)(row + e);
    float4 w4 = *(const float4*)(w + e);
    atomicAdd(&pk[r4.x], (1ULL << 40) | (unsigned long long)__float2uint_rn(w4.x * FIX_SCALE));
    atomicAdd(&pk[r4.y], (1ULL << 40) | (unsigned long long)__float2uint_rn(w4.y * FIX_SCALE));
    atomicAdd(&pk[r4.z], (1ULL << 40) | (unsigned long long)__float2uint_rn(w4.z * FIX_SCALE));
    atomicAdd(&pk[r4.w], (1ULL << 40) | (unsigned long long)__float2uint_rn(w4.w * FIX_SCALE));
  } else {
    for (int i = e; i < Ne; i++) {
      atomicAdd(&pk[row[i]], (1ULL << 40) | (unsigned long long)__float2uint_rn(w[i] * FIX_SCALE));
    }
  }
}

// unpack: cnt = pk>>40 ; deg = fix*2^-24 + 1 (self loop) ; dinv = rsqrt(deg)
__global__ void dinv_cnt_kernel(const unsigned long long* __restrict__ pk,
                                float* __restrict__ dinv, int* __restrict__ cnt) {
  int i = blockIdx.x * blockDim.x + threadIdx.x;
  if (i < Nn) {
    unsigned long long v = pk[i];
    cnt[i] = (int)(v >> 40);
    float deg = (float)(v & ((1ULL << 40) - 1)) * FIX_INV + 1.0f;  // + self-loop weight
    dinv[i] = (deg > 0.f) ? rsqrtf(fmaxf(deg, 1e-12f)) : 0.f;
  }
}

// ---------- multi-block exclusive scan (cnt[Nn] -> rowptr[Nn+1], off) ----------

__global__ __launch_bounds__(256)
void scan_phase1(const int* __restrict__ cnt, int* __restrict__ bsum) {
  __shared__ int s[256];
  int b = blockIdx.x, tid = threadIdx.x;
  int base = b * SCAN_TILE + tid * 4;
  int t = 0;
#pragma unroll
  for (int i = 0; i < 4; i++) {
    int idx = base + i;
    if (idx < Nn) t += cnt[idx];
  }
  s[tid] = t;
  __syncthreads();
  for (int st = 128; st > 0; st >>= 1) {
    if (tid < st) s[tid] += s[tid + st];
    __syncthreads();
  }
  if (tid == 0) bsum[b] = s[0];
}

__global__ __launch_bounds__(128)
void scan_phase2(int* __restrict__ bsum) {  // in-place exclusive scan, SCAN_NB <= 128
  __shared__ int s[128];
  int tid = threadIdx.x;
  int v = (tid < SCAN_NB) ? bsum[tid] : 0;
  s[tid] = v;
  __syncthreads();
  for (int st = 1; st < 128; st <<= 1) {
    int u = (tid >= st) ? s[tid - st] : 0;
    __syncthreads();
    s[tid] += u;
    __syncthreads();
  }
  if (tid < SCAN_NB) bsum[tid] = s[tid] - v;  // exclusive prefix
}

__global__ __launch_bounds__(256)
void scan_phase3(const int* __restrict__ cnt, const int* __restrict__ bsum,
                 int* __restrict__ rowptr, int* __restrict__ off) {
  __shared__ int s[256];
  int b = blockIdx.x, tid = threadIdx.x;
  int base = b * SCAN_TILE + tid * 4;
  int vals[4];
  int t = 0;
#pragma unroll
  for (int i = 0; i < 4; i++) {
    int idx = base + i;
    vals[i] = (idx < Nn) ? cnt[idx] : 0;
    t += vals[i];
  }
  s[tid] = t;
  __syncthreads();
  for (int st = 1; st < 256; st <<= 1) {
    int u = (tid >= st) ? s[tid - st] : 0;
    __syncthreads();
    s[tid] += u;
    __syncthreads();
  }
  int run = bsum[b] + s[tid] - t;  // exclusive prefix for this thread's 4 elems
#pragma unroll
  for (int i = 0; i < 4; i++) {
    int idx = base + i;
    if (idx < Nn) { rowptr[idx] = run; off[idx] = run; run += vals[i]; }
  }
  if (b == SCAN_NB - 1 && tid == 255) rowptr[Nn] = bsum[b] + s[255];
}

// CSR fill: interleaved {col, norm} -> single 8B scattered store per edge
__global__ __launch_bounds__(256)
void csr_fill_kernel(const int* __restrict__ row, const int* __restrict__ col,
                     const float* __restrict__ w, const float* __restrict__ dinv,
                     int* __restrict__ off, int2* __restrict__ edge_s) {
  int e = (blockIdx.x * blockDim.x + threadIdx.x) * 4;
  if (e + 4 <= Ne) {
    int4 r4 = *(const int4*)(row + e);
    int4 c4 = *(const int4*)(col + e);
    float4 w4 = *(const float4*)(w + e);
    {
      int p = atomicAdd(&off[r4.x], 1);
      edge_s[p] = make_int2(c4.x, __float_as_int(dinv[r4.x] * w4.x * dinv[c4.x]));
    }
    {
      int p = atomicAdd(&off[r4.y], 1);
      edge_s[p] = make_int2(c4.y, __float_as_int(dinv[r4.y] * w4.y * dinv[c4.y]));
    }
    {
      int p = atomicAdd(&off[r4.z], 1);
      edge_s[p] = make_int2(c4.z, __float_as_int(dinv[r4.z] * w4.z * dinv[c4.z]));
    }
    {
      int p = atomicAdd(&off[r4.w], 1);
      edge_s[p] = make_int2(c4.w, __float_as_int(dinv[r4.w] * w4.w * dinv[c4.w]));
    }
  } else {
    for (int i = e; i < Ne; i++) {
      int r = row[i], c = col[i];
      int p = atomicAdd(&off[r], 1);
      edge_s[p] = make_int2(c, __float_as_int(dinv[r] * w[i] * dinv[c]));
    }
  }
}

// ---------- FP32 tiled GEMM with optional BN-fold (input) / BN-stats (output) /
// ---------- fp16 output:  C = [BN_in](A) @ W (+bias)(relu) ----------

__global__ __launch_bounds__(256)
void gemm_kernel(const float* __restrict__ A, const float* __restrict__ W,
                 const float* __restrict__ bias, float* __restrict__ C,
                 __half* __restrict__ Ch,
                 const float* __restrict__ in_stats, const float* __restrict__ in_g,
                 const float* __restrict__ in_beta, float* __restrict__ out_stats,
                 int M, int K, int Nc, int relu) {
  constexpr int BM = 64, BN = 64, BK = 16;
  __shared__ float As[BK][BM + 4];
  __shared__ float Ws[BK][BN];
  __shared__ float bnsc[128], bnsh[128];
  int t = threadIdx.x;
  int tx = t & 15, ty = t >> 4;
  int row0 = blockIdx.y * BM, col0 = blockIdx.x * BN;
  if (in_stats) {
    for (int c = t; c < K; c += 256) {
      float m = in_stats[c] * (1.f / Nn);
      float var = in_stats[K + c] * (1.f / Nn) - m * m;
      float sc = rsqrtf(var + BN_EPS) * in_g[c];
      bnsc[c] = sc;
      bnsh[c] = in_beta[c] - m * sc;
    }
    __syncthreads();
  }
  float acc[4][4] = {};
  for (int k0 = 0; k0 < K; k0 += BK) {
    {
      int r = t >> 2;
      int kq = (t & 3) << 2;
      int grow = row0 + r;
      float4 a = make_float4(0.f, 0.f, 0.f, 0.f);
      if (grow < M) a = *(const float4*)(A + (size_t)grow * K + (k0 + kq));
      if (in_stats) {
        a.x = a.x * bnsc[k0 + kq + 0] + bnsh[k0 + kq + 0];
        a.y = a.y * bnsc[k0 + kq + 1] + bnsh[k0 + kq + 1];
        a.z = a.z * bnsc[k0 + kq + 2] + bnsh[k0 + kq + 2];
        a.w = a.w * bnsc[k0 + kq + 3] + bnsh[k0 + kq + 3];
      }
      As[kq + 0][r] = a.x; As[kq + 1][r] = a.y;
      As[kq + 2][r] = a.z; As[kq + 3][r] = a.w;
    }
    {
      int r = t >> 4;
      int c = (t & 15) << 2;
      int gc = col0 + c;
      float4 w4 = make_float4(0.f, 0.f, 0.f, 0.f);
      if (gc < Nc) w4 = *(const float4*)(W + (size_t)(k0 + r) * Nc + gc);
      Ws[r][c + 0] = w4.x; Ws[r][c + 1] = w4.y;
      Ws[r][c + 2] = w4.z; Ws[r][c + 3] = w4.w;
    }
    __syncthreads();
#pragma unroll
    for (int kk = 0; kk < BK; kk++) {
      float4 av = *(const float4*)&As[kk][ty << 2];
      float4 wv = *(const float4*)&Ws[kk][tx << 2];
      float a4[4] = {av.x, av.y, av.z, av.w};
      float w4[4] = {wv.x, wv.y, wv.z, wv.w};
#pragma unroll
      for (int i = 0; i < 4; i++)
#pragma unroll
        for (int j = 0; j < 4; j++)
          acc[i][j] += a4[i] * w4[j];
    }
    __syncthreads();
  }
  float cs[4] = {0.f, 0.f, 0.f, 0.f}, cq[4] = {0.f, 0.f, 0.f, 0.f};
#pragma unroll
  for (int i = 0; i < 4; i++) {
    int grow = row0 + (ty << 2) + i;
    if (grow >= M) continue;
    float v[4];
#pragma unroll
    for (int j = 0; j < 4; j++) {
      int gc = col0 + (tx << 2) + j;
      float vv = acc[i][j];
      if (bias && gc < Nc) vv += bias[gc];
      if (relu) vv = fmaxf(vv, 0.f);
      v[j] = vv;
      if (out_stats) { cs[j] += vv; cq[j] += vv * vv; }
    }
    if (Ch) {  // fp16 path: Nc multiple of 64, all cols in-range
      __half2 h01 = __floats2half2_rn(v[0], v[1]);
      __half2 h23 = __floats2half2_rn(v[2], v[3]);
      __half2* p = (__half2*)(Ch + (size_t)grow * Nc + col0 + (tx << 2));
      p[0] = h01; p[1] = h23;
    } else {
#pragma unroll
      for (int j = 0; j < 4; j++) {
        int gc = col0 + (tx << 2) + j;
        if (gc < Nc) C[(size_t)grow * Nc + gc] = v[j];
      }
    }
  }
  if (out_stats) {
    int cbase = tx << 2;
#pragma unroll
    for (int j = 0; j < 4; j++) { As[ty][cbase + j] = cs[j]; Ws[ty][cbase + j] = cq[j]; }
    __syncthreads();
    for (int st = 8; st > 0; st >>= 1) {
      if (ty < st) {
#pragma unroll
        for (int j = 0; j < 4; j++) {
          As[ty][cbase + j] += As[ty + st][cbase + j];
          Ws[ty][cbase + j] += Ws[ty + st][cbase + j];
        }
      }
      __syncthreads();
    }
    if (ty == 0) {
#pragma unroll
      for (int j = 0; j < 4; j++) {
        int gc = col0 + cbase + j;
        if (gc < Nc) {
          atomicAdd(&out_stats[gc], As[0][cbase + j]);
          atomicAdd(&out_stats[Nc + gc], Ws[0][cbase + j]);
        }
      }
    }
  }
}

// ---------- gather SpMM (fp16 features, fp32 accumulate): one wave per node ----------

__global__ __launch_bounds__(256)
void gather64_kernel(const __half* __restrict__ t, const int* __restrict__ rowptr,
                     const int2* __restrict__ edge_s,
                     const float* __restrict__ dinv, const float* __restrict__ bias,
                     float* __restrict__ out, int relu) {
  int wave = threadIdx.x >> 6;
  int lane = threadIdx.x & 63;
  int node = blockIdx.x * 4 + wave;
  if (node >= Nn) return;
  int start = rowptr[node], end = rowptr[node + 1];
  float s = dinv[node];
  float acc = s * s * __half2float(t[(size_t)node * 64 + lane]);
  for (int base = start; base < end; base += 64) {
    int m = end - base; if (m > 64) m = 64;
    int cv = 0; float nv = 0.f;
    if (lane < m) {
      int2 ev = edge_s[base + lane];
      cv = ev.x; nv = __int_as_float(ev.y);
    }
    int k = 0;
    for (; k + 4 <= m; k += 4) {
      int c0 = __shfl(cv, k), c1 = __shfl(cv, k + 1);
      int c2 = __shfl(cv, k + 2), c3 = __shfl(cv, k + 3);
      float n0 = __shfl(nv, k), n1 = __shfl(nv, k + 1);
      float n2 = __shfl(nv, k + 2), n3 = __shfl(nv, k + 3);
      float t0 = __half2float(t[(size_t)c0 * 64 + lane]);
      float t1 = __half2float(t[(size_t)c1 * 64 + lane]);
      float t2 = __half2float(t[(size_t)c2 * 64 + lane]);
      float t3 = __half2float(t[(size_t)c3 * 64 + lane]);
      acc += n0 * t0; acc += n1 * t1; acc += n2 * t2; acc += n3 * t3;
    }
    for (; k < m; k++) {
      int c = __shfl(cv, k);
      float nm = __shfl(nv, k);
      acc += nm * __half2float(t[(size_t)c * 64 + lane]);
    }
  }
  acc += bias[lane];
  if (relu) acc = fmaxf(acc, 0.f);
  out[(size_t)node * 64 + lane] = acc;
}

__global__ __launch_bounds__(256)
void gather128_kernel(const __half* __restrict__ t, const int* __restrict__ rowptr,
                      const int2* __restrict__ edge_s,
                      const float* __restrict__ dinv, const float* __restrict__ bias,
                      float* __restrict__ out, int relu) {
  int wave = threadIdx.x >> 6;
  int lane = threadIdx.x & 63;
  int node = blockIdx.x * 4 + wave;
  if (node >= Nn) return;
  int start = rowptr[node], end = rowptr[node + 1];
  float s = dinv[node];
  const __half2* tp = (const __half2*)t;  // row stride = 64 half2
  float2 ti = __half22float2(tp[(size_t)node * 64 + lane]);
  float ax = s * s * ti.x, ay = s * s * ti.y;
  for (int base = start; base < end; base += 64) {
    int m = end - base; if (m > 64) m = 64;
    int cv = 0; float nv = 0.f;
    if (lane < m) {
      int2 ev = edge_s[base + lane];
      cv = ev.x; nv = __int_as_float(ev.y);
    }
    int k = 0;
    for (; k + 4 <= m; k += 4) {
      int c0 = __shfl(cv, k), c1 = __shfl(cv, k + 1);
      int c2 = __shfl(cv, k + 2), c3 = __shfl(cv, k + 3);
      float n0 = __shfl(nv, k), n1 = __shfl(nv, k + 1);
      float n2 = __shfl(nv, k + 2), n3 = __shfl(nv, k + 3);
      float2 t0 = __half22float2(tp[(size_t)c0 * 64 + lane]);
      float2 t1 = __half22float2(tp[(size_t)c1 * 64 + lane]);
      float2 t2 = __half22float2(tp[(size_t)c2 * 64 + lane]);
      float2 t3 = __half22float2(tp[(size_t)c3 * 64 + lane]);
      ax += n0 * t0.x; ay += n0 * t0.y;
      ax += n1 * t1.x; ay += n1 * t1.y;
      ax += n2 * t2.x; ay += n2 * t2.y;
      ax += n3 * t3.x; ay += n3 * t3.y;
    }
    for (; k < m; k++) {
      int c = __shfl(cv, k);
      float nm = __shfl(nv, k);
      float2 tv = __half22float2(tp[(size_t)c * 64 + lane]);
      ax += nm * tv.x; ay += nm * tv.y;
    }
  }
  float2 bb = ((const float2*)bias)[lane];
  ax += bb.x; ay += bb.y;
  if (relu) { ax = fmaxf(ax, 0.f); ay = fmaxf(ay, 0.f); }
  ((float2*)(out + (size_t)node * 128))[lane] = make_float2(ax, ay);
}

// ---------- BatchNorm apply (only for logvar head now) ----------

__global__ void bn_apply_kernel(float* __restrict__ x, float* __restrict__ dup,
                                const float* __restrict__ stats,
                                const float* __restrict__ g, const float* __restrict__ beta,
                                int total, int cmask, int C) {
  int i = blockIdx.x * blockDim.x + threadIdx.x;
  if (i >= total) return;
  int c = i & cmask;
  float m = stats[c] * (1.f / Nn);
  float var = stats[C + c] * (1.f / Nn) - m * m;
  float v = (x[i] - m) * rsqrtf(var + BN_EPS) * g[c] + beta[c];
  x[i] = v;
  if (dup) dup[i] = v;
}

// ---------- fused mu-BN + z copy + Student-t cluster assignment ----------

__global__ __launch_bounds__(256)
void q_bn_kernel(const float* __restrict__ mu_raw, const float* __restrict__ stats,
                 const float* __restrict__ g, const float* __restrict__ beta,
                 const float* __restrict__ centers,
                 float* __restrict__ out_mu, float* __restrict__ out_z,
                 float* __restrict__ q) {
  __shared__ float cs[50 * 32];
  __shared__ float cn[50];
  __shared__ float sc[32], sh[32];
  int tid = threadIdx.x;
  for (int i = tid; i < 50 * 32; i += 256) cs[i] = centers[i];
  if (tid < 32) {
    float m = stats[tid] * (1.f / Nn);
    float var = stats[32 + tid] * (1.f / Nn) - m * m;
    float s = rsqrtf(var + BN_EPS) * g[tid];
    sc[tid] = s; sh[tid] = beta[tid] - m * s;
  }
  __syncthreads();
  if (tid < 50) {
    float s = 0.f;
    for (int j = 0; j < 32; j++) { float v = cs[tid * 32 + j]; s += v * v; }
    cn[tid] = s;
  }
  __syncthreads();
  int n = blockIdx.x * blockDim.x + tid;
  if (n >= Nn) return;
  float zr[32];
  float zn = 0.f;
  const float4* zp = (const float4*)(mu_raw + (size_t)n * 32);
  float4* mo = (float4*)(out_mu + (size_t)n * 32);
  float4* zo = (float4*)(out_z + (size_t)n * 32);
#pragma unroll
  for (int j = 0; j < 8; j++) {
    float4 v = zp[j];
    int c = j * 4;
    v.x = v.x * sc[c + 0] + sh[c + 0];
    v.y = v.y * sc[c + 1] + sh[c + 1];
    v.z = v.z * sc[c + 2] + sh[c + 2];
    v.w = v.w * sc[c + 3] + sh[c + 3];
    mo[j] = v; zo[j] = v;
    zr[c + 0] = v.x; zr[c + 1] = v.y; zr[c + 2] = v.z; zr[c + 3] = v.w;
    zn += v.x * v.x + v.y * v.y + v.z * v.z + v.w * v.w;
  }
  float qv[50];
  float qs = 0.f;
  for (int k = 0; k < 50; k++) {
    float dot = 0.f;
#pragma unroll
    for (int j = 0; j < 32; j++) dot += zr[j] * cs[k * 32 + j];
    float d2 = zn + cn[k] - 2.f * dot;
    d2 = fmaxf(d2, 0.f);
    float qq = 1.f / (1.f + d2);
    qv[k] = qq; qs += qq;
  }
  float inv = 1.f / qs;
  float* qo = q + (size_t)n * 50;
  for (int k = 0; k < 50; k++) qo[k] = qv[k] * inv;
}

// ---------- launch ----------

extern "C" void kernel_launch(void* const* d_in, const int* in_sizes, int n_in,
                              void* d_out, int out_size, void* d_ws, size_t ws_size,
                              hipStream_t stream) {
  const float* x     = (const float*)d_in[0];
  const int*   ei    = (const int*)d_in[1];
  const float* ew    = (const float*)d_in[2];
  const float* W_g1  = (const float*)d_in[3];
  const float* b_g1  = (const float*)d_in[4];
  const float* W_g2  = (const float*)d_in[5];
  const float* b_g2  = (const float*)d_in[6];
  const float* W_g3  = (const float*)d_in[7];
  const float* b_g3  = (const float*)d_in[8];
  const float* W_mu  = (const float*)d_in[9];
  const float* b_mu  = (const float*)d_in[10];
  const float* W_lv  = (const float*)d_in[11];
  const float* b_lv  = (const float*)d_in[12];
  const float* g_mu  = (const float*)d_in[13];
  const float* be_mu = (const float*)d_in[14];
  const float* g_lv  = (const float*)d_in[15];
  const float* be_lv = (const float*)d_in[16];
  const float* W_d1  = (const float*)d_in[17];
  const float* b_d1  = (const float*)d_in[18];
  const float* g_d1  = (const float*)d_in[19];
  const float* be_d1 = (const float*)d_in[20];
  const float* W_d2  = (const float*)d_in[21];
  const float* b_d2  = (const float*)d_in[22];
  const float* g_d2  = (const float*)d_in[23];
  const float* be_d2 = (const float*)d_in[24];
  const float* W_d3  = (const float*)d_in[25];
  const float* b_d3  = (const float*)d_in[26];
  const float* cent  = (const float*)d_in[27];

  const int* row = ei;
  const int* col = ei + Ne;

  float* out    = (float*)d_out;
  float* out_z  = out;
  float* out_mu = out + (size_t)Nn * 32;
  float* out_lv = out + (size_t)Nn * 64;
  float* out_xr = out + (size_t)Nn * 96;   // [N,256]
  float* out_q  = out + (size_t)Nn * 352;  // [N,50]

  // workspace layout (~66 MB):
  // dinv[N] | bufB[N*128] | stats[512] | cnt[N] | rowptr[N+1] | off[N] | bsum[128] | pad | edge_s[E int2]
  // pk[N] (u64) aliases bufB (dead until first gather)
  float* ws     = (float*)d_ws;
  float* dinv   = ws;
  float* bufB   = dinv + Nn;
  float* stats  = bufB + (size_t)Nn * 128;
  int*   cnt    = (int*)(stats + 512);
  int*   rowptr = cnt + Nn;
  int*   off    = rowptr + Nn + 1;
  int*   bsum   = off + Nn;
  int2*  edge_s = (int2*)(bsum + 128 + 1);  // +1 pad keeps 8B alignment
  unsigned long long* pk = (unsigned long long*)bufB;  // aliased; dead before gather128 writes bufB
  float* st_mu = stats, *st_lv = stats + 64, *st_d1 = stats + 128, *st_d2 = stats + 256;

  // scratch in the x_recon output region (written last):
  __half* tA   = (__half*)out_xr;                    // layer1 t [N,128] fp16; reused layer3 t [N,64] fp16
  __half* tC   = (__half*)(out_xr + (size_t)Nn * 128); // layer2 t [N,64] fp16 (region later reused fp32)
  float* bufC  = out_xr + (size_t)Nn * 128;          // layer3 gather out [N,64] fp32 (after tC dead)
  float* bufD  = out_xr + (size_t)Nn * 192;          // [N,64] fp32

  auto cdiv = [](long a, long b) { return (int)((a + b - 1) / b); };
  dim3 blk(256);

  // degree + histogram: single packed u64 atomic per edge
  izero_kernel<<<cdiv(2L * Nn, 256), blk, 0, stream>>>((int*)pk, 2 * Nn);
  fill_kernel<<<1, blk, 0, stream>>>(stats, 0.f, 512);
  deg_pack_kernel<<<cdiv(Ne / 4, 256), blk, 0, stream>>>(row, ew, pk);
  dinv_cnt_kernel<<<cdiv(Nn, 256), blk, 0, stream>>>(pk, dinv, cnt);

  // CSR build: multi-block scan then fill
  scan_phase1<<<SCAN_NB, blk, 0, stream>>>(cnt, bsum);
  scan_phase2<<<1, 128, 0, stream>>>(bsum);
  scan_phase3<<<SCAN_NB, blk, 0, stream>>>(cnt, bsum, rowptr, off);
  csr_fill_kernel<<<cdiv(Ne / 4, 256), blk, 0, stream>>>(row, col, ew, dinv, off, edge_s);

  int ggrid = cdiv(Nn, 4);  // one wave per node, 4 waves/block

  // GCN layer 1: 256 -> 128 (t in fp16), aggregate, relu
  gemm_kernel<<<dim3(2, cdiv(Nn, 64)), blk, 0, stream>>>(
      x, W_g1, nullptr, nullptr, tA, nullptr, nullptr, nullptr, nullptr, Nn, 256, 128, 0);
  gather128_kernel<<<ggrid, blk, 0, stream>>>(tA, rowptr, edge_s, dinv, b_g1, bufB, 1);

  // GCN layer 2: 128 -> 64 (t in fp16), aggregate, relu
  gemm_kernel<<<dim3(1, cdiv(Nn, 64)), blk, 0, stream>>>(
      bufB, W_g2, nullptr, nullptr, tC, nullptr, nullptr, nullptr, nullptr, Nn, 128, 64, 0);
  gather64_kernel<<<ggrid, blk, 0, stream>>>(tC, rowptr, edge_s, dinv, b_g2, bufD, 1);

  // GCN layer 3: 64 -> 64 (t in fp16), aggregate, no relu
  gemm_kernel<<<dim3(1, cdiv(Nn, 64)), blk, 0, stream>>>(
      bufD, W_g3, nullptr, nullptr, tA, nullptr, nullptr, nullptr, nullptr, Nn, 64, 64, 0);
  gather64_kernel<<<ggrid, blk, 0, stream>>>(tA, rowptr, edge_s, dinv, b_g3, bufC, 0);

  // VAE heads: 64 -> 32, stats fused into GEMM epilogue
  gemm_kernel<<<dim3(1, cdiv(Nn, 64)), blk, 0, stream>>>(
      bufC, W_mu, b_mu, out_mu, nullptr, nullptr, nullptr, nullptr, st_mu, Nn, 64, 32, 0);
  gemm_kernel<<<dim3(1, cdiv(Nn, 64)), blk, 0, stream>>>(
      bufC, W_lv, b_lv, out_lv, nullptr, nullptr, nullptr, nullptr, st_lv, Nn, 64, 32, 0);
  bn_apply_kernel<<<cdiv((long)Nn * 32, 256), blk, 0, stream>>>(
      out_lv, nullptr, st_lv, g_lv, be_lv, Nn * 32, 31, 32);

  // fused mu-BN + z + Student-t q (out_z needed by decoder below)
  q_bn_kernel<<<cdiv(Nn, 256), blk, 0, stream>>>(out_mu, st_mu, g_mu, be_mu, cent,
                                                 out_mu, out_z, out_q);

  // decoder 32 -> 64 -> 128 -> 256 with BN folded into following GEMM A-loads
  gemm_kernel<<<dim3(1, cdiv(Nn, 64)), blk, 0, stream>>>(
      out_z, W_d1, b_d1, bufD, nullptr, nullptr, nullptr, nullptr, st_d1, Nn, 32, 64, 1);
  gemm_kernel<<<dim3(2, cdiv(Nn, 64)), blk, 0, stream>>>(
      bufD, W_d2, b_d2, bufB, nullptr, st_d1, g_d1, be_d1, st_d2, Nn, 64, 128, 1);
  gemm_kernel<<<dim3(4, cdiv(Nn, 64)), blk, 0, stream>>>(
      bufB, W_d3, b_d3, out_xr, nullptr, st_d2, g_d2, be_d2, nullptr, Nn, 128, 256, 0);
}

// Round 3
// 1002.676 us; speedup vs baseline: 1.3745x; 1.3745x over previous
//
#include <hip/hip_runtime.h>
#include <hip/hip_fp16.h>

constexpr int Nn = 100000;
constexpr int Ne = 1600000;
constexpr float BN_EPS = 1e-5f;

constexpr int SCAN_TILE = 1024;                          // elements per block
constexpr int SCAN_NB = (Nn + SCAN_TILE - 1) / SCAN_TILE; // 98

constexpr float FIX_SCALE = 16777216.f;       // 2^24
constexpr float FIX_INV = 1.f / 16777216.f;

constexpr int NCOPY = 32;        // replicated stats slots (anti-contention)
constexpr int CSTRIDE = 512;     // floats per slot

// ---------- small utility kernels ----------

__global__ void fill_kernel(float* __restrict__ p, float v, int n) {
  int i = blockIdx.x * blockDim.x + threadIdx.x;
  if (i < n) p[i] = v;
}

__global__ void izero_kernel(int* __restrict__ p, int n) {
  int i = blockIdx.x * blockDim.x + threadIdx.x;
  if (i < n) p[i] = 0;
}

// fold NCOPY replicated partial-stat slots into the final stats array
__global__ void fold_stats_kernel(const float* __restrict__ part, float* __restrict__ dst,
                                  int len) {
  int i = blockIdx.x * blockDim.x + threadIdx.x;
  if (i < len) {
    float s = 0.f;
#pragma unroll 8
    for (int k = 0; k < NCOPY; k++) s += part[k * CSTRIDE + i];
    dst[i] = s;
  }
}

// fused: one u64 atomic per edge packs {cnt:1 << 40 | fix24(w)}
__global__ __launch_bounds__(256)
void deg_pack_kernel(const int* __restrict__ row, const float* __restrict__ w,
                     unsigned long long* __restrict__ pk) {
  int e = (blockIdx.x * blockDim.x + threadIdx.x) * 4;
  if (e + 4 <= Ne) {
    int4 r4 = *(const int4*)(row + e);
    float4 w4 = *(const float4*)(w + e);
    atomicAdd(&pk[r4.x], (1ULL << 40) | (unsigned long long)__float2uint_rn(w4.x * FIX_SCALE));
    atomicAdd(&pk[r4.y], (1ULL << 40) | (unsigned long long)__float2uint_rn(w4.y * FIX_SCALE));
    atomicAdd(&pk[r4.z], (1ULL << 40) | (unsigned long long)__float2uint_rn(w4.z * FIX_SCALE));
    atomicAdd(&pk[r4.w], (1ULL << 40) | (unsigned long long)__float2uint_rn(w4.w * FIX_SCALE));
  } else {
    for (int i = e; i < Ne; i++) {
      atomicAdd(&pk[row[i]], (1ULL << 40) | (unsigned long long)__float2uint_rn(w[i] * FIX_SCALE));
    }
  }
}

// unpack: cnt = pk>>40 ; deg = fix*2^-24 + 1 (self loop) ; dinv = rsqrt(deg)
__global__ void dinv_cnt_kernel(const unsigned long long* __restrict__ pk,
                                float* __restrict__ dinv, int* __restrict__ cnt) {
  int i = blockIdx.x * blockDim.x + threadIdx.x;
  if (i < Nn) {
    unsigned long long v = pk[i];
    cnt[i] = (int)(v >> 40);
    float deg = (float)(v & ((1ULL << 40) - 1)) * FIX_INV + 1.0f;  // + self-loop weight
    dinv[i] = (deg > 0.f) ? rsqrtf(fmaxf(deg, 1e-12f)) : 0.f;
  }
}

// ---------- multi-block exclusive scan (cnt[Nn] -> rowptr[Nn+1], off) ----------

__global__ __launch_bounds__(256)
void scan_phase1(const int* __restrict__ cnt, int* __restrict__ bsum) {
  __shared__ int s[256];
  int b = blockIdx.x, tid = threadIdx.x;
  int base = b * SCAN_TILE + tid * 4;
  int t = 0;
#pragma unroll
  for (int i = 0; i < 4; i++) {
    int idx = base + i;
    if (idx < Nn) t += cnt[idx];
  }
  s[tid] = t;
  __syncthreads();
  for (int st = 128; st > 0; st >>= 1) {
    if (tid < st) s[tid] += s[tid + st];
    __syncthreads();
  }
  if (tid == 0) bsum[b] = s[0];
}

__global__ __launch_bounds__(128)
void scan_phase2(int* __restrict__ bsum) {  // in-place exclusive scan, SCAN_NB <= 128
  __shared__ int s[128];
  int tid = threadIdx.x;
  int v = (tid < SCAN_NB) ? bsum[tid] : 0;
  s[tid] = v;
  __syncthreads();
  for (int st = 1; st < 128; st <<= 1) {
    int u = (tid >= st) ? s[tid - st] : 0;
    __syncthreads();
    s[tid] += u;
    __syncthreads();
  }
  if (tid < SCAN_NB) bsum[tid] = s[tid] - v;  // exclusive prefix
}

__global__ __launch_bounds__(256)
void scan_phase3(const int* __restrict__ cnt, const int* __restrict__ bsum,
                 int* __restrict__ rowptr, int* __restrict__ off) {
  __shared__ int s[256];
  int b = blockIdx.x, tid = threadIdx.x;
  int base = b * SCAN_TILE + tid * 4;
  int vals[4];
  int t = 0;
#pragma unroll
  for (int i = 0; i < 4; i++) {
    int idx = base + i;
    vals[i] = (idx < Nn) ? cnt[idx] : 0;
    t += vals[i];
  }
  s[tid] = t;
  __syncthreads();
  for (int st = 1; st < 256; st <<= 1) {
    int u = (tid >= st) ? s[tid - st] : 0;
    __syncthreads();
    s[tid] += u;
    __syncthreads();
  }
  int run = bsum[b] + s[tid] - t;  // exclusive prefix for this thread's 4 elems
#pragma unroll
  for (int i = 0; i < 4; i++) {
    int idx = base + i;
    if (idx < Nn) { rowptr[idx] = run; off[idx] = run; run += vals[i]; }
  }
  if (b == SCAN_NB - 1 && tid == 255) rowptr[Nn] = bsum[b] + s[255];
}

// CSR fill: interleaved {col, norm} -> single 8B scattered store per edge
__global__ __launch_bounds__(256)
void csr_fill_kernel(const int* __restrict__ row, const int* __restrict__ col,
                     const float* __restrict__ w, const float* __restrict__ dinv,
                     int* __restrict__ off, int2* __restrict__ edge_s) {
  int e = (blockIdx.x * blockDim.x + threadIdx.x) * 4;
  if (e + 4 <= Ne) {
    int4 r4 = *(const int4*)(row + e);
    int4 c4 = *(const int4*)(col + e);
    float4 w4 = *(const float4*)(w + e);
    {
      int p = atomicAdd(&off[r4.x], 1);
      edge_s[p] = make_int2(c4.x, __float_as_int(dinv[r4.x] * w4.x * dinv[c4.x]));
    }
    {
      int p = atomicAdd(&off[r4.y], 1);
      edge_s[p] = make_int2(c4.y, __float_as_int(dinv[r4.y] * w4.y * dinv[c4.y]));
    }
    {
      int p = atomicAdd(&off[r4.z], 1);
      edge_s[p] = make_int2(c4.z, __float_as_int(dinv[r4.z] * w4.z * dinv[c4.z]));
    }
    {
      int p = atomicAdd(&off[r4.w], 1);
      edge_s[p] = make_int2(c4.w, __float_as_int(dinv[r4.w] * w4.w * dinv[c4.w]));
    }
  } else {
    for (int i = e; i < Ne; i++) {
      int r = row[i], c = col[i];
      int p = atomicAdd(&off[r], 1);
      edge_s[p] = make_int2(c, __float_as_int(dinv[r] * w[i] * dinv[c]));
    }
  }
}

// ---------- FP32 tiled GEMM with optional BN-fold (input) / replicated BN-stats
// ---------- (output) / fp16 output:  C = [BN_in](A) @ W (+bias)(relu) ----------

__global__ __launch_bounds__(256)
void gemm_kernel(const float* __restrict__ A, const float* __restrict__ W,
                 const float* __restrict__ bias, float* __restrict__ C,
                 __half* __restrict__ Ch,
                 const float* __restrict__ in_stats, const float* __restrict__ in_g,
                 const float* __restrict__ in_beta, float* __restrict__ out_part,
                 int M, int K, int Nc, int relu) {
  constexpr int BM = 64, BN = 64, BK = 16;
  __shared__ float As[BK][BM + 4];
  __shared__ float Ws[BK][BN];
  __shared__ float bnsc[128], bnsh[128];
  int t = threadIdx.x;
  int tx = t & 15, ty = t >> 4;
  int row0 = blockIdx.y * BM, col0 = blockIdx.x * BN;
  if (in_stats) {
    for (int c = t; c < K; c += 256) {
      float m = in_stats[c] * (1.f / Nn);
      float var = in_stats[K + c] * (1.f / Nn) - m * m;
      float sc = rsqrtf(var + BN_EPS) * in_g[c];
      bnsc[c] = sc;
      bnsh[c] = in_beta[c] - m * sc;
    }
    __syncthreads();
  }
  float acc[4][4] = {};
  for (int k0 = 0; k0 < K; k0 += BK) {
    {
      int r = t >> 2;
      int kq = (t & 3) << 2;
      int grow = row0 + r;
      float4 a = make_float4(0.f, 0.f, 0.f, 0.f);
      if (grow < M) a = *(const float4*)(A + (size_t)grow * K + (k0 + kq));
      if (in_stats) {
        a.x = a.x * bnsc[k0 + kq + 0] + bnsh[k0 + kq + 0];
        a.y = a.y * bnsc[k0 + kq + 1] + bnsh[k0 + kq + 1];
        a.z = a.z * bnsc[k0 + kq + 2] + bnsh[k0 + kq + 2];
        a.w = a.w * bnsc[k0 + kq + 3] + bnsh[k0 + kq + 3];
      }
      As[kq + 0][r] = a.x; As[kq + 1][r] = a.y;
      As[kq + 2][r] = a.z; As[kq + 3][r] = a.w;
    }
    {
      int r = t >> 4;
      int c = (t & 15) << 2;
      int gc = col0 + c;
      float4 w4 = make_float4(0.f, 0.f, 0.f, 0.f);
      if (gc < Nc) w4 = *(const float4*)(W + (size_t)(k0 + r) * Nc + gc);
      Ws[r][c + 0] = w4.x; Ws[r][c + 1] = w4.y;
      Ws[r][c + 2] = w4.z; Ws[r][c + 3] = w4.w;
    }
    __syncthreads();
#pragma unroll
    for (int kk = 0; kk < BK; kk++) {
      float4 av = *(const float4*)&As[kk][ty << 2];
      float4 wv = *(const float4*)&Ws[kk][tx << 2];
      float a4[4] = {av.x, av.y, av.z, av.w};
      float w4[4] = {wv.x, wv.y, wv.z, wv.w};
#pragma unroll
      for (int i = 0; i < 4; i++)
#pragma unroll
        for (int j = 0; j < 4; j++)
          acc[i][j] += a4[i] * w4[j];
    }
    __syncthreads();
  }
  float cs[4] = {0.f, 0.f, 0.f, 0.f}, cq[4] = {0.f, 0.f, 0.f, 0.f};
#pragma unroll
  for (int i = 0; i < 4; i++) {
    int grow = row0 + (ty << 2) + i;
    if (grow >= M) continue;
    float v[4];
#pragma unroll
    for (int j = 0; j < 4; j++) {
      int gc = col0 + (tx << 2) + j;
      float vv = acc[i][j];
      if (bias && gc < Nc) vv += bias[gc];
      if (relu) vv = fmaxf(vv, 0.f);
      v[j] = vv;
      if (out_part) { cs[j] += vv; cq[j] += vv * vv; }
    }
    if (Ch) {  // fp16 path: Nc multiple of 64, all cols in-range
      __half2 h01 = __floats2half2_rn(v[0], v[1]);
      __half2 h23 = __floats2half2_rn(v[2], v[3]);
      __half2* p = (__half2*)(Ch + (size_t)grow * Nc + col0 + (tx << 2));
      p[0] = h01; p[1] = h23;
    } else {
#pragma unroll
      for (int j = 0; j < 4; j++) {
        int gc = col0 + (tx << 2) + j;
        if (gc < Nc) C[(size_t)grow * Nc + gc] = v[j];
      }
    }
  }
  if (out_part) {
    int cbase = tx << 2;
#pragma unroll
    for (int j = 0; j < 4; j++) { As[ty][cbase + j] = cs[j]; Ws[ty][cbase + j] = cq[j]; }
    __syncthreads();
    for (int st = 8; st > 0; st >>= 1) {
      if (ty < st) {
#pragma unroll
        for (int j = 0; j < 4; j++) {
          As[ty][cbase + j] += As[ty + st][cbase + j];
          Ws[ty][cbase + j] += Ws[ty + st][cbase + j];
        }
      }
      __syncthreads();
    }
    if (ty == 0) {
      float* dst = out_part + (blockIdx.y & (NCOPY - 1)) * CSTRIDE;
#pragma unroll
      for (int j = 0; j < 4; j++) {
        int gc = col0 + cbase + j;
        if (gc < Nc) {
          atomicAdd(&dst[gc], As[0][cbase + j]);
          atomicAdd(&dst[Nc + gc], Ws[0][cbase + j]);
        }
      }
    }
  }
}

// ---------- gather SpMM (fp16 features, fp32 accumulate): one wave per node ----------

__global__ __launch_bounds__(256)
void gather64_kernel(const __half* __restrict__ t, const int* __restrict__ rowptr,
                     const int2* __restrict__ edge_s,
                     const float* __restrict__ dinv, const float* __restrict__ bias,
                     float* __restrict__ out, int relu) {
  int wave = threadIdx.x >> 6;
  int lane = threadIdx.x & 63;
  int node = blockIdx.x * 4 + wave;
  if (node >= Nn) return;
  int start = rowptr[node], end = rowptr[node + 1];
  float s = dinv[node];
  float acc = s * s * __half2float(t[(size_t)node * 64 + lane]);
  for (int base = start; base < end; base += 64) {
    int m = end - base; if (m > 64) m = 64;
    int cv = 0; float nv = 0.f;
    if (lane < m) {
      int2 ev = edge_s[base + lane];
      cv = ev.x; nv = __int_as_float(ev.y);
    }
    int k = 0;
    for (; k + 4 <= m; k += 4) {
      int c0 = __shfl(cv, k), c1 = __shfl(cv, k + 1);
      int c2 = __shfl(cv, k + 2), c3 = __shfl(cv, k + 3);
      float n0 = __shfl(nv, k), n1 = __shfl(nv, k + 1);
      float n2 = __shfl(nv, k + 2), n3 = __shfl(nv, k + 3);
      float t0 = __half2float(t[(size_t)c0 * 64 + lane]);
      float t1 = __half2float(t[(size_t)c1 * 64 + lane]);
      float t2 = __half2float(t[(size_t)c2 * 64 + lane]);
      float t3 = __half2float(t[(size_t)c3 * 64 + lane]);
      acc += n0 * t0; acc += n1 * t1; acc += n2 * t2; acc += n3 * t3;
    }
    for (; k < m; k++) {
      int c = __shfl(cv, k);
      float nm = __shfl(nv, k);
      acc += nm * __half2float(t[(size_t)c * 64 + lane]);
    }
  }
  acc += bias[lane];
  if (relu) acc = fmaxf(acc, 0.f);
  out[(size_t)node * 64 + lane] = acc;
}

__global__ __launch_bounds__(256)
void gather128_kernel(const __half* __restrict__ t, const int* __restrict__ rowptr,
                      const int2* __restrict__ edge_s,
                      const float* __restrict__ dinv, const float* __restrict__ bias,
                      float* __restrict__ out, int relu) {
  int wave = threadIdx.x >> 6;
  int lane = threadIdx.x & 63;
  int node = blockIdx.x * 4 + wave;
  if (node >= Nn) return;
  int start = rowptr[node], end = rowptr[node + 1];
  float s = dinv[node];
  const __half2* tp = (const __half2*)t;  // row stride = 64 half2
  float2 ti = __half22float2(tp[(size_t)node * 64 + lane]);
  float ax = s * s * ti.x, ay = s * s * ti.y;
  for (int base = start; base < end; base += 64) {
    int m = end - base; if (m > 64) m = 64;
    int cv = 0; float nv = 0.f;
    if (lane < m) {
      int2 ev = edge_s[base + lane];
      cv = ev.x; nv = __int_as_float(ev.y);
    }
    int k = 0;
    for (; k + 4 <= m; k += 4) {
      int c0 = __shfl(cv, k), c1 = __shfl(cv, k + 1);
      int c2 = __shfl(cv, k + 2), c3 = __shfl(cv, k + 3);
      float n0 = __shfl(nv, k), n1 = __shfl(nv, k + 1);
      float n2 = __shfl(nv, k + 2), n3 = __shfl(nv, k + 3);
      float2 t0 = __half22float2(tp[(size_t)c0 * 64 + lane]);
      float2 t1 = __half22float2(tp[(size_t)c1 * 64 + lane]);
      float2 t2 = __half22float2(tp[(size_t)c2 * 64 + lane]);
      float2 t3 = __half22float2(tp[(size_t)c3 * 64 + lane]);
      ax += n0 * t0.x; ay += n0 * t0.y;
      ax += n1 * t1.x; ay += n1 * t1.y;
      ax += n2 * t2.x; ay += n2 * t2.y;
      ax += n3 * t3.x; ay += n3 * t3.y;
    }
    for (; k < m; k++) {
      int c = __shfl(cv, k);
      float nm = __shfl(nv, k);
      float2 tv = __half22float2(tp[(size_t)c * 64 + lane]);
      ax += nm * tv.x; ay += nm * tv.y;
    }
  }
  float2 bb = ((const float2*)bias)[lane];
  ax += bb.x; ay += bb.y;
  if (relu) { ax = fmaxf(ax, 0.f); ay = fmaxf(ay, 0.f); }
  ((float2*)(out + (size_t)node * 128))[lane] = make_float2(ax, ay);
}

// ---------- BatchNorm apply (only for logvar head now) ----------

__global__ void bn_apply_kernel(float* __restrict__ x, float* __restrict__ dup,
                                const float* __restrict__ stats,
                                const float* __restrict__ g, const float* __restrict__ beta,
                                int total, int cmask, int C) {
  int i = blockIdx.x * blockDim.x + threadIdx.x;
  if (i >= total) return;
  int c = i & cmask;
  float m = stats[c] * (1.f / Nn);
  float var = stats[C + c] * (1.f / Nn) - m * m;
  float v = (x[i] - m) * rsqrtf(var + BN_EPS) * g[c] + beta[c];
  x[i] = v;
  if (dup) dup[i] = v;
}

// ---------- fused mu-BN + z copy + Student-t cluster assignment ----------

__global__ __launch_bounds__(256)
void q_bn_kernel(const float* __restrict__ mu_raw, const float* __restrict__ stats,
                 const float* __restrict__ g, const float* __restrict__ beta,
                 const float* __restrict__ centers,
                 float* __restrict__ out_mu, float* __restrict__ out_z,
                 float* __restrict__ q) {
  __shared__ float cs[50 * 32];
  __shared__ float cn[50];
  __shared__ float sc[32], sh[32];
  int tid = threadIdx.x;
  for (int i = tid; i < 50 * 32; i += 256) cs[i] = centers[i];
  if (tid < 32) {
    float m = stats[tid] * (1.f / Nn);
    float var = stats[32 + tid] * (1.f / Nn) - m * m;
    float s = rsqrtf(var + BN_EPS) * g[tid];
    sc[tid] = s; sh[tid] = beta[tid] - m * s;
  }
  __syncthreads();
  if (tid < 50) {
    float s = 0.f;
    for (int j = 0; j < 32; j++) { float v = cs[tid * 32 + j]; s += v * v; }
    cn[tid] = s;
  }
  __syncthreads();
  int n = blockIdx.x * blockDim.x + tid;
  if (n >= Nn) return;
  float zr[32];
  float zn = 0.f;
  const float4* zp = (const float4*)(mu_raw + (size_t)n * 32);
  float4* mo = (float4*)(out_mu + (size_t)n * 32);
  float4* zo = (float4*)(out_z + (size_t)n * 32);
#pragma unroll
  for (int j = 0; j < 8; j++) {
    float4 v = zp[j];
    int c = j * 4;
    v.x = v.x * sc[c + 0] + sh[c + 0];
    v.y = v.y * sc[c + 1] + sh[c + 1];
    v.z = v.z * sc[c + 2] + sh[c + 2];
    v.w = v.w * sc[c + 3] + sh[c + 3];
    mo[j] = v; zo[j] = v;
    zr[c + 0] = v.x; zr[c + 1] = v.y; zr[c + 2] = v.z; zr[c + 3] = v.w;
    zn += v.x * v.x + v.y * v.y + v.z * v.z + v.w * v.w;
  }
  float qv[50];
  float qs = 0.f;
  for (int k = 0; k < 50; k++) {
    float dot = 0.f;
#pragma unroll
    for (int j = 0; j < 32; j++) dot += zr[j] * cs[k * 32 + j];
    float d2 = zn + cn[k] - 2.f * dot;
    d2 = fmaxf(d2, 0.f);
    float qq = 1.f / (1.f + d2);
    qv[k] = qq; qs += qq;
  }
  float inv = 1.f / qs;
  float* qo = q + (size_t)n * 50;
  for (int k = 0; k < 50; k++) qo[k] = qv[k] * inv;
}

// ---------- launch ----------

extern "C" void kernel_launch(void* const* d_in, const int* in_sizes, int n_in,
                              void* d_out, int out_size, void* d_ws, size_t ws_size,
                              hipStream_t stream) {
  const float* x     = (const float*)d_in[0];
  const int*   ei    = (const int*)d_in[1];
  const float* ew    = (const float*)d_in[2];
  const float* W_g1  = (const float*)d_in[3];
  const float* b_g1  = (const float*)d_in[4];
  const float* W_g2  = (const float*)d_in[5];
  const float* b_g2  = (const float*)d_in[6];
  const float* W_g3  = (const float*)d_in[7];
  const float* b_g3  = (const float*)d_in[8];
  const float* W_mu  = (const float*)d_in[9];
  const float* b_mu  = (const float*)d_in[10];
  const float* W_lv  = (const float*)d_in[11];
  const float* b_lv  = (const float*)d_in[12];
  const float* g_mu  = (const float*)d_in[13];
  const float* be_mu = (const float*)d_in[14];
  const float* g_lv  = (const float*)d_in[15];
  const float* be_lv = (const float*)d_in[16];
  const float* W_d1  = (const float*)d_in[17];
  const float* b_d1  = (const float*)d_in[18];
  const float* g_d1  = (const float*)d_in[19];
  const float* be_d1 = (const float*)d_in[20];
  const float* W_d2  = (const float*)d_in[21];
  const float* b_d2  = (const float*)d_in[22];
  const float* g_d2  = (const float*)d_in[23];
  const float* be_d2 = (const float*)d_in[24];
  const float* W_d3  = (const float*)d_in[25];
  const float* b_d3  = (const float*)d_in[26];
  const float* cent  = (const float*)d_in[27];

  const int* row = ei;
  const int* col = ei + Ne;

  float* out    = (float*)d_out;
  float* out_z  = out;
  float* out_mu = out + (size_t)Nn * 32;
  float* out_lv = out + (size_t)Nn * 64;
  float* out_xr = out + (size_t)Nn * 96;   // [N,256]
  float* out_q  = out + (size_t)Nn * 352;  // [N,50]

  // workspace layout (~66 MB):
  // dinv[N] | bufB[N*128] | stats[512] | cnt[N] | rowptr[N+1] | off[N] | bsum[128] | pad | edge_s[E int2]
  // pk[N] (u64) aliases bufB (dead until first gather)
  float* ws     = (float*)d_ws;
  float* dinv   = ws;
  float* bufB   = dinv + Nn;
  float* stats  = bufB + (size_t)Nn * 128;
  int*   cnt    = (int*)(stats + 512);
  int*   rowptr = cnt + Nn;
  int*   off    = rowptr + Nn + 1;
  int*   bsum   = off + Nn;
  int2*  edge_s = (int2*)(bsum + 128 + 1);  // +1 pad keeps 8B alignment
  unsigned long long* pk = (unsigned long long*)bufB;  // aliased; dead before gather128 writes bufB
  float* st_mu = stats, *st_lv = stats + 64, *st_d1 = stats + 128, *st_d2 = stats + 256;

  // scratch in the x_recon output region (written last):
  __half* tA   = (__half*)out_xr;                    // layer1 t [N,128] fp16; reused layer3 t [N,64] fp16
  __half* tC   = (__half*)(out_xr + (size_t)Nn * 128); // layer2 t [N,64] fp16 (region later reused fp32)
  float* bufC  = out_xr + (size_t)Nn * 128;          // layer3 gather out [N,64] fp32 (after tC dead)
  float* bufD  = out_xr + (size_t)Nn * 192;          // [N,64] fp32
  // replicated stats partials: 2nd quarter of out_xr region — untouched by tA
  // (tA is only N*64 floats of halfs), dead until d3 writes out_xr at the end.
  float* stats_part = out_xr + (size_t)Nn * 64;      // NCOPY*CSTRIDE = 16K floats

  auto cdiv = [](long a, long b) { return (int)((a + b - 1) / b); };
  dim3 blk(256);

  // degree + histogram: single packed u64 atomic per edge
  izero_kernel<<<cdiv(2L * Nn, 256), blk, 0, stream>>>((int*)pk, 2 * Nn);
  fill_kernel<<<1, blk, 0, stream>>>(stats, 0.f, 512);
  fill_kernel<<<cdiv(NCOPY * CSTRIDE, 256), blk, 0, stream>>>(stats_part, 0.f, NCOPY * CSTRIDE);
  deg_pack_kernel<<<cdiv(Ne / 4, 256), blk, 0, stream>>>(row, ew, pk);
  dinv_cnt_kernel<<<cdiv(Nn, 256), blk, 0, stream>>>(pk, dinv, cnt);

  // CSR build: multi-block scan then fill
  scan_phase1<<<SCAN_NB, blk, 0, stream>>>(cnt, bsum);
  scan_phase2<<<1, 128, 0, stream>>>(bsum);
  scan_phase3<<<SCAN_NB, blk, 0, stream>>>(cnt, bsum, rowptr, off);
  csr_fill_kernel<<<cdiv(Ne / 4, 256), blk, 0, stream>>>(row, col, ew, dinv, off, edge_s);

  int ggrid = cdiv(Nn, 4);  // one wave per node, 4 waves/block

  // GCN layer 1: 256 -> 128 (t in fp16), aggregate, relu
  gemm_kernel<<<dim3(2, cdiv(Nn, 64)), blk, 0, stream>>>(
      x, W_g1, nullptr, nullptr, tA, nullptr, nullptr, nullptr, nullptr, Nn, 256, 128, 0);
  gather128_kernel<<<ggrid, blk, 0, stream>>>(tA, rowptr, edge_s, dinv, b_g1, bufB, 1);

  // GCN layer 2: 128 -> 64 (t in fp16), aggregate, relu
  gemm_kernel<<<dim3(1, cdiv(Nn, 64)), blk, 0, stream>>>(
      bufB, W_g2, nullptr, nullptr, tC, nullptr, nullptr, nullptr, nullptr, Nn, 128, 64, 0);
  gather64_kernel<<<ggrid, blk, 0, stream>>>(tC, rowptr, edge_s, dinv, b_g2, bufD, 1);

  // GCN layer 3: 64 -> 64 (t in fp16), aggregate, no relu
  gemm_kernel<<<dim3(1, cdiv(Nn, 64)), blk, 0, stream>>>(
      bufD, W_g3, nullptr, nullptr, tA, nullptr, nullptr, nullptr, nullptr, Nn, 64, 64, 0);
  gather64_kernel<<<ggrid, blk, 0, stream>>>(tA, rowptr, edge_s, dinv, b_g3, bufC, 0);

  // VAE heads: 64 -> 32, partial stats fused into GEMM epilogue (replicated slots)
  gemm_kernel<<<dim3(1, cdiv(Nn, 64)), blk, 0, stream>>>(
      bufC, W_mu, b_mu, out_mu, nullptr, nullptr, nullptr, nullptr, stats_part, Nn, 64, 32, 0);
  gemm_kernel<<<dim3(1, cdiv(Nn, 64)), blk, 0, stream>>>(
      bufC, W_lv, b_lv, out_lv, nullptr, nullptr, nullptr, nullptr, stats_part + 64, Nn, 64, 32, 0);
  fold_stats_kernel<<<1, blk, 0, stream>>>(stats_part, stats, 128);  // mu+lv slices
  bn_apply_kernel<<<cdiv((long)Nn * 32, 256), blk, 0, stream>>>(
      out_lv, nullptr, st_lv, g_lv, be_lv, Nn * 32, 31, 32);

  // fused mu-BN + z + Student-t q (out_z needed by decoder below)
  q_bn_kernel<<<cdiv(Nn, 256), blk, 0, stream>>>(out_mu, st_mu, g_mu, be_mu, cent,
                                                 out_mu, out_z, out_q);

  // decoder 32 -> 64 -> 128 -> 256 with BN folded into following GEMM A-loads
  gemm_kernel<<<dim3(1, cdiv(Nn, 64)), blk, 0, stream>>>(
      out_z, W_d1, b_d1, bufD, nullptr, nullptr, nullptr, nullptr, stats_part + 128, Nn, 32, 64, 1);
  fold_stats_kernel<<<1, blk, 0, stream>>>(stats_part + 128, stats + 128, 128);  // d1 slice
  gemm_kernel<<<dim3(2, cdiv(Nn, 64)), blk, 0, stream>>>(
      bufD, W_d2, b_d2, bufB, nullptr, st_d1, g_d1, be_d1, stats_part + 256, Nn, 64, 128, 1);
  fold_stats_kernel<<<1, blk, 0, stream>>>(stats_part + 256, stats + 256, 256);  // d2 slice
  gemm_kernel<<<dim3(4, cdiv(Nn, 64)), blk, 0, stream>>>(
      bufB, W_d3, b_d3, out_xr, nullptr, st_d2, g_d2, be_d2, nullptr, Nn, 128, 256, 0);
}

// Round 4
// 999.804 us; speedup vs baseline: 1.3784x; 1.0029x over previous
//
#include <hip/hip_runtime.h>
#include <hip/hip_fp16.h>

constexpr int Nn = 100000;
constexpr int Ne = 1600000;
constexpr float BN_EPS = 1e-5f;

constexpr int SCAN_TILE = 1024;                          // elements per block
constexpr int SCAN_NB = (Nn + SCAN_TILE - 1) / SCAN_TILE; // 98

constexpr float FIX_SCALE = 16777216.f;       // 2^24
constexpr float FIX_INV = 1.f / 16777216.f;

constexpr int NCOPY = 32;        // replicated stats slots (anti-contention)
constexpr int CSTRIDE = 512;     // floats per slot

// ---------- small utility kernels ----------

__global__ void fill_kernel(float* __restrict__ p, float v, int n) {
  int i = blockIdx.x * blockDim.x + threadIdx.x;
  if (i < n) p[i] = v;
}

__global__ void izero_kernel(int* __restrict__ p, int n) {
  int i = blockIdx.x * blockDim.x + threadIdx.x;
  if (i < n) p[i] = 0;
}

// fold NCOPY replicated partial-stat slots into the final stats array
__global__ void fold_stats_kernel(const float* __restrict__ part, float* __restrict__ dst,
                                  int len) {
  int i = blockIdx.x * blockDim.x + threadIdx.x;
  if (i < len) {
    float s = 0.f;
#pragma unroll 8
    for (int k = 0; k < NCOPY; k++) s += part[k * CSTRIDE + i];
    dst[i] = s;
  }
}

// fused: one u64 atomic per edge packs {cnt:1 << 40 | fix24(w)}
__global__ __launch_bounds__(256)
void deg_pack_kernel(const int* __restrict__ row, const float* __restrict__ w,
                     unsigned long long* __restrict__ pk) {
  int e = (blockIdx.x * blockDim.x + threadIdx.x) * 4;
  if (e + 4 <= Ne) {
    int4 r4 = *(const int4*)(row + e);
    float4 w4 = *(const float4*)(w + e);
    atomicAdd(&pk[r4.x], (1ULL << 40) | (unsigned long long)__float2uint_rn(w4.x * FIX_SCALE));
    atomicAdd(&pk[r4.y], (1ULL << 40) | (unsigned long long)__float2uint_rn(w4.y * FIX_SCALE));
    atomicAdd(&pk[r4.z], (1ULL << 40) | (unsigned long long)__float2uint_rn(w4.z * FIX_SCALE));
    atomicAdd(&pk[r4.w], (1ULL << 40) | (unsigned long long)__float2uint_rn(w4.w * FIX_SCALE));
  } else {
    for (int i = e; i < Ne; i++) {
      atomicAdd(&pk[row[i]], (1ULL << 40) | (unsigned long long)__float2uint_rn(w[i] * FIX_SCALE));
    }
  }
}

// unpack: cnt = pk>>40 ; deg = fix*2^-24 + 1 (self loop) ; dinv = rsqrt(deg)
__global__ void dinv_cnt_kernel(const unsigned long long* __restrict__ pk,
                                float* __restrict__ dinv, int* __restrict__ cnt) {
  int i = blockIdx.x * blockDim.x + threadIdx.x;
  if (i < Nn) {
    unsigned long long v = pk[i];
    cnt[i] = (int)(v >> 40);
    float deg = (float)(v & ((1ULL << 40) - 1)) * FIX_INV + 1.0f;  // + self-loop weight
    dinv[i] = (deg > 0.f) ? rsqrtf(fmaxf(deg, 1e-12f)) : 0.f;
  }
}

// ---------- multi-block exclusive scan (cnt[Nn] -> rowptr[Nn+1], off) ----------

__global__ __launch_bounds__(256)
void scan_phase1(const int* __restrict__ cnt, int* __restrict__ bsum) {
  __shared__ int s[256];
  int b = blockIdx.x, tid = threadIdx.x;
  int base = b * SCAN_TILE + tid * 4;
  int t = 0;
#pragma unroll
  for (int i = 0; i < 4; i++) {
    int idx = base + i;
    if (idx < Nn) t += cnt[idx];
  }
  s[tid] = t;
  __syncthreads();
  for (int st = 128; st > 0; st >>= 1) {
    if (tid < st) s[tid] += s[tid + st];
    __syncthreads();
  }
  if (tid == 0) bsum[b] = s[0];
}

__global__ __launch_bounds__(128)
void scan_phase2(int* __restrict__ bsum) {  // in-place exclusive scan, SCAN_NB <= 128
  __shared__ int s[128];
  int tid = threadIdx.x;
  int v = (tid < SCAN_NB) ? bsum[tid] : 0;
  s[tid] = v;
  __syncthreads();
  for (int st = 1; st < 128; st <<= 1) {
    int u = (tid >= st) ? s[tid - st] : 0;
    __syncthreads();
    s[tid] += u;
    __syncthreads();
  }
  if (tid < SCAN_NB) bsum[tid] = s[tid] - v;  // exclusive prefix
}

__global__ __launch_bounds__(256)
void scan_phase3(const int* __restrict__ cnt, const int* __restrict__ bsum,
                 int* __restrict__ rowptr, int* __restrict__ off) {
  __shared__ int s[256];
  int b = blockIdx.x, tid = threadIdx.x;
  int base = b * SCAN_TILE + tid * 4;
  int vals[4];
  int t = 0;
#pragma unroll
  for (int i = 0; i < 4; i++) {
    int idx = base + i;
    vals[i] = (idx < Nn) ? cnt[idx] : 0;
    t += vals[i];
  }
  s[tid] = t;
  __syncthreads();
  for (int st = 1; st < 256; st <<= 1) {
    int u = (tid >= st) ? s[tid - st] : 0;
    __syncthreads();
    s[tid] += u;
    __syncthreads();
  }
  int run = bsum[b] + s[tid] - t;  // exclusive prefix for this thread's 4 elems
#pragma unroll
  for (int i = 0; i < 4; i++) {
    int idx = base + i;
    if (idx < Nn) { rowptr[idx] = run; off[idx] = run; run += vals[i]; }
  }
  if (b == SCAN_NB - 1 && tid == 255) rowptr[Nn] = bsum[b] + s[255];
}

// CSR fill: interleaved {col, norm} -> single 8B scattered store per edge
__global__ __launch_bounds__(256)
void csr_fill_kernel(const int* __restrict__ row, const int* __restrict__ col,
                     const float* __restrict__ w, const float* __restrict__ dinv,
                     int* __restrict__ off, int2* __restrict__ edge_s) {
  int e = (blockIdx.x * blockDim.x + threadIdx.x) * 4;
  if (e + 4 <= Ne) {
    int4 r4 = *(const int4*)(row + e);
    int4 c4 = *(const int4*)(col + e);
    float4 w4 = *(const float4*)(w + e);
    {
      int p = atomicAdd(&off[r4.x], 1);
      edge_s[p] = make_int2(c4.x, __float_as_int(dinv[r4.x] * w4.x * dinv[c4.x]));
    }
    {
      int p = atomicAdd(&off[r4.y], 1);
      edge_s[p] = make_int2(c4.y, __float_as_int(dinv[r4.y] * w4.y * dinv[c4.y]));
    }
    {
      int p = atomicAdd(&off[r4.z], 1);
      edge_s[p] = make_int2(c4.z, __float_as_int(dinv[r4.z] * w4.z * dinv[c4.z]));
    }
    {
      int p = atomicAdd(&off[r4.w], 1);
      edge_s[p] = make_int2(c4.w, __float_as_int(dinv[r4.w] * w4.w * dinv[c4.w]));
    }
  } else {
    for (int i = e; i < Ne; i++) {
      int r = row[i], c = col[i];
      int p = atomicAdd(&off[r], 1);
      edge_s[p] = make_int2(c, __float_as_int(dinv[r] * w[i] * dinv[c]));
    }
  }
}

// ---------- FP32 tiled GEMM 64x64 (small Nc) with optional BN-fold (input) /
// ---------- replicated BN-stats (output):  C = [BN_in](A) @ W (+bias)(relu) ----------

__global__ __launch_bounds__(256)
void gemm_kernel(const float* __restrict__ A, const float* __restrict__ W,
                 const float* __restrict__ bias, float* __restrict__ C,
                 __half* __restrict__ Ch,
                 const float* __restrict__ in_stats, const float* __restrict__ in_g,
                 const float* __restrict__ in_beta, float* __restrict__ out_part,
                 int M, int K, int Nc, int relu) {
  constexpr int BM = 64, BN = 64, BK = 16;
  __shared__ float As[BK][BM + 4];
  __shared__ float Ws[BK][BN];
  __shared__ float bnsc[128], bnsh[128];
  int t = threadIdx.x;
  int tx = t & 15, ty = t >> 4;
  int row0 = blockIdx.y * BM, col0 = blockIdx.x * BN;
  if (in_stats) {
    for (int c = t; c < K; c += 256) {
      float m = in_stats[c] * (1.f / Nn);
      float var = in_stats[K + c] * (1.f / Nn) - m * m;
      float sc = rsqrtf(var + BN_EPS) * in_g[c];
      bnsc[c] = sc;
      bnsh[c] = in_beta[c] - m * sc;
    }
    __syncthreads();
  }
  float acc[4][4] = {};
  for (int k0 = 0; k0 < K; k0 += BK) {
    {
      int r = t >> 2;
      int kq = (t & 3) << 2;
      int grow = row0 + r;
      float4 a = make_float4(0.f, 0.f, 0.f, 0.f);
      if (grow < M) a = *(const float4*)(A + (size_t)grow * K + (k0 + kq));
      if (in_stats) {
        a.x = a.x * bnsc[k0 + kq + 0] + bnsh[k0 + kq + 0];
        a.y = a.y * bnsc[k0 + kq + 1] + bnsh[k0 + kq + 1];
        a.z = a.z * bnsc[k0 + kq + 2] + bnsh[k0 + kq + 2];
        a.w = a.w * bnsc[k0 + kq + 3] + bnsh[k0 + kq + 3];
      }
      As[kq + 0][r] = a.x; As[kq + 1][r] = a.y;
      As[kq + 2][r] = a.z; As[kq + 3][r] = a.w;
    }
    {
      int r = t >> 4;
      int c = (t & 15) << 2;
      int gc = col0 + c;
      float4 w4 = make_float4(0.f, 0.f, 0.f, 0.f);
      if (gc < Nc) w4 = *(const float4*)(W + (size_t)(k0 + r) * Nc + gc);
      Ws[r][c + 0] = w4.x; Ws[r][c + 1] = w4.y;
      Ws[r][c + 2] = w4.z; Ws[r][c + 3] = w4.w;
    }
    __syncthreads();
#pragma unroll
    for (int kk = 0; kk < BK; kk++) {
      float4 av = *(const float4*)&As[kk][ty << 2];
      float4 wv = *(const float4*)&Ws[kk][tx << 2];
      float a4[4] = {av.x, av.y, av.z, av.w};
      float w4[4] = {wv.x, wv.y, wv.z, wv.w};
#pragma unroll
      for (int i = 0; i < 4; i++)
#pragma unroll
        for (int j = 0; j < 4; j++)
          acc[i][j] += a4[i] * w4[j];
    }
    __syncthreads();
  }
  float cs[4] = {0.f, 0.f, 0.f, 0.f}, cq[4] = {0.f, 0.f, 0.f, 0.f};
#pragma unroll
  for (int i = 0; i < 4; i++) {
    int grow = row0 + (ty << 2) + i;
    if (grow >= M) continue;
    float v[4];
#pragma unroll
    for (int j = 0; j < 4; j++) {
      int gc = col0 + (tx << 2) + j;
      float vv = acc[i][j];
      if (bias && gc < Nc) vv += bias[gc];
      if (relu) vv = fmaxf(vv, 0.f);
      v[j] = vv;
      if (out_part) { cs[j] += vv; cq[j] += vv * vv; }
    }
    if (Ch) {
      __half2 h01 = __floats2half2_rn(v[0], v[1]);
      __half2 h23 = __floats2half2_rn(v[2], v[3]);
      __half2* p = (__half2*)(Ch + (size_t)grow * Nc + col0 + (tx << 2));
      p[0] = h01; p[1] = h23;
    } else {
#pragma unroll
      for (int j = 0; j < 4; j++) {
        int gc = col0 + (tx << 2) + j;
        if (gc < Nc) C[(size_t)grow * Nc + gc] = v[j];
      }
    }
  }
  if (out_part) {
    int cbase = tx << 2;
#pragma unroll
    for (int j = 0; j < 4; j++) { As[ty][cbase + j] = cs[j]; Ws[ty][cbase + j] = cq[j]; }
    __syncthreads();
    for (int st = 8; st > 0; st >>= 1) {
      if (ty < st) {
#pragma unroll
        for (int j = 0; j < 4; j++) {
          As[ty][cbase + j] += As[ty + st][cbase + j];
          Ws[ty][cbase + j] += Ws[ty + st][cbase + j];
        }
      }
      __syncthreads();
    }
    if (ty == 0) {
      float* dst = out_part + (blockIdx.y & (NCOPY - 1)) * CSTRIDE;
#pragma unroll
      for (int j = 0; j < 4; j++) {
        int gc = col0 + cbase + j;
        if (gc < Nc) {
          atomicAdd(&dst[gc], As[0][cbase + j]);
          atomicAdd(&dst[Nc + gc], Ws[0][cbase + j]);
        }
      }
    }
  }
}

// ---------- FP32 tiled GEMM 128x128, 8x8/thread (large GEMMs) ----------
// split-half register tile keeps all LDS reads at 16B/lane stride (conflict-free)

__global__ __launch_bounds__(256)
void gemm128_kernel(const float* __restrict__ A, const float* __restrict__ W,
                    const float* __restrict__ bias, float* __restrict__ C,
                    __half* __restrict__ Ch,
                    const float* __restrict__ in_stats, const float* __restrict__ in_g,
                    const float* __restrict__ in_beta, float* __restrict__ out_part,
                    int M, int K, int Nc, int relu) {
  constexpr int BM = 128, BN = 128, BK = 8;
  __shared__ float As[BK][BM + 4];
  __shared__ float Ws[BK][BN];
  __shared__ float bnsc[128], bnsh[128];
  __shared__ float red[16][BN + 4];
  int t = threadIdx.x;
  int tx = t & 15, ty = t >> 4;
  int row0 = blockIdx.y * BM, col0 = blockIdx.x * BN;
  if (in_stats) {
    for (int c = t; c < K; c += 256) {
      float m = in_stats[c] * (1.f / Nn);
      float var = in_stats[K + c] * (1.f / Nn) - m * m;
      float sc = rsqrtf(var + BN_EPS) * in_g[c];
      bnsc[c] = sc;
      bnsh[c] = in_beta[c] - m * sc;
    }
    __syncthreads();
  }
  float acc[8][8] = {};
  int ar = t >> 1;            // A stage: row 0..127
  int akq = (t & 1) * 4;      //          k 0 or 4
  int wr = t >> 5;            // W stage: k-row 0..7
  int wc = (t & 31) * 4;      //          col 0..124
  for (int k0 = 0; k0 < K; k0 += BK) {
    {
      int grow = row0 + ar;
      float4 a = make_float4(0.f, 0.f, 0.f, 0.f);
      if (grow < M) a = *(const float4*)(A + (size_t)grow * K + (k0 + akq));
      if (in_stats) {
        a.x = a.x * bnsc[k0 + akq + 0] + bnsh[k0 + akq + 0];
        a.y = a.y * bnsc[k0 + akq + 1] + bnsh[k0 + akq + 1];
        a.z = a.z * bnsc[k0 + akq + 2] + bnsh[k0 + akq + 2];
        a.w = a.w * bnsc[k0 + akq + 3] + bnsh[k0 + akq + 3];
      }
      As[akq + 0][ar] = a.x; As[akq + 1][ar] = a.y;
      As[akq + 2][ar] = a.z; As[akq + 3][ar] = a.w;
    }
    {
      float4 w4 = *(const float4*)(W + (size_t)(k0 + wr) * Nc + col0 + wc);
      Ws[wr][wc + 0] = w4.x; Ws[wr][wc + 1] = w4.y;
      Ws[wr][wc + 2] = w4.z; Ws[wr][wc + 3] = w4.w;
    }
    __syncthreads();
#pragma unroll
    for (int kk = 0; kk < BK; kk++) {
      float4 a0 = *(const float4*)&As[kk][tx * 0 + ty * 4];       // rows ty*4..+3
      float4 a1 = *(const float4*)&As[kk][64 + ty * 4];           // rows 64+ty*4..+3
      float4 w0 = *(const float4*)&Ws[kk][tx * 4];                // cols tx*4..+3
      float4 w1 = *(const float4*)&Ws[kk][64 + tx * 4];           // cols 64+tx*4..+3
      float av[8] = {a0.x, a0.y, a0.z, a0.w, a1.x, a1.y, a1.z, a1.w};
      float wv[8] = {w0.x, w0.y, w0.z, w0.w, w1.x, w1.y, w1.z, w1.w};
#pragma unroll
      for (int i = 0; i < 8; i++)
#pragma unroll
        for (int j = 0; j < 8; j++)
          acc[i][j] += av[i] * wv[j];
    }
    __syncthreads();
  }
  float cs[8] = {}, cq[8] = {};
#pragma unroll
  for (int i = 0; i < 8; i++) {
    int lr = (i < 4) ? (ty * 4 + i) : (64 + ty * 4 + i - 4);
    int grow = row0 + lr;
    if (grow >= M) continue;
    float v[8];
#pragma unroll
    for (int j = 0; j < 8; j++) {
      int lc = (j < 4) ? (tx * 4 + j) : (64 + tx * 4 + j - 4);
      int gc = col0 + lc;
      float vv = acc[i][j];
      if (bias) vv += bias[gc];
      if (relu) vv = fmaxf(vv, 0.f);
      v[j] = vv;
      if (out_part) { cs[j] += vv; cq[j] += vv * vv; }
    }
    if (Ch) {  // Nc multiple of 128, cols always in range
      __half2 h01 = __floats2half2_rn(v[0], v[1]);
      __half2 h23 = __floats2half2_rn(v[2], v[3]);
      __half2* p = (__half2*)(Ch + (size_t)grow * Nc + col0 + tx * 4);
      p[0] = h01; p[1] = h23;
      __half2 h45 = __floats2half2_rn(v[4], v[5]);
      __half2 h67 = __floats2half2_rn(v[6], v[7]);
      __half2* p2 = (__half2*)(Ch + (size_t)grow * Nc + col0 + 64 + tx * 4);
      p2[0] = h45; p2[1] = h67;
    } else {
      *(float4*)(C + (size_t)grow * Nc + col0 + tx * 4) = make_float4(v[0], v[1], v[2], v[3]);
      *(float4*)(C + (size_t)grow * Nc + col0 + 64 + tx * 4) = make_float4(v[4], v[5], v[6], v[7]);
    }
  }
  if (out_part) {
    float* dst = out_part + (blockIdx.y & (NCOPY - 1)) * CSTRIDE;
    // pass 1: column sums
    __syncthreads();
#pragma unroll
    for (int j = 0; j < 4; j++) {
      red[ty][tx * 4 + j] = cs[j];
      red[ty][64 + tx * 4 + j] = cs[4 + j];
    }
    __syncthreads();
    for (int st = 8; st > 0; st >>= 1) {
      if (ty < st) {
#pragma unroll
        for (int j = 0; j < 4; j++) {
          red[ty][tx * 4 + j] += red[ty + st][tx * 4 + j];
          red[ty][64 + tx * 4 + j] += red[ty + st][64 + tx * 4 + j];
        }
      }
      __syncthreads();
    }
    if (ty == 0) {
#pragma unroll
      for (int j = 0; j < 4; j++) {
        atomicAdd(&dst[col0 + tx * 4 + j], red[0][tx * 4 + j]);
        atomicAdd(&dst[col0 + 64 + tx * 4 + j], red[0][64 + tx * 4 + j]);
      }
    }
    __syncthreads();
    // pass 2: column sums of squares
#pragma unroll
    for (int j = 0; j < 4; j++) {
      red[ty][tx * 4 + j] = cq[j];
      red[ty][64 + tx * 4 + j] = cq[4 + j];
    }
    __syncthreads();
    for (int st = 8; st > 0; st >>= 1) {
      if (ty < st) {
#pragma unroll
        for (int j = 0; j < 4; j++) {
          red[ty][tx * 4 + j] += red[ty + st][tx * 4 + j];
          red[ty][64 + tx * 4 + j] += red[ty + st][64 + tx * 4 + j];
        }
      }
      __syncthreads();
    }
    if (ty == 0) {
#pragma unroll
      for (int j = 0; j < 4; j++) {
        atomicAdd(&dst[Nc + col0 + tx * 4 + j], red[0][tx * 4 + j]);
        atomicAdd(&dst[Nc + col0 + 64 + tx * 4 + j], red[0][64 + tx * 4 + j]);
      }
    }
  }
}

// ---------- gather SpMM (fp16 features, fp32 accumulate): one wave per node ----------

__global__ __launch_bounds__(256)
void gather64_kernel(const __half* __restrict__ t, const int* __restrict__ rowptr,
                     const int2* __restrict__ edge_s,
                     const float* __restrict__ dinv, const float* __restrict__ bias,
                     float* __restrict__ out, int relu) {
  int wave = threadIdx.x >> 6;
  int lane = threadIdx.x & 63;
  int node = blockIdx.x * 4 + wave;
  if (node >= Nn) return;
  int start = rowptr[node], end = rowptr[node + 1];
  float s = dinv[node];
  float acc = s * s * __half2float(t[(size_t)node * 64 + lane]);
  for (int base = start; base < end; base += 64) {
    int m = end - base; if (m > 64) m = 64;
    int cv = 0; float nv = 0.f;
    if (lane < m) {
      int2 ev = edge_s[base + lane];
      cv = ev.x; nv = __int_as_float(ev.y);
    }
    int k = 0;
    for (; k + 4 <= m; k += 4) {
      int c0 = __shfl(cv, k), c1 = __shfl(cv, k + 1);
      int c2 = __shfl(cv, k + 2), c3 = __shfl(cv, k + 3);
      float n0 = __shfl(nv, k), n1 = __shfl(nv, k + 1);
      float n2 = __shfl(nv, k + 2), n3 = __shfl(nv, k + 3);
      float t0 = __half2float(t[(size_t)c0 * 64 + lane]);
      float t1 = __half2float(t[(size_t)c1 * 64 + lane]);
      float t2 = __half2float(t[(size_t)c2 * 64 + lane]);
      float t3 = __half2float(t[(size_t)c3 * 64 + lane]);
      acc += n0 * t0; acc += n1 * t1; acc += n2 * t2; acc += n3 * t3;
    }
    for (; k < m; k++) {
      int c = __shfl(cv, k);
      float nm = __shfl(nv, k);
      acc += nm * __half2float(t[(size_t)c * 64 + lane]);
    }
  }
  acc += bias[lane];
  if (relu) acc = fmaxf(acc, 0.f);
  out[(size_t)node * 64 + lane] = acc;
}

__global__ __launch_bounds__(256)
void gather128_kernel(const __half* __restrict__ t, const int* __restrict__ rowptr,
                      const int2* __restrict__ edge_s,
                      const float* __restrict__ dinv, const float* __restrict__ bias,
                      float* __restrict__ out, int relu) {
  int wave = threadIdx.x >> 6;
  int lane = threadIdx.x & 63;
  int node = blockIdx.x * 4 + wave;
  if (node >= Nn) return;
  int start = rowptr[node], end = rowptr[node + 1];
  float s = dinv[node];
  const __half2* tp = (const __half2*)t;  // row stride = 64 half2
  float2 ti = __half22float2(tp[(size_t)node * 64 + lane]);
  float ax = s * s * ti.x, ay = s * s * ti.y;
  for (int base = start; base < end; base += 64) {
    int m = end - base; if (m > 64) m = 64;
    int cv = 0; float nv = 0.f;
    if (lane < m) {
      int2 ev = edge_s[base + lane];
      cv = ev.x; nv = __int_as_float(ev.y);
    }
    int k = 0;
    for (; k + 4 <= m; k += 4) {
      int c0 = __shfl(cv, k), c1 = __shfl(cv, k + 1);
      int c2 = __shfl(cv, k + 2), c3 = __shfl(cv, k + 3);
      float n0 = __shfl(nv, k), n1 = __shfl(nv, k + 1);
      float n2 = __shfl(nv, k + 2), n3 = __shfl(nv, k + 3);
      float2 t0 = __half22float2(tp[(size_t)c0 * 64 + lane]);
      float2 t1 = __half22float2(tp[(size_t)c1 * 64 + lane]);
      float2 t2 = __half22float2(tp[(size_t)c2 * 64 + lane]);
      float2 t3 = __half22float2(tp[(size_t)c3 * 64 + lane]);
      ax += n0 * t0.x; ay += n0 * t0.y;
      ax += n1 * t1.x; ay += n1 * t1.y;
      ax += n2 * t2.x; ay += n2 * t2.y;
      ax += n3 * t3.x; ay += n3 * t3.y;
    }
    for (; k < m; k++) {
      int c = __shfl(cv, k);
      float nm = __shfl(nv, k);
      float2 tv = __half22float2(tp[(size_t)c * 64 + lane]);
      ax += nm * tv.x; ay += nm * tv.y;
    }
  }
  float2 bb = ((const float2*)bias)[lane];
  ax += bb.x; ay += bb.y;
  if (relu) { ax = fmaxf(ax, 0.f); ay = fmaxf(ay, 0.f); }
  ((float2*)(out + (size_t)node * 128))[lane] = make_float2(ax, ay);
}

// ---------- BatchNorm apply (only for logvar head now) ----------

__global__ void bn_apply_kernel(float* __restrict__ x, float* __restrict__ dup,
                                const float* __restrict__ stats,
                                const float* __restrict__ g, const float* __restrict__ beta,
                                int total, int cmask, int C) {
  int i = blockIdx.x * blockDim.x + threadIdx.x;
  if (i >= total) return;
  int c = i & cmask;
  float m = stats[c] * (1.f / Nn);
  float var = stats[C + c] * (1.f / Nn) - m * m;
  float v = (x[i] - m) * rsqrtf(var + BN_EPS) * g[c] + beta[c];
  x[i] = v;
  if (dup) dup[i] = v;
}

// ---------- fused mu-BN + z copy + Student-t cluster assignment (two-pass, no scratch) ----------

__global__ __launch_bounds__(256)
void q_bn_kernel(const float* __restrict__ mu_raw, const float* __restrict__ stats,
                 const float* __restrict__ g, const float* __restrict__ beta,
                 const float* __restrict__ centers,
                 float* __restrict__ out_mu, float* __restrict__ out_z,
                 float* __restrict__ q) {
  __shared__ float cs[50 * 32];
  __shared__ float cn[50];
  __shared__ float sc[32], sh[32];
  int tid = threadIdx.x;
  for (int i = tid; i < 50 * 32; i += 256) cs[i] = centers[i];
  if (tid < 32) {
    float m = stats[tid] * (1.f / Nn);
    float var = stats[32 + tid] * (1.f / Nn) - m * m;
    float s = rsqrtf(var + BN_EPS) * g[tid];
    sc[tid] = s; sh[tid] = beta[tid] - m * s;
  }
  __syncthreads();
  if (tid < 50) {
    float s = 0.f;
    for (int j = 0; j < 32; j++) { float v = cs[tid * 32 + j]; s += v * v; }
    cn[tid] = s;
  }
  __syncthreads();
  int n = blockIdx.x * blockDim.x + tid;
  if (n >= Nn) return;
  float zr[32];
  float zn = 0.f;
  const float4* zp = (const float4*)(mu_raw + (size_t)n * 32);
  float4* mo = (float4*)(out_mu + (size_t)n * 32);
  float4* zo = (float4*)(out_z + (size_t)n * 32);
#pragma unroll
  for (int j = 0; j < 8; j++) {
    float4 v = zp[j];
    int c = j * 4;
    v.x = v.x * sc[c + 0] + sh[c + 0];
    v.y = v.y * sc[c + 1] + sh[c + 1];
    v.z = v.z * sc[c + 2] + sh[c + 2];
    v.w = v.w * sc[c + 3] + sh[c + 3];
    mo[j] = v; zo[j] = v;
    zr[c + 0] = v.x; zr[c + 1] = v.y; zr[c + 2] = v.z; zr[c + 3] = v.w;
    zn += v.x * v.x + v.y * v.y + v.z * v.z + v.w * v.w;
  }
  // pass 1: denominator only (no qv array -> no scratch)
  float qs = 0.f;
  for (int k = 0; k < 50; k++) {
    float dot = 0.f;
#pragma unroll
    for (int j = 0; j < 32; j++) dot += zr[j] * cs[k * 32 + j];
    float d2 = fmaxf(zn + cn[k] - 2.f * dot, 0.f);
    qs += 1.f / (1.f + d2);
  }
  float inv = 1.f / qs;
  // pass 2: recompute and store normalized
  float* qo = q + (size_t)n * 50;
  for (int k = 0; k < 50; k++) {
    float dot = 0.f;
#pragma unroll
    for (int j = 0; j < 32; j++) dot += zr[j] * cs[k * 32 + j];
    float d2 = fmaxf(zn + cn[k] - 2.f * dot, 0.f);
    qo[k] = inv / (1.f + d2);
  }
}

// ---------- launch ----------

extern "C" void kernel_launch(void* const* d_in, const int* in_sizes, int n_in,
                              void* d_out, int out_size, void* d_ws, size_t ws_size,
                              hipStream_t stream) {
  const float* x     = (const float*)d_in[0];
  const int*   ei    = (const int*)d_in[1];
  const float* ew    = (const float*)d_in[2];
  const float* W_g1  = (const float*)d_in[3];
  const float* b_g1  = (const float*)d_in[4];
  const float* W_g2  = (const float*)d_in[5];
  const float* b_g2  = (const float*)d_in[6];
  const float* W_g3  = (const float*)d_in[7];
  const float* b_g3  = (const float*)d_in[8];
  const float* W_mu  = (const float*)d_in[9];
  const float* b_mu  = (const float*)d_in[10];
  const float* W_lv  = (const float*)d_in[11];
  const float* b_lv  = (const float*)d_in[12];
  const float* g_mu  = (const float*)d_in[13];
  const float* be_mu = (const float*)d_in[14];
  const float* g_lv  = (const float*)d_in[15];
  const float* be_lv = (const float*)d_in[16];
  const float* W_d1  = (const float*)d_in[17];
  const float* b_d1  = (const float*)d_in[18];
  const float* g_d1  = (const float*)d_in[19];
  const float* be_d1 = (const float*)d_in[20];
  const float* W_d2  = (const float*)d_in[21];
  const float* b_d2  = (const float*)d_in[22];
  const float* g_d2  = (const float*)d_in[23];
  const float* be_d2 = (const float*)d_in[24];
  const float* W_d3  = (const float*)d_in[25];
  const float* b_d3  = (const float*)d_in[26];
  const float* cent  = (const float*)d_in[27];

  const int* row = ei;
  const int* col = ei + Ne;

  float* out    = (float*)d_out;
  float* out_z  = out;
  float* out_mu = out + (size_t)Nn * 32;
  float* out_lv = out + (size_t)Nn * 64;
  float* out_xr = out + (size_t)Nn * 96;   // [N,256]
  float* out_q  = out + (size_t)Nn * 352;  // [N,50]

  // workspace layout (~66 MB):
  // dinv[N] | bufB[N*128] | stats[512] | cnt[N] | rowptr[N+1] | off[N] | bsum[128] | pad | edge_s[E int2]
  // pk[N] (u64) aliases bufB (dead until first gather)
  float* ws     = (float*)d_ws;
  float* dinv   = ws;
  float* bufB   = dinv + Nn;
  float* stats  = bufB + (size_t)Nn * 128;
  int*   cnt    = (int*)(stats + 512);
  int*   rowptr = cnt + Nn;
  int*   off    = rowptr + Nn + 1;
  int*   bsum   = off + Nn;
  int2*  edge_s = (int2*)(bsum + 128 + 1);  // +1 pad keeps 8B alignment
  unsigned long long* pk = (unsigned long long*)bufB;  // aliased; dead before gather128 writes bufB
  float* st_mu = stats, *st_lv = stats + 64, *st_d1 = stats + 128, *st_d2 = stats + 256;

  // scratch in the x_recon output region (written last):
  __half* tA   = (__half*)out_xr;                    // layer1 t [N,128] fp16; reused layer3 t [N,64] fp16
  __half* tC   = (__half*)(out_xr + (size_t)Nn * 128); // layer2 t [N,64] fp16 (region later reused fp32)
  float* bufC  = out_xr + (size_t)Nn * 128;          // layer3 gather out [N,64] fp32 (after tC dead)
  float* bufD  = out_xr + (size_t)Nn * 192;          // [N,64] fp32
  // replicated stats partials: 2nd quarter of out_xr region — untouched by tA
  // (tA is only N*64 floats of halfs), dead until d3 writes out_xr at the end.
  float* stats_part = out_xr + (size_t)Nn * 64;      // NCOPY*CSTRIDE = 16K floats

  auto cdiv = [](long a, long b) { return (int)((a + b - 1) / b); };
  dim3 blk(256);

  // degree + histogram: single packed u64 atomic per edge
  izero_kernel<<<cdiv(2L * Nn, 256), blk, 0, stream>>>((int*)pk, 2 * Nn);
  fill_kernel<<<1, blk, 0, stream>>>(stats, 0.f, 512);
  fill_kernel<<<cdiv(NCOPY * CSTRIDE, 256), blk, 0, stream>>>(stats_part, 0.f, NCOPY * CSTRIDE);
  deg_pack_kernel<<<cdiv(Ne / 4, 256), blk, 0, stream>>>(row, ew, pk);
  dinv_cnt_kernel<<<cdiv(Nn, 256), blk, 0, stream>>>(pk, dinv, cnt);

  // CSR build: multi-block scan then fill
  scan_phase1<<<SCAN_NB, blk, 0, stream>>>(cnt, bsum);
  scan_phase2<<<1, 128, 0, stream>>>(bsum);
  scan_phase3<<<SCAN_NB, blk, 0, stream>>>(cnt, bsum, rowptr, off);
  csr_fill_kernel<<<cdiv(Ne / 4, 256), blk, 0, stream>>>(row, col, ew, dinv, off, edge_s);

  int ggrid = cdiv(Nn, 4);  // one wave per node, 4 waves/block

  // GCN layer 1: 256 -> 128 (t in fp16, 128x128 tile), aggregate, relu
  gemm128_kernel<<<dim3(1, cdiv(Nn, 128)), blk, 0, stream>>>(
      x, W_g1, nullptr, nullptr, tA, nullptr, nullptr, nullptr, nullptr, Nn, 256, 128, 0);
  gather128_kernel<<<ggrid, blk, 0, stream>>>(tA, rowptr, edge_s, dinv, b_g1, bufB, 1);

  // GCN layer 2: 128 -> 64 (t in fp16), aggregate, relu
  gemm_kernel<<<dim3(1, cdiv(Nn, 64)), blk, 0, stream>>>(
      bufB, W_g2, nullptr, nullptr, tC, nullptr, nullptr, nullptr, nullptr, Nn, 128, 64, 0);
  gather64_kernel<<<ggrid, blk, 0, stream>>>(tC, rowptr, edge_s, dinv, b_g2, bufD, 1);

  // GCN layer 3: 64 -> 64 (t in fp16), aggregate, no relu
  gemm_kernel<<<dim3(1, cdiv(Nn, 64)), blk, 0, stream>>>(
      bufD, W_g3, nullptr, nullptr, tA, nullptr, nullptr, nullptr, nullptr, Nn, 64, 64, 0);
  gather64_kernel<<<ggrid, blk, 0, stream>>>(tA, rowptr, edge_s, dinv, b_g3, bufC, 0);

  // VAE heads: 64 -> 32, partial stats fused into GEMM epilogue (replicated slots)
  gemm_kernel<<<dim3(1, cdiv(Nn, 64)), blk, 0, stream>>>(
      bufC, W_mu, b_mu, out_mu, nullptr, nullptr, nullptr, nullptr, stats_part, Nn, 64, 32, 0);
  gemm_kernel<<<dim3(1, cdiv(Nn, 64)), blk, 0, stream>>>(
      bufC, W_lv, b_lv, out_lv, nullptr, nullptr, nullptr, nullptr, stats_part + 64, Nn, 64, 32, 0);
  fold_stats_kernel<<<1, blk, 0, stream>>>(stats_part, stats, 128);  // mu+lv slices
  bn_apply_kernel<<<cdiv((long)Nn * 32, 256), blk, 0, stream>>>(
      out_lv, nullptr, st_lv, g_lv, be_lv, Nn * 32, 31, 32);

  // fused mu-BN + z + Student-t q (out_z needed by decoder below)
  q_bn_kernel<<<cdiv(Nn, 256), blk, 0, stream>>>(out_mu, st_mu, g_mu, be_mu, cent,
                                                 out_mu, out_z, out_q);

  // decoder 32 -> 64 -> 128 -> 256 with BN folded into following GEMM A-loads
  gemm_kernel<<<dim3(1, cdiv(Nn, 64)), blk, 0, stream>>>(
      out_z, W_d1, b_d1, bufD, nullptr, nullptr, nullptr, nullptr, stats_part + 128, Nn, 32, 64, 1);
  fold_stats_kernel<<<1, blk, 0, stream>>>(stats_part + 128, stats + 128, 128);  // d1 slice
  gemm128_kernel<<<dim3(1, cdiv(Nn, 128)), blk, 0, stream>>>(
      bufD, W_d2, b_d2, bufB, nullptr, st_d1, g_d1, be_d1, stats_part + 256, Nn, 64, 128, 1);
  fold_stats_kernel<<<1, blk, 0, stream>>>(stats_part + 256, stats + 256, 256);  // d2 slice
  gemm128_kernel<<<dim3(2, cdiv(Nn, 128)), blk, 0, stream>>>(
      bufB, W_d3, b_d3, out_xr, nullptr, st_d2, g_d2, be_d2, nullptr, Nn, 128, 256, 0);
}

// Round 5
// 869.302 us; speedup vs baseline: 1.5853x; 1.1501x over previous
//
#include <hip/hip_runtime.h>
#include <hip/hip_fp16.h>

constexpr int Nn = 100000;
constexpr int Ne = 1600000;
constexpr float BN_EPS = 1e-5f;

constexpr int SCAN_TILE = 1024;                          // elements per block
constexpr int SCAN_NB = (Nn + SCAN_TILE - 1) / SCAN_TILE; // 98

constexpr float FIX_SCALE = 16777216.f;       // 2^24
constexpr float FIX_INV = 1.f / 16777216.f;

constexpr int NCOPY = 32;        // replicated stats slots (anti-contention)
constexpr int CSTRIDE = 512;     // floats per slot

typedef _Float16 f16x8 __attribute__((ext_vector_type(8)));
typedef float f32x4 __attribute__((ext_vector_type(4)));

// ---------- small utility kernels ----------

__global__ void fill_kernel(float* __restrict__ p, float v, int n) {
  int i = blockIdx.x * blockDim.x + threadIdx.x;
  if (i < n) p[i] = v;
}

__global__ void izero_kernel(int* __restrict__ p, int n) {
  int i = blockIdx.x * blockDim.x + threadIdx.x;
  if (i < n) p[i] = 0;
}

// fold NCOPY replicated partial-stat slots into the final stats array
__global__ void fold_stats_kernel(const float* __restrict__ part, float* __restrict__ dst,
                                  int len) {
  int i = blockIdx.x * blockDim.x + threadIdx.x;
  if (i < len) {
    float s = 0.f;
#pragma unroll 8
    for (int k = 0; k < NCOPY; k++) s += part[k * CSTRIDE + i];
    dst[i] = s;
  }
}

// fused: one u64 atomic per edge packs {cnt:1 << 40 | fix24(w)}
__global__ __launch_bounds__(256)
void deg_pack_kernel(const int* __restrict__ row, const float* __restrict__ w,
                     unsigned long long* __restrict__ pk) {
  int e = (blockIdx.x * blockDim.x + threadIdx.x) * 4;
  if (e + 4 <= Ne) {
    int4 r4 = *(const int4*)(row + e);
    float4 w4 = *(const float4*)(w + e);
    atomicAdd(&pk[r4.x], (1ULL << 40) | (unsigned long long)__float2uint_rn(w4.x * FIX_SCALE));
    atomicAdd(&pk[r4.y], (1ULL << 40) | (unsigned long long)__float2uint_rn(w4.y * FIX_SCALE));
    atomicAdd(&pk[r4.z], (1ULL << 40) | (unsigned long long)__float2uint_rn(w4.z * FIX_SCALE));
    atomicAdd(&pk[r4.w], (1ULL << 40) | (unsigned long long)__float2uint_rn(w4.w * FIX_SCALE));
  } else {
    for (int i = e; i < Ne; i++) {
      atomicAdd(&pk[row[i]], (1ULL << 40) | (unsigned long long)__float2uint_rn(w[i] * FIX_SCALE));
    }
  }
}

// unpack: cnt = pk>>40 ; deg = fix*2^-24 + 1 (self loop) ; dinv = rsqrt(deg)
__global__ void dinv_cnt_kernel(const unsigned long long* __restrict__ pk,
                                float* __restrict__ dinv, int* __restrict__ cnt) {
  int i = blockIdx.x * blockDim.x + threadIdx.x;
  if (i < Nn) {
    unsigned long long v = pk[i];
    cnt[i] = (int)(v >> 40);
    float deg = (float)(v & ((1ULL << 40) - 1)) * FIX_INV + 1.0f;  // + self-loop weight
    dinv[i] = (deg > 0.f) ? rsqrtf(fmaxf(deg, 1e-12f)) : 0.f;
  }
}

// ---------- multi-block exclusive scan (cnt[Nn] -> rowptr[Nn+1], off) ----------

__global__ __launch_bounds__(256)
void scan_phase1(const int* __restrict__ cnt, int* __restrict__ bsum) {
  __shared__ int s[256];
  int b = blockIdx.x, tid = threadIdx.x;
  int base = b * SCAN_TILE + tid * 4;
  int t = 0;
#pragma unroll
  for (int i = 0; i < 4; i++) {
    int idx = base + i;
    if (idx < Nn) t += cnt[idx];
  }
  s[tid] = t;
  __syncthreads();
  for (int st = 128; st > 0; st >>= 1) {
    if (tid < st) s[tid] += s[tid + st];
    __syncthreads();
  }
  if (tid == 0) bsum[b] = s[0];
}

__global__ __launch_bounds__(128)
void scan_phase2(int* __restrict__ bsum) {  // in-place exclusive scan, SCAN_NB <= 128
  __shared__ int s[128];
  int tid = threadIdx.x;
  int v = (tid < SCAN_NB) ? bsum[tid] : 0;
  s[tid] = v;
  __syncthreads();
  for (int st = 1; st < 128; st <<= 1) {
    int u = (tid >= st) ? s[tid - st] : 0;
    __syncthreads();
    s[tid] += u;
    __syncthreads();
  }
  if (tid < SCAN_NB) bsum[tid] = s[tid] - v;  // exclusive prefix
}

__global__ __launch_bounds__(256)
void scan_phase3(const int* __restrict__ cnt, const int* __restrict__ bsum,
                 int* __restrict__ rowptr, int* __restrict__ off) {
  __shared__ int s[256];
  int b = blockIdx.x, tid = threadIdx.x;
  int base = b * SCAN_TILE + tid * 4;
  int vals[4];
  int t = 0;
#pragma unroll
  for (int i = 0; i < 4; i++) {
    int idx = base + i;
    vals[i] = (idx < Nn) ? cnt[idx] : 0;
    t += vals[i];
  }
  s[tid] = t;
  __syncthreads();
  for (int st = 1; st < 256; st <<= 1) {
    int u = (tid >= st) ? s[tid - st] : 0;
    __syncthreads();
    s[tid] += u;
    __syncthreads();
  }
  int run = bsum[b] + s[tid] - t;  // exclusive prefix for this thread's 4 elems
#pragma unroll
  for (int i = 0; i < 4; i++) {
    int idx = base + i;
    if (idx < Nn) { rowptr[idx] = run; off[idx] = run; run += vals[i]; }
  }
  if (b == SCAN_NB - 1 && tid == 255) rowptr[Nn] = bsum[b] + s[255];
}

// CSR fill: interleaved {col, norm} -> single 8B scattered store per edge
__global__ __launch_bounds__(256)
void csr_fill_kernel(const int* __restrict__ row, const int* __restrict__ col,
                     const float* __restrict__ w, const float* __restrict__ dinv,
                     int* __restrict__ off, int2* __restrict__ edge_s) {
  int e = (blockIdx.x * blockDim.x + threadIdx.x) * 4;
  if (e + 4 <= Ne) {
    int4 r4 = *(const int4*)(row + e);
    int4 c4 = *(const int4*)(col + e);
    float4 w4 = *(const float4*)(w + e);
    {
      int p = atomicAdd(&off[r4.x], 1);
      edge_s[p] = make_int2(c4.x, __float_as_int(dinv[r4.x] * w4.x * dinv[c4.x]));
    }
    {
      int p = atomicAdd(&off[r4.y], 1);
      edge_s[p] = make_int2(c4.y, __float_as_int(dinv[r4.y] * w4.y * dinv[c4.y]));
    }
    {
      int p = atomicAdd(&off[r4.z], 1);
      edge_s[p] = make_int2(c4.z, __float_as_int(dinv[r4.z] * w4.z * dinv[c4.z]));
    }
    {
      int p = atomicAdd(&off[r4.w], 1);
      edge_s[p] = make_int2(c4.w, __float_as_int(dinv[r4.w] * w4.w * dinv[c4.w]));
    }
  } else {
    for (int i = e; i < Ne; i++) {
      int r = row[i], c = col[i];
      int p = atomicAdd(&off[r], 1);
      edge_s[p] = make_int2(c, __float_as_int(dinv[r] * w[i] * dinv[c]));
    }
  }
}

// ---------- FP32 tiled GEMM 64x64 (small Nc: mu/lv heads) ----------

__global__ __launch_bounds__(256)
void gemm_kernel(const float* __restrict__ A, const float* __restrict__ W,
                 const float* __restrict__ bias, float* __restrict__ C,
                 __half* __restrict__ Ch,
                 const float* __restrict__ in_stats, const float* __restrict__ in_g,
                 const float* __restrict__ in_beta, float* __restrict__ out_part,
                 int M, int K, int Nc, int relu) {
  constexpr int BM = 64, BN = 64, BK = 16;
  __shared__ float As[BK][BM + 4];
  __shared__ float Ws[BK][BN];
  __shared__ float bnsc[128], bnsh[128];
  int t = threadIdx.x;
  int tx = t & 15, ty = t >> 4;
  int row0 = blockIdx.y * BM, col0 = blockIdx.x * BN;
  if (in_stats) {
    for (int c = t; c < K; c += 256) {
      float m = in_stats[c] * (1.f / Nn);
      float var = in_stats[K + c] * (1.f / Nn) - m * m;
      float sc = rsqrtf(var + BN_EPS) * in_g[c];
      bnsc[c] = sc;
      bnsh[c] = in_beta[c] - m * sc;
    }
    __syncthreads();
  }
  float acc[4][4] = {};
  for (int k0 = 0; k0 < K; k0 += BK) {
    {
      int r = t >> 2;
      int kq = (t & 3) << 2;
      int grow = row0 + r;
      float4 a = make_float4(0.f, 0.f, 0.f, 0.f);
      if (grow < M) a = *(const float4*)(A + (size_t)grow * K + (k0 + kq));
      if (in_stats) {
        a.x = a.x * bnsc[k0 + kq + 0] + bnsh[k0 + kq + 0];
        a.y = a.y * bnsc[k0 + kq + 1] + bnsh[k0 + kq + 1];
        a.z = a.z * bnsc[k0 + kq + 2] + bnsh[k0 + kq + 2];
        a.w = a.w * bnsc[k0 + kq + 3] + bnsh[k0 + kq + 3];
      }
      As[kq + 0][r] = a.x; As[kq + 1][r] = a.y;
      As[kq + 2][r] = a.z; As[kq + 3][r] = a.w;
    }
    {
      int r = t >> 4;
      int c = (t & 15) << 2;
      int gc = col0 + c;
      float4 w4 = make_float4(0.f, 0.f, 0.f, 0.f);
      if (gc < Nc) w4 = *(const float4*)(W + (size_t)(k0 + r) * Nc + gc);
      Ws[r][c + 0] = w4.x; Ws[r][c + 1] = w4.y;
      Ws[r][c + 2] = w4.z; Ws[r][c + 3] = w4.w;
    }
    __syncthreads();
#pragma unroll
    for (int kk = 0; kk < BK; kk++) {
      float4 av = *(const float4*)&As[kk][ty << 2];
      float4 wv = *(const float4*)&Ws[kk][tx << 2];
      float a4[4] = {av.x, av.y, av.z, av.w};
      float w4[4] = {wv.x, wv.y, wv.z, wv.w};
#pragma unroll
      for (int i = 0; i < 4; i++)
#pragma unroll
        for (int j = 0; j < 4; j++)
          acc[i][j] += a4[i] * w4[j];
    }
    __syncthreads();
  }
  float cs[4] = {0.f, 0.f, 0.f, 0.f}, cq[4] = {0.f, 0.f, 0.f, 0.f};
#pragma unroll
  for (int i = 0; i < 4; i++) {
    int grow = row0 + (ty << 2) + i;
    if (grow >= M) continue;
    float v[4];
#pragma unroll
    for (int j = 0; j < 4; j++) {
      int gc = col0 + (tx << 2) + j;
      float vv = acc[i][j];
      if (bias && gc < Nc) vv += bias[gc];
      if (relu) vv = fmaxf(vv, 0.f);
      v[j] = vv;
      if (out_part) { cs[j] += vv; cq[j] += vv * vv; }
    }
    if (Ch) {
      __half2 h01 = __floats2half2_rn(v[0], v[1]);
      __half2 h23 = __floats2half2_rn(v[2], v[3]);
      __half2* p = (__half2*)(Ch + (size_t)grow * Nc + col0 + (tx << 2));
      p[0] = h01; p[1] = h23;
    } else {
#pragma unroll
      for (int j = 0; j < 4; j++) {
        int gc = col0 + (tx << 2) + j;
        if (gc < Nc) C[(size_t)grow * Nc + gc] = v[j];
      }
    }
  }
  if (out_part) {
    int cbase = tx << 2;
#pragma unroll
    for (int j = 0; j < 4; j++) { As[ty][cbase + j] = cs[j]; Ws[ty][cbase + j] = cq[j]; }
    __syncthreads();
    for (int st = 8; st > 0; st >>= 1) {
      if (ty < st) {
#pragma unroll
        for (int j = 0; j < 4; j++) {
          As[ty][cbase + j] += As[ty + st][cbase + j];
          Ws[ty][cbase + j] += Ws[ty + st][cbase + j];
        }
      }
      __syncthreads();
    }
    if (ty == 0) {
      float* dst = out_part + (blockIdx.y & (NCOPY - 1)) * CSTRIDE;
#pragma unroll
      for (int j = 0; j < 4; j++) {
        int gc = col0 + cbase + j;
        if (gc < Nc) {
          atomicAdd(&dst[gc], As[0][cbase + j]);
          atomicAdd(&dst[Nc + gc], Ws[0][cbase + j]);
        }
      }
    }
  }
}

// ---------- MFMA f16 GEMM: BM=128 BN=64 BK=32, 4 waves, 2x4 frags of 16x16x32 ----------
// A fp32 -> fp16 staged in LDS (pad to 40 elems/row: 80B stride, 16B aligned,
// 2-way bank alias = free). W staged transposed. fp32 accumulate via MFMA.
// C/D layout (m89-verified): col = lane&15, row = (lane>>4)*4 + reg.

__global__ __launch_bounds__(256)
void gemm_mfma_kernel(const float* __restrict__ A, const float* __restrict__ W,
                      const float* __restrict__ bias, float* __restrict__ C,
                      __half* __restrict__ Ch,
                      const float* __restrict__ in_stats, const float* __restrict__ in_g,
                      const float* __restrict__ in_beta, float* __restrict__ out_part,
                      int M, int K, int Nc, int relu) {
  constexpr int BM = 128, BN = 64, BK = 32;
  constexpr int LDA = 40;  // fp16 elems/row incl pad
  __shared__ __half Asm[BM][LDA];
  __shared__ __half Wsm[BN][LDA];     // Wsm[col][k] (transposed tile)
  __shared__ float bnsc[256], bnsh[256];
  __shared__ float sred[2][4][BN];
  int t = threadIdx.x;
  int wid = t >> 6, lane = t & 63;
  int fr = lane & 15, fg = lane >> 4;
  int row0 = blockIdx.y * BM, col0 = blockIdx.x * BN;
  if (in_stats) {
    for (int c = t; c < K; c += 256) {
      float m = in_stats[c] * (1.f / Nn);
      float var = in_stats[K + c] * (1.f / Nn) - m * m;
      float sc = rsqrtf(var + BN_EPS) * in_g[c];
      bnsc[c] = sc;
      bnsh[c] = in_beta[c] - m * sc;
    }
    __syncthreads();
  }
  f32x4 acc[2][4] = {};
  int ar = t >> 1;             // A stage: row 0..127
  int ac = (t & 1) * 16;       //          k-chunk 0 or 16
  int wc = t >> 2;             // W stage: col 0..63
  int wk = (t & 3) * 8;        //          k-chunk 0/8/16/24
  for (int k0 = 0; k0 < K; k0 += BK) {
    {
      int grow = row0 + ar;
      float v[16];
      if (grow < M) {
        const float4* ap = (const float4*)(A + (size_t)grow * K + k0 + ac);
#pragma unroll
        for (int q = 0; q < 4; q++) {
          float4 a = ap[q];
          v[q * 4 + 0] = a.x; v[q * 4 + 1] = a.y;
          v[q * 4 + 2] = a.z; v[q * 4 + 3] = a.w;
        }
        if (in_stats) {
#pragma unroll
          for (int j = 0; j < 16; j++)
            v[j] = v[j] * bnsc[k0 + ac + j] + bnsh[k0 + ac + j];
        }
      } else {
#pragma unroll
        for (int j = 0; j < 16; j++) v[j] = 0.f;
      }
      union { __half2 h2[8]; uint4 u4[2]; } pk_;
#pragma unroll
      for (int j = 0; j < 8; j++) pk_.h2[j] = __floats2half2_rn(v[2 * j], v[2 * j + 1]);
      *(uint4*)&Asm[ar][ac] = pk_.u4[0];
      *(uint4*)&Asm[ar][ac + 8] = pk_.u4[1];
    }
    {
      int gc = col0 + wc;
      union { __half2 h2[4]; uint4 u4; } wpk;
#pragma unroll
      for (int j = 0; j < 4; j++) {
        float w0 = W[(size_t)(k0 + wk + 2 * j) * Nc + gc];
        float w1 = W[(size_t)(k0 + wk + 2 * j + 1) * Nc + gc];
        wpk.h2[j] = __floats2half2_rn(w0, w1);
      }
      *(uint4*)&Wsm[wc][wk] = wpk.u4;
    }
    __syncthreads();
    {
      f16x8 a0 = *(const f16x8*)&Asm[wid * 32 + fr][fg * 8];
      f16x8 a1 = *(const f16x8*)&Asm[wid * 32 + 16 + fr][fg * 8];
      f16x8 b0 = *(const f16x8*)&Wsm[fr][fg * 8];
      f16x8 b1 = *(const f16x8*)&Wsm[16 + fr][fg * 8];
      f16x8 b2 = *(const f16x8*)&Wsm[32 + fr][fg * 8];
      f16x8 b3 = *(const f16x8*)&Wsm[48 + fr][fg * 8];
      acc[0][0] = __builtin_amdgcn_mfma_f32_16x16x32_f16(a0, b0, acc[0][0], 0, 0, 0);
      acc[0][1] = __builtin_amdgcn_mfma_f32_16x16x32_f16(a0, b1, acc[0][1], 0, 0, 0);
      acc[0][2] = __builtin_amdgcn_mfma_f32_16x16x32_f16(a0, b2, acc[0][2], 0, 0, 0);
      acc[0][3] = __builtin_amdgcn_mfma_f32_16x16x32_f16(a0, b3, acc[0][3], 0, 0, 0);
      acc[1][0] = __builtin_amdgcn_mfma_f32_16x16x32_f16(a1, b0, acc[1][0], 0, 0, 0);
      acc[1][1] = __builtin_amdgcn_mfma_f32_16x16x32_f16(a1, b1, acc[1][1], 0, 0, 0);
      acc[1][2] = __builtin_amdgcn_mfma_f32_16x16x32_f16(a1, b2, acc[1][2], 0, 0, 0);
      acc[1][3] = __builtin_amdgcn_mfma_f32_16x16x32_f16(a1, b3, acc[1][3], 0, 0, 0);
    }
    __syncthreads();
  }
  // epilogue
  float csum[4] = {}, cssq[4] = {};
  float bv[4];
#pragma unroll
  for (int ni = 0; ni < 4; ni++) bv[ni] = bias ? bias[col0 + ni * 16 + fr] : 0.f;
#pragma unroll
  for (int mi = 0; mi < 2; mi++) {
#pragma unroll
    for (int ni = 0; ni < 4; ni++) {
      int col = col0 + ni * 16 + fr;
      f32x4 d = acc[mi][ni];
#pragma unroll
      for (int j = 0; j < 4; j++) {
        int r = row0 + wid * 32 + mi * 16 + fg * 4 + j;
        if (r >= M) continue;
        float vv = d[j] + bv[ni];
        if (relu) vv = fmaxf(vv, 0.f);
        if (out_part) { csum[ni] += vv; cssq[ni] += vv * vv; }
        if (Ch) Ch[(size_t)r * Nc + col] = __float2half(vv);
        else    C[(size_t)r * Nc + col] = vv;
      }
    }
  }
  if (out_part) {
#pragma unroll
    for (int ni = 0; ni < 4; ni++) {
      csum[ni] += __shfl_xor(csum[ni], 16); csum[ni] += __shfl_xor(csum[ni], 32);
      cssq[ni] += __shfl_xor(cssq[ni], 16); cssq[ni] += __shfl_xor(cssq[ni], 32);
    }
    if (fg == 0) {
#pragma unroll
      for (int ni = 0; ni < 4; ni++) {
        sred[0][wid][ni * 16 + fr] = csum[ni];
        sred[1][wid][ni * 16 + fr] = cssq[ni];
      }
    }
    __syncthreads();
    if (t < BN) {
      float s = sred[0][0][t] + sred[0][1][t] + sred[0][2][t] + sred[0][3][t];
      float q = sred[1][0][t] + sred[1][1][t] + sred[1][2][t] + sred[1][3][t];
      float* dst = out_part + (blockIdx.y & (NCOPY - 1)) * CSTRIDE;
      atomicAdd(&dst[col0 + t], s);
      atomicAdd(&dst[Nc + col0 + t], q);
    }
  }
}

// ---------- gather SpMM (fp16 features, fp32 accumulate): one wave per node ----------

__global__ __launch_bounds__(256)
void gather64_kernel(const __half* __restrict__ t, const int* __restrict__ rowptr,
                     const int2* __restrict__ edge_s,
                     const float* __restrict__ dinv, const float* __restrict__ bias,
                     float* __restrict__ out, int relu) {
  int wave = threadIdx.x >> 6;
  int lane = threadIdx.x & 63;
  int node = blockIdx.x * 4 + wave;
  if (node >= Nn) return;
  int start = rowptr[node], end = rowptr[node + 1];
  float s = dinv[node];
  float acc = s * s * __half2float(t[(size_t)node * 64 + lane]);
  for (int base = start; base < end; base += 64) {
    int m = end - base; if (m > 64) m = 64;
    int cv = 0; float nv = 0.f;
    if (lane < m) {
      int2 ev = edge_s[base + lane];
      cv = ev.x; nv = __int_as_float(ev.y);
    }
    int k = 0;
    for (; k + 4 <= m; k += 4) {
      int c0 = __shfl(cv, k), c1 = __shfl(cv, k + 1);
      int c2 = __shfl(cv, k + 2), c3 = __shfl(cv, k + 3);
      float n0 = __shfl(nv, k), n1 = __shfl(nv, k + 1);
      float n2 = __shfl(nv, k + 2), n3 = __shfl(nv, k + 3);
      float t0 = __half2float(t[(size_t)c0 * 64 + lane]);
      float t1 = __half2float(t[(size_t)c1 * 64 + lane]);
      float t2 = __half2float(t[(size_t)c2 * 64 + lane]);
      float t3 = __half2float(t[(size_t)c3 * 64 + lane]);
      acc += n0 * t0; acc += n1 * t1; acc += n2 * t2; acc += n3 * t3;
    }
    for (; k < m; k++) {
      int c = __shfl(cv, k);
      float nm = __shfl(nv, k);
      acc += nm * __half2float(t[(size_t)c * 64 + lane]);
    }
  }
  acc += bias[lane];
  if (relu) acc = fmaxf(acc, 0.f);
  out[(size_t)node * 64 + lane] = acc;
}

__global__ __launch_bounds__(256)
void gather128_kernel(const __half* __restrict__ t, const int* __restrict__ rowptr,
                      const int2* __restrict__ edge_s,
                      const float* __restrict__ dinv, const float* __restrict__ bias,
                      float* __restrict__ out, int relu) {
  int wave = threadIdx.x >> 6;
  int lane = threadIdx.x & 63;
  int node = blockIdx.x * 4 + wave;
  if (node >= Nn) return;
  int start = rowptr[node], end = rowptr[node + 1];
  float s = dinv[node];
  const __half2* tp = (const __half2*)t;  // row stride = 64 half2
  float2 ti = __half22float2(tp[(size_t)node * 64 + lane]);
  float ax = s * s * ti.x, ay = s * s * ti.y;
  for (int base = start; base < end; base += 64) {
    int m = end - base; if (m > 64) m = 64;
    int cv = 0; float nv = 0.f;
    if (lane < m) {
      int2 ev = edge_s[base + lane];
      cv = ev.x; nv = __int_as_float(ev.y);
    }
    int k = 0;
    for (; k + 4 <= m; k += 4) {
      int c0 = __shfl(cv, k), c1 = __shfl(cv, k + 1);
      int c2 = __shfl(cv, k + 2), c3 = __shfl(cv, k + 3);
      float n0 = __shfl(nv, k), n1 = __shfl(nv, k + 1);
      float n2 = __shfl(nv, k + 2), n3 = __shfl(nv, k + 3);
      float2 t0 = __half22float2(tp[(size_t)c0 * 64 + lane]);
      float2 t1 = __half22float2(tp[(size_t)c1 * 64 + lane]);
      float2 t2 = __half22float2(tp[(size_t)c2 * 64 + lane]);
      float2 t3 = __half22float2(tp[(size_t)c3 * 64 + lane]);
      ax += n0 * t0.x; ay += n0 * t0.y;
      ax += n1 * t1.x; ay += n1 * t1.y;
      ax += n2 * t2.x; ay += n2 * t2.y;
      ax += n3 * t3.x; ay += n3 * t3.y;
    }
    for (; k < m; k++) {
      int c = __shfl(cv, k);
      float nm = __shfl(nv, k);
      float2 tv = __half22float2(tp[(size_t)c * 64 + lane]);
      ax += nm * tv.x; ay += nm * tv.y;
    }
  }
  float2 bb = ((const float2*)bias)[lane];
  ax += bb.x; ay += bb.y;
  if (relu) { ax = fmaxf(ax, 0.f); ay = fmaxf(ay, 0.f); }
  ((float2*)(out + (size_t)node * 128))[lane] = make_float2(ax, ay);
}

// ---------- BatchNorm apply (only for logvar head now) ----------

__global__ void bn_apply_kernel(float* __restrict__ x, float* __restrict__ dup,
                                const float* __restrict__ stats,
                                const float* __restrict__ g, const float* __restrict__ beta,
                                int total, int cmask, int C) {
  int i = blockIdx.x * blockDim.x + threadIdx.x;
  if (i >= total) return;
  int c = i & cmask;
  float m = stats[c] * (1.f / Nn);
  float var = stats[C + c] * (1.f / Nn) - m * m;
  float v = (x[i] - m) * rsqrtf(var + BN_EPS) * g[c] + beta[c];
  x[i] = v;
  if (dup) dup[i] = v;
}

// ---------- fused mu-BN + z copy + Student-t cluster assignment (two-pass) ----------

__global__ __launch_bounds__(256)
void q_bn_kernel(const float* __restrict__ mu_raw, const float* __restrict__ stats,
                 const float* __restrict__ g, const float* __restrict__ beta,
                 const float* __restrict__ centers,
                 float* __restrict__ out_mu, float* __restrict__ out_z,
                 float* __restrict__ q) {
  __shared__ float cs[50 * 32];
  __shared__ float cn[50];
  __shared__ float sc[32], sh[32];
  int tid = threadIdx.x;
  for (int i = tid; i < 50 * 32; i += 256) cs[i] = centers[i];
  if (tid < 32) {
    float m = stats[tid] * (1.f / Nn);
    float var = stats[32 + tid] * (1.f / Nn) - m * m;
    float s = rsqrtf(var + BN_EPS) * g[tid];
    sc[tid] = s; sh[tid] = beta[tid] - m * s;
  }
  __syncthreads();
  if (tid < 50) {
    float s = 0.f;
    for (int j = 0; j < 32; j++) { float v = cs[tid * 32 + j]; s += v * v; }
    cn[tid] = s;
  }
  __syncthreads();
  int n = blockIdx.x * blockDim.x + tid;
  if (n >= Nn) return;
  float zr[32];
  float zn = 0.f;
  const float4* zp = (const float4*)(mu_raw + (size_t)n * 32);
  float4* mo = (float4*)(out_mu + (size_t)n * 32);
  float4* zo = (float4*)(out_z + (size_t)n * 32);
#pragma unroll
  for (int j = 0; j < 8; j++) {
    float4 v = zp[j];
    int c = j * 4;
    v.x = v.x * sc[c + 0] + sh[c + 0];
    v.y = v.y * sc[c + 1] + sh[c + 1];
    v.z = v.z * sc[c + 2] + sh[c + 2];
    v.w = v.w * sc[c + 3] + sh[c + 3];
    mo[j] = v; zo[j] = v;
    zr[c + 0] = v.x; zr[c + 1] = v.y; zr[c + 2] = v.z; zr[c + 3] = v.w;
    zn += v.x * v.x + v.y * v.y + v.z * v.z + v.w * v.w;
  }
  float qs = 0.f;
  for (int k = 0; k < 50; k++) {
    float dot = 0.f;
#pragma unroll
    for (int j = 0; j < 32; j++) dot += zr[j] * cs[k * 32 + j];
    float d2 = fmaxf(zn + cn[k] - 2.f * dot, 0.f);
    qs += 1.f / (1.f + d2);
  }
  float inv = 1.f / qs;
  float* qo = q + (size_t)n * 50;
  for (int k = 0; k < 50; k++) {
    float dot = 0.f;
#pragma unroll
    for (int j = 0; j < 32; j++) dot += zr[j] * cs[k * 32 + j];
    float d2 = fmaxf(zn + cn[k] - 2.f * dot, 0.f);
    qo[k] = inv / (1.f + d2);
  }
}

// ---------- launch ----------

extern "C" void kernel_launch(void* const* d_in, const int* in_sizes, int n_in,
                              void* d_out, int out_size, void* d_ws, size_t ws_size,
                              hipStream_t stream) {
  const float* x     = (const float*)d_in[0];
  const int*   ei    = (const int*)d_in[1];
  const float* ew    = (const float*)d_in[2];
  const float* W_g1  = (const float*)d_in[3];
  const float* b_g1  = (const float*)d_in[4];
  const float* W_g2  = (const float*)d_in[5];
  const float* b_g2  = (const float*)d_in[6];
  const float* W_g3  = (const float*)d_in[7];
  const float* b_g3  = (const float*)d_in[8];
  const float* W_mu  = (const float*)d_in[9];
  const float* b_mu  = (const float*)d_in[10];
  const float* W_lv  = (const float*)d_in[11];
  const float* b_lv  = (const float*)d_in[12];
  const float* g_mu  = (const float*)d_in[13];
  const float* be_mu = (const float*)d_in[14];
  const float* g_lv  = (const float*)d_in[15];
  const float* be_lv = (const float*)d_in[16];
  const float* W_d1  = (const float*)d_in[17];
  const float* b_d1  = (const float*)d_in[18];
  const float* g_d1  = (const float*)d_in[19];
  const float* be_d1 = (const float*)d_in[20];
  const float* W_d2  = (const float*)d_in[21];
  const float* b_d2  = (const float*)d_in[22];
  const float* g_d2  = (const float*)d_in[23];
  const float* be_d2 = (const float*)d_in[24];
  const float* W_d3  = (const float*)d_in[25];
  const float* b_d3  = (const float*)d_in[26];
  const float* cent  = (const float*)d_in[27];

  const int* row = ei;
  const int* col = ei + Ne;

  float* out    = (float*)d_out;
  float* out_z  = out;
  float* out_mu = out + (size_t)Nn * 32;
  float* out_lv = out + (size_t)Nn * 64;
  float* out_xr = out + (size_t)Nn * 96;   // [N,256]
  float* out_q  = out + (size_t)Nn * 352;  // [N,50]

  float* ws     = (float*)d_ws;
  float* dinv   = ws;
  float* bufB   = dinv + Nn;
  float* stats  = bufB + (size_t)Nn * 128;
  int*   cnt    = (int*)(stats + 512);
  int*   rowptr = cnt + Nn;
  int*   off    = rowptr + Nn + 1;
  int*   bsum   = off + Nn;
  int2*  edge_s = (int2*)(bsum + 128 + 1);
  unsigned long long* pk = (unsigned long long*)bufB;
  float* st_mu = stats, *st_lv = stats + 64, *st_d1 = stats + 128, *st_d2 = stats + 256;

  __half* tA   = (__half*)out_xr;                      // layer1/3 fp16 t
  __half* tC   = (__half*)(out_xr + (size_t)Nn * 128); // layer2 fp16 t
  float* bufC  = out_xr + (size_t)Nn * 128;            // layer3 gather out fp32
  float* bufD  = out_xr + (size_t)Nn * 192;            // [N,64] fp32
  float* stats_part = out_xr + (size_t)Nn * 64;        // NCOPY*CSTRIDE floats

  auto cdiv = [](long a, long b) { return (int)((a + b - 1) / b); };
  dim3 blk(256);

  izero_kernel<<<cdiv(2L * Nn, 256), blk, 0, stream>>>((int*)pk, 2 * Nn);
  fill_kernel<<<1, blk, 0, stream>>>(stats, 0.f, 512);
  fill_kernel<<<cdiv(NCOPY * CSTRIDE, 256), blk, 0, stream>>>(stats_part, 0.f, NCOPY * CSTRIDE);
  deg_pack_kernel<<<cdiv(Ne / 4, 256), blk, 0, stream>>>(row, ew, pk);
  dinv_cnt_kernel<<<cdiv(Nn, 256), blk, 0, stream>>>(pk, dinv, cnt);

  scan_phase1<<<SCAN_NB, blk, 0, stream>>>(cnt, bsum);
  scan_phase2<<<1, 128, 0, stream>>>(bsum);
  scan_phase3<<<SCAN_NB, blk, 0, stream>>>(cnt, bsum, rowptr, off);
  csr_fill_kernel<<<cdiv(Ne / 4, 256), blk, 0, stream>>>(row, col, ew, dinv, off, edge_s);

  int ggrid = cdiv(Nn, 4);
  int gy = cdiv(Nn, 128);  // 782

  // GCN layer 1: 256 -> 128 (MFMA, fp16 out), aggregate+relu
  gemm_mfma_kernel<<<dim3(2, gy), blk, 0, stream>>>(
      x, W_g1, nullptr, nullptr, tA, nullptr, nullptr, nullptr, nullptr, Nn, 256, 128, 0);
  gather128_kernel<<<ggrid, blk, 0, stream>>>(tA, rowptr, edge_s, dinv, b_g1, bufB, 1);

  // GCN layer 2: 128 -> 64 (MFMA, fp16 out), aggregate+relu
  gemm_mfma_kernel<<<dim3(1, gy), blk, 0, stream>>>(
      bufB, W_g2, nullptr, nullptr, tC, nullptr, nullptr, nullptr, nullptr, Nn, 128, 64, 0);
  gather64_kernel<<<ggrid, blk, 0, stream>>>(tC, rowptr, edge_s, dinv, b_g2, bufD, 1);

  // GCN layer 3: 64 -> 64 (MFMA, fp16 out), aggregate
  gemm_mfma_kernel<<<dim3(1, gy), blk, 0, stream>>>(
      bufD, W_g3, nullptr, nullptr, tA, nullptr, nullptr, nullptr, nullptr, Nn, 64, 64, 0);
  gather64_kernel<<<ggrid, blk, 0, stream>>>(tA, rowptr, edge_s, dinv, b_g3, bufC, 0);

  // VAE heads: 64 -> 32 (fp32 64x64 kernel), stats in epilogue
  gemm_kernel<<<dim3(1, cdiv(Nn, 64)), blk, 0, stream>>>(
      bufC, W_mu, b_mu, out_mu, nullptr, nullptr, nullptr, nullptr, stats_part, Nn, 64, 32, 0);
  gemm_kernel<<<dim3(1, cdiv(Nn, 64)), blk, 0, stream>>>(
      bufC, W_lv, b_lv, out_lv, nullptr, nullptr, nullptr, nullptr, stats_part + 64, Nn, 64, 32, 0);
  fold_stats_kernel<<<1, blk, 0, stream>>>(stats_part, stats, 128);
  bn_apply_kernel<<<cdiv((long)Nn * 32, 256), blk, 0, stream>>>(
      out_lv, nullptr, st_lv, g_lv, be_lv, Nn * 32, 31, 32);

  q_bn_kernel<<<cdiv(Nn, 256), blk, 0, stream>>>(out_mu, st_mu, g_mu, be_mu, cent,
                                                 out_mu, out_z, out_q);

  // decoder 32 -> 64 -> 128 -> 256 (MFMA) with BN folded into A-loads
  gemm_mfma_kernel<<<dim3(1, gy), blk, 0, stream>>>(
      out_z, W_d1, b_d1, bufD, nullptr, nullptr, nullptr, nullptr, stats_part + 128, Nn, 32, 64, 1);
  fold_stats_kernel<<<1, blk, 0, stream>>>(stats_part + 128, stats + 128, 128);
  gemm_mfma_kernel<<<dim3(2, gy), blk, 0, stream>>>(
      bufD, W_d2, b_d2, bufB, nullptr, st_d1, g_d1, be_d1, stats_part + 256, Nn, 64, 128, 1);
  fold_stats_kernel<<<1, blk, 0, stream>>>(stats_part + 256, stats + 256, 256);
  gemm_mfma_kernel<<<dim3(4, gy), blk, 0, stream>>>(
      bufB, W_d3, b_d3, out_xr, nullptr, st_d2, g_d2, be_d2, nullptr, Nn, 128, 256, 0);
}

// Round 6
// 825.888 us; speedup vs baseline: 1.6687x; 1.0526x over previous
//
#include <hip/hip_runtime.h>
#include <hip/hip_fp16.h>

constexpr int Nn = 100000;
constexpr int Ne = 1600000;
constexpr float BN_EPS = 1e-5f;

constexpr int SCAN_TILE = 1024;                          // elements per block
constexpr int SCAN_NB = (Nn + SCAN_TILE - 1) / SCAN_TILE; // 98

constexpr float FIX_SCALE = 16777216.f;       // 2^24
constexpr float FIX_INV = 1.f / 16777216.f;

constexpr int NCOPY = 32;        // replicated stats slots (anti-contention)
constexpr int CSTRIDE = 512;     // floats per slot

typedef _Float16 f16x8 __attribute__((ext_vector_type(8)));
typedef float f32x4 __attribute__((ext_vector_type(4)));

// ---------- small utility kernels ----------

__global__ void fill_kernel(float* __restrict__ p, float v, int n) {
  int i = blockIdx.x * blockDim.x + threadIdx.x;
  if (i < n) p[i] = v;
}

__global__ void izero_kernel(int* __restrict__ p, int n) {
  int i = blockIdx.x * blockDim.x + threadIdx.x;
  if (i < n) p[i] = 0;
}

// fold NCOPY replicated partial-stat slots into the final stats array
__global__ void fold_stats_kernel(const float* __restrict__ part, float* __restrict__ dst,
                                  int len) {
  int i = blockIdx.x * blockDim.x + threadIdx.x;
  if (i < len) {
    float s = 0.f;
#pragma unroll 8
    for (int k = 0; k < NCOPY; k++) s += part[k * CSTRIDE + i];
    dst[i] = s;
  }
}

// fused: one u64 atomic per edge packs {cnt:1 << 40 | fix24(w)}
__global__ __launch_bounds__(256)
void deg_pack_kernel(const int* __restrict__ row, const float* __restrict__ w,
                     unsigned long long* __restrict__ pk) {
  int e = (blockIdx.x * blockDim.x + threadIdx.x) * 4;
  if (e + 4 <= Ne) {
    int4 r4 = *(const int4*)(row + e);
    float4 w4 = *(const float4*)(w + e);
    atomicAdd(&pk[r4.x], (1ULL << 40) | (unsigned long long)__float2uint_rn(w4.x * FIX_SCALE));
    atomicAdd(&pk[r4.y], (1ULL << 40) | (unsigned long long)__float2uint_rn(w4.y * FIX_SCALE));
    atomicAdd(&pk[r4.z], (1ULL << 40) | (unsigned long long)__float2uint_rn(w4.z * FIX_SCALE));
    atomicAdd(&pk[r4.w], (1ULL << 40) | (unsigned long long)__float2uint_rn(w4.w * FIX_SCALE));
  } else {
    for (int i = e; i < Ne; i++) {
      atomicAdd(&pk[row[i]], (1ULL << 40) | (unsigned long long)__float2uint_rn(w[i] * FIX_SCALE));
    }
  }
}

// ---------- multi-block exclusive scan over pk counts -> rowptr/off + dinv ----------

__global__ __launch_bounds__(256)
void scan_phase1(const unsigned long long* __restrict__ pk, int* __restrict__ bsum) {
  __shared__ int s[256];
  int b = blockIdx.x, tid = threadIdx.x;
  int base = b * SCAN_TILE + tid * 4;
  int t = 0;
#pragma unroll
  for (int i = 0; i < 4; i++) {
    int idx = base + i;
    if (idx < Nn) t += (int)(pk[idx] >> 40);
  }
  s[tid] = t;
  __syncthreads();
  for (int st = 128; st > 0; st >>= 1) {
    if (tid < st) s[tid] += s[tid + st];
    __syncthreads();
  }
  if (tid == 0) bsum[b] = s[0];
}

__global__ __launch_bounds__(128)
void scan_phase2(int* __restrict__ bsum) {  // in-place exclusive scan, SCAN_NB <= 128
  __shared__ int s[128];
  int tid = threadIdx.x;
  int v = (tid < SCAN_NB) ? bsum[tid] : 0;
  s[tid] = v;
  __syncthreads();
  for (int st = 1; st < 128; st <<= 1) {
    int u = (tid >= st) ? s[tid - st] : 0;
    __syncthreads();
    s[tid] += u;
    __syncthreads();
  }
  if (tid < SCAN_NB) bsum[tid] = s[tid] - v;  // exclusive prefix
}

__global__ __launch_bounds__(256)
void scan_phase3(const unsigned long long* __restrict__ pk, const int* __restrict__ bsum,
                 int* __restrict__ rowptr, int* __restrict__ off,
                 float* __restrict__ dinv) {
  __shared__ int s[256];
  int b = blockIdx.x, tid = threadIdx.x;
  int base = b * SCAN_TILE + tid * 4;
  int vals[4];
  int t = 0;
#pragma unroll
  for (int i = 0; i < 4; i++) {
    int idx = base + i;
    if (idx < Nn) {
      unsigned long long v = pk[idx];
      vals[i] = (int)(v >> 40);
      float deg = (float)(v & ((1ULL << 40) - 1)) * FIX_INV + 1.0f;  // + self-loop
      dinv[idx] = rsqrtf(fmaxf(deg, 1e-12f));
    } else vals[i] = 0;
    t += vals[i];
  }
  s[tid] = t;
  __syncthreads();
  for (int st = 1; st < 256; st <<= 1) {
    int u = (tid >= st) ? s[tid - st] : 0;
    __syncthreads();
    s[tid] += u;
    __syncthreads();
  }
  int run = bsum[b] + s[tid] - t;  // exclusive prefix for this thread's 4 elems
#pragma unroll
  for (int i = 0; i < 4; i++) {
    int idx = base + i;
    if (idx < Nn) { rowptr[idx] = run; off[idx] = run; run += vals[i]; }
  }
  if (b == SCAN_NB - 1 && tid == 255) rowptr[Nn] = bsum[b] + s[255];
}

// CSR fill: interleaved {col, norm} -> single 8B scattered store per edge
__global__ __launch_bounds__(256)
void csr_fill_kernel(const int* __restrict__ row, const int* __restrict__ col,
                     const float* __restrict__ w, const float* __restrict__ dinv,
                     int* __restrict__ off, int2* __restrict__ edge_s) {
  int e = (blockIdx.x * blockDim.x + threadIdx.x) * 4;
  if (e + 4 <= Ne) {
    int4 r4 = *(const int4*)(row + e);
    int4 c4 = *(const int4*)(col + e);
    float4 w4 = *(const float4*)(w + e);
    {
      int p = atomicAdd(&off[r4.x], 1);
      edge_s[p] = make_int2(c4.x, __float_as_int(dinv[r4.x] * w4.x * dinv[c4.x]));
    }
    {
      int p = atomicAdd(&off[r4.y], 1);
      edge_s[p] = make_int2(c4.y, __float_as_int(dinv[r4.y] * w4.y * dinv[c4.y]));
    }
    {
      int p = atomicAdd(&off[r4.z], 1);
      edge_s[p] = make_int2(c4.z, __float_as_int(dinv[r4.z] * w4.z * dinv[c4.z]));
    }
    {
      int p = atomicAdd(&off[r4.w], 1);
      edge_s[p] = make_int2(c4.w, __float_as_int(dinv[r4.w] * w4.w * dinv[c4.w]));
    }
  } else {
    for (int i = e; i < Ne; i++) {
      int r = row[i], c = col[i];
      int p = atomicAdd(&off[r], 1);
      edge_s[p] = make_int2(c, __float_as_int(dinv[r] * w[i] * dinv[c]));
    }
  }
}

// ---------- FP32 tiled GEMM 64x64 (small Nc: mu/lv heads) ----------

__global__ __launch_bounds__(256)
void gemm_kernel(const float* __restrict__ A, const float* __restrict__ W,
                 const float* __restrict__ bias, float* __restrict__ C,
                 __half* __restrict__ Ch,
                 const float* __restrict__ in_stats, const float* __restrict__ in_g,
                 const float* __restrict__ in_beta, float* __restrict__ out_part,
                 int M, int K, int Nc, int relu) {
  constexpr int BM = 64, BN = 64, BK = 16;
  __shared__ float As[BK][BM + 4];
  __shared__ float Ws[BK][BN];
  __shared__ float bnsc[128], bnsh[128];
  int t = threadIdx.x;
  int tx = t & 15, ty = t >> 4;
  int row0 = blockIdx.y * BM, col0 = blockIdx.x * BN;
  if (in_stats) {
    for (int c = t; c < K; c += 256) {
      float m = in_stats[c] * (1.f / Nn);
      float var = in_stats[K + c] * (1.f / Nn) - m * m;
      float sc = rsqrtf(var + BN_EPS) * in_g[c];
      bnsc[c] = sc;
      bnsh[c] = in_beta[c] - m * sc;
    }
    __syncthreads();
  }
  float acc[4][4] = {};
  for (int k0 = 0; k0 < K; k0 += BK) {
    {
      int r = t >> 2;
      int kq = (t & 3) << 2;
      int grow = row0 + r;
      float4 a = make_float4(0.f, 0.f, 0.f, 0.f);
      if (grow < M) a = *(const float4*)(A + (size_t)grow * K + (k0 + kq));
      if (in_stats) {
        a.x = a.x * bnsc[k0 + kq + 0] + bnsh[k0 + kq + 0];
        a.y = a.y * bnsc[k0 + kq + 1] + bnsh[k0 + kq + 1];
        a.z = a.z * bnsc[k0 + kq + 2] + bnsh[k0 + kq + 2];
        a.w = a.w * bnsc[k0 + kq + 3] + bnsh[k0 + kq + 3];
      }
      As[kq + 0][r] = a.x; As[kq + 1][r] = a.y;
      As[kq + 2][r] = a.z; As[kq + 3][r] = a.w;
    }
    {
      int r = t >> 4;
      int c = (t & 15) << 2;
      int gc = col0 + c;
      float4 w4 = make_float4(0.f, 0.f, 0.f, 0.f);
      if (gc < Nc) w4 = *(const float4*)(W + (size_t)(k0 + r) * Nc + gc);
      Ws[r][c + 0] = w4.x; Ws[r][c + 1] = w4.y;
      Ws[r][c + 2] = w4.z; Ws[r][c + 3] = w4.w;
    }
    __syncthreads();
#pragma unroll
    for (int kk = 0; kk < BK; kk++) {
      float4 av = *(const float4*)&As[kk][ty << 2];
      float4 wv = *(const float4*)&Ws[kk][tx << 2];
      float a4[4] = {av.x, av.y, av.z, av.w};
      float w4[4] = {wv.x, wv.y, wv.z, wv.w};
#pragma unroll
      for (int i = 0; i < 4; i++)
#pragma unroll
        for (int j = 0; j < 4; j++)
          acc[i][j] += a4[i] * w4[j];
    }
    __syncthreads();
  }
  float cs[4] = {0.f, 0.f, 0.f, 0.f}, cq[4] = {0.f, 0.f, 0.f, 0.f};
#pragma unroll
  for (int i = 0; i < 4; i++) {
    int grow = row0 + (ty << 2) + i;
    if (grow >= M) continue;
    float v[4];
#pragma unroll
    for (int j = 0; j < 4; j++) {
      int gc = col0 + (tx << 2) + j;
      float vv = acc[i][j];
      if (bias && gc < Nc) vv += bias[gc];
      if (relu) vv = fmaxf(vv, 0.f);
      v[j] = vv;
      if (out_part) { cs[j] += vv; cq[j] += vv * vv; }
    }
    if (Ch) {
      __half2 h01 = __floats2half2_rn(v[0], v[1]);
      __half2 h23 = __floats2half2_rn(v[2], v[3]);
      __half2* p = (__half2*)(Ch + (size_t)grow * Nc + col0 + (tx << 2));
      p[0] = h01; p[1] = h23;
    } else {
#pragma unroll
      for (int j = 0; j < 4; j++) {
        int gc = col0 + (tx << 2) + j;
        if (gc < Nc) C[(size_t)grow * Nc + gc] = v[j];
      }
    }
  }
  if (out_part) {
    int cbase = tx << 2;
#pragma unroll
    for (int j = 0; j < 4; j++) { As[ty][cbase + j] = cs[j]; Ws[ty][cbase + j] = cq[j]; }
    __syncthreads();
    for (int st = 8; st > 0; st >>= 1) {
      if (ty < st) {
#pragma unroll
        for (int j = 0; j < 4; j++) {
          As[ty][cbase + j] += As[ty + st][cbase + j];
          Ws[ty][cbase + j] += Ws[ty + st][cbase + j];
        }
      }
      __syncthreads();
    }
    if (ty == 0) {
      float* dst = out_part + (blockIdx.y & (NCOPY - 1)) * CSTRIDE;
#pragma unroll
      for (int j = 0; j < 4; j++) {
        int gc = col0 + cbase + j;
        if (gc < Nc) {
          atomicAdd(&dst[gc], As[0][cbase + j]);
          atomicAdd(&dst[Nc + gc], Ws[0][cbase + j]);
        }
      }
    }
  }
}

// ---------- MFMA f16 GEMM: BM=128 BN=64 BK=32, 4 waves, 2x4 frags of 16x16x32 ----------
// A from fp32 (A) or fp16 (A16). LDS rows padded to 40 elems (80B stride).
// C/D layout (m89-verified): col = lane&15, row = (lane>>4)*4 + reg.

__global__ __launch_bounds__(256)
void gemm_mfma_kernel(const float* __restrict__ A, const __half* __restrict__ A16,
                      const float* __restrict__ W,
                      const float* __restrict__ bias, float* __restrict__ C,
                      __half* __restrict__ Ch,
                      const float* __restrict__ in_stats, const float* __restrict__ in_g,
                      const float* __restrict__ in_beta, float* __restrict__ out_part,
                      int M, int K, int Nc, int relu) {
  constexpr int BM = 128, BN = 64, BK = 32;
  constexpr int LDA = 40;  // fp16 elems/row incl pad
  __shared__ __half Asm[BM][LDA];
  __shared__ __half Wsm[BN][LDA];     // Wsm[col][k] (transposed tile)
  __shared__ float bnsc[256], bnsh[256];
  __shared__ float sred[2][4][BN];
  int t = threadIdx.x;
  int wid = t >> 6, lane = t & 63;
  int fr = lane & 15, fg = lane >> 4;
  int row0 = blockIdx.y * BM, col0 = blockIdx.x * BN;
  if (in_stats) {
    for (int c = t; c < K; c += 256) {
      float m = in_stats[c] * (1.f / Nn);
      float var = in_stats[K + c] * (1.f / Nn) - m * m;
      float sc = rsqrtf(var + BN_EPS) * in_g[c];
      bnsc[c] = sc;
      bnsh[c] = in_beta[c] - m * sc;
    }
    __syncthreads();
  }
  f32x4 acc[2][4] = {};
  int ar = t >> 1;             // A stage: row 0..127
  int ac = (t & 1) * 16;       //          k-chunk 0 or 16
  int wc = t >> 2;             // W stage: col 0..63
  int wk = (t & 3) * 8;        //          k-chunk 0/8/16/24
  for (int k0 = 0; k0 < K; k0 += BK) {
    {
      int grow = row0 + ar;
      float v[16];
      if (grow < M) {
        if (A16) {
          union { uint4 u[2]; __half h[16]; } raw;
          const uint4* ap = (const uint4*)(A16 + (size_t)grow * K + k0 + ac);
          raw.u[0] = ap[0]; raw.u[1] = ap[1];
#pragma unroll
          for (int j = 0; j < 16; j++) v[j] = __half2float(raw.h[j]);
        } else {
          const float4* ap = (const float4*)(A + (size_t)grow * K + k0 + ac);
#pragma unroll
          for (int q = 0; q < 4; q++) {
            float4 a = ap[q];
            v[q * 4 + 0] = a.x; v[q * 4 + 1] = a.y;
            v[q * 4 + 2] = a.z; v[q * 4 + 3] = a.w;
          }
        }
        if (in_stats) {
#pragma unroll
          for (int j = 0; j < 16; j++)
            v[j] = v[j] * bnsc[k0 + ac + j] + bnsh[k0 + ac + j];
        }
      } else {
#pragma unroll
        for (int j = 0; j < 16; j++) v[j] = 0.f;
      }
      union { __half2 h2[8]; uint4 u4[2]; } pk_;
#pragma unroll
      for (int j = 0; j < 8; j++) pk_.h2[j] = __floats2half2_rn(v[2 * j], v[2 * j + 1]);
      *(uint4*)&Asm[ar][ac] = pk_.u4[0];
      *(uint4*)&Asm[ar][ac + 8] = pk_.u4[1];
    }
    {
      int gc = col0 + wc;
      union { __half2 h2[4]; uint4 u4; } wpk;
#pragma unroll
      for (int j = 0; j < 4; j++) {
        float w0 = W[(size_t)(k0 + wk + 2 * j) * Nc + gc];
        float w1 = W[(size_t)(k0 + wk + 2 * j + 1) * Nc + gc];
        wpk.h2[j] = __floats2half2_rn(w0, w1);
      }
      *(uint4*)&Wsm[wc][wk] = wpk.u4;
    }
    __syncthreads();
    {
      f16x8 a0 = *(const f16x8*)&Asm[wid * 32 + fr][fg * 8];
      f16x8 a1 = *(const f16x8*)&Asm[wid * 32 + 16 + fr][fg * 8];
      f16x8 b0 = *(const f16x8*)&Wsm[fr][fg * 8];
      f16x8 b1 = *(const f16x8*)&Wsm[16 + fr][fg * 8];
      f16x8 b2 = *(const f16x8*)&Wsm[32 + fr][fg * 8];
      f16x8 b3 = *(const f16x8*)&Wsm[48 + fr][fg * 8];
      acc[0][0] = __builtin_amdgcn_mfma_f32_16x16x32_f16(a0, b0, acc[0][0], 0, 0, 0);
      acc[0][1] = __builtin_amdgcn_mfma_f32_16x16x32_f16(a0, b1, acc[0][1], 0, 0, 0);
      acc[0][2] = __builtin_amdgcn_mfma_f32_16x16x32_f16(a0, b2, acc[0][2], 0, 0, 0);
      acc[0][3] = __builtin_amdgcn_mfma_f32_16x16x32_f16(a0, b3, acc[0][3], 0, 0, 0);
      acc[1][0] = __builtin_amdgcn_mfma_f32_16x16x32_f16(a1, b0, acc[1][0], 0, 0, 0);
      acc[1][1] = __builtin_amdgcn_mfma_f32_16x16x32_f16(a1, b1, acc[1][1], 0, 0, 0);
      acc[1][2] = __builtin_amdgcn_mfma_f32_16x16x32_f16(a1, b2, acc[1][2], 0, 0, 0);
      acc[1][3] = __builtin_amdgcn_mfma_f32_16x16x32_f16(a1, b3, acc[1][3], 0, 0, 0);
    }
    __syncthreads();
  }
  // epilogue
  float csum[4] = {}, cssq[4] = {};
  float bv[4];
#pragma unroll
  for (int ni = 0; ni < 4; ni++) bv[ni] = bias ? bias[col0 + ni * 16 + fr] : 0.f;
#pragma unroll
  for (int mi = 0; mi < 2; mi++) {
#pragma unroll
    for (int ni = 0; ni < 4; ni++) {
      int col = col0 + ni * 16 + fr;
      f32x4 d = acc[mi][ni];
#pragma unroll
      for (int j = 0; j < 4; j++) {
        int r = row0 + wid * 32 + mi * 16 + fg * 4 + j;
        if (r >= M) continue;
        float vv = d[j] + bv[ni];
        if (relu) vv = fmaxf(vv, 0.f);
        if (out_part) { csum[ni] += vv; cssq[ni] += vv * vv; }
        if (Ch) Ch[(size_t)r * Nc + col] = __float2half(vv);
        else    C[(size_t)r * Nc + col] = vv;
      }
    }
  }
  if (out_part) {
#pragma unroll
    for (int ni = 0; ni < 4; ni++) {
      csum[ni] += __shfl_xor(csum[ni], 16); csum[ni] += __shfl_xor(csum[ni], 32);
      cssq[ni] += __shfl_xor(cssq[ni], 16); cssq[ni] += __shfl_xor(cssq[ni], 32);
    }
    if (fg == 0) {
#pragma unroll
      for (int ni = 0; ni < 4; ni++) {
        sred[0][wid][ni * 16 + fr] = csum[ni];
        sred[1][wid][ni * 16 + fr] = cssq[ni];
      }
    }
    __syncthreads();
    if (t < BN) {
      float s = sred[0][0][t] + sred[0][1][t] + sred[0][2][t] + sred[0][3][t];
      float q = sred[1][0][t] + sred[1][1][t] + sred[1][2][t] + sred[1][3][t];
      float* dst = out_part + (blockIdx.y & (NCOPY - 1)) * CSTRIDE;
      atomicAdd(&dst[col0 + t], s);
      atomicAdd(&dst[Nc + col0 + t], q);
    }
  }
}

// ---------- gather SpMM (fp16 features, fp32 accumulate) ----------

// 64-dim: 32 lanes per node (half2/lane), 2 nodes per wave, 8 loads in flight
__global__ __launch_bounds__(256)
void gather64_kernel(const __half* __restrict__ t, const int* __restrict__ rowptr,
                     const int2* __restrict__ edge_s,
                     const float* __restrict__ dinv, const float* __restrict__ bias,
                     float* __restrict__ out, __half* __restrict__ outh, int relu) {
  int sub = threadIdx.x >> 5;       // 8 sub-groups of 32 lanes
  int lane = threadIdx.x & 31;
  int node = blockIdx.x * 8 + sub;
  if (node >= Nn) return;
  int start = rowptr[node], end = rowptr[node + 1];
  float s = dinv[node];
  const __half2* tp = (const __half2*)t;  // row stride = 32 half2
  float2 ti = __half22float2(tp[(size_t)node * 32 + lane]);
  float ax = s * s * ti.x, ay = s * s * ti.y;
  for (int base = start; base < end; base += 32) {
    int m = end - base; if (m > 32) m = 32;
    int cv = 0; float nv = 0.f;
    if (lane < m) {
      int2 ev = edge_s[base + lane];
      cv = ev.x; nv = __int_as_float(ev.y);
    }
    int k = 0;
    for (; k + 8 <= m; k += 8) {
      int c0 = __shfl(cv, k + 0, 32), c1 = __shfl(cv, k + 1, 32);
      int c2 = __shfl(cv, k + 2, 32), c3 = __shfl(cv, k + 3, 32);
      int c4 = __shfl(cv, k + 4, 32), c5 = __shfl(cv, k + 5, 32);
      int c6 = __shfl(cv, k + 6, 32), c7 = __shfl(cv, k + 7, 32);
      float n0 = __shfl(nv, k + 0, 32), n1 = __shfl(nv, k + 1, 32);
      float n2 = __shfl(nv, k + 2, 32), n3 = __shfl(nv, k + 3, 32);
      float n4 = __shfl(nv, k + 4, 32), n5 = __shfl(nv, k + 5, 32);
      float n6 = __shfl(nv, k + 6, 32), n7 = __shfl(nv, k + 7, 32);
      float2 t0 = __half22float2(tp[(size_t)c0 * 32 + lane]);
      float2 t1 = __half22float2(tp[(size_t)c1 * 32 + lane]);
      float2 t2 = __half22float2(tp[(size_t)c2 * 32 + lane]);
      float2 t3 = __half22float2(tp[(size_t)c3 * 32 + lane]);
      float2 t4 = __half22float2(tp[(size_t)c4 * 32 + lane]);
      float2 t5 = __half22float2(tp[(size_t)c5 * 32 + lane]);
      float2 t6 = __half22float2(tp[(size_t)c6 * 32 + lane]);
      float2 t7 = __half22float2(tp[(size_t)c7 * 32 + lane]);
      ax += n0 * t0.x; ay += n0 * t0.y;  ax += n1 * t1.x; ay += n1 * t1.y;
      ax += n2 * t2.x; ay += n2 * t2.y;  ax += n3 * t3.x; ay += n3 * t3.y;
      ax += n4 * t4.x; ay += n4 * t4.y;  ax += n5 * t5.x; ay += n5 * t5.y;
      ax += n6 * t6.x; ay += n6 * t6.y;  ax += n7 * t7.x; ay += n7 * t7.y;
    }
    for (; k < m; k++) {
      int c = __shfl(cv, k, 32);
      float nm = __shfl(nv, k, 32);
      float2 tv = __half22float2(tp[(size_t)c * 32 + lane]);
      ax += nm * tv.x; ay += nm * tv.y;
    }
  }
  float2 bb = ((const float2*)bias)[lane];
  ax += bb.x; ay += bb.y;
  if (relu) { ax = fmaxf(ax, 0.f); ay = fmaxf(ay, 0.f); }
  if (outh) ((__half2*)outh)[(size_t)node * 32 + lane] = __floats2half2_rn(ax, ay);
  else      ((float2*)out)[(size_t)node * 32 + lane] = make_float2(ax, ay);
}

// 128-dim: 64 lanes per node (half2/lane), 8 loads in flight, fp16 out
__global__ __launch_bounds__(256)
void gather128_kernel(const __half* __restrict__ t, const int* __restrict__ rowptr,
                      const int2* __restrict__ edge_s,
                      const float* __restrict__ dinv, const float* __restrict__ bias,
                      __half* __restrict__ outh, int relu) {
  int wave = threadIdx.x >> 6;
  int lane = threadIdx.x & 63;
  int node = blockIdx.x * 4 + wave;
  if (node >= Nn) return;
  int start = rowptr[node], end = rowptr[node + 1];
  float s = dinv[node];
  const __half2* tp = (const __half2*)t;  // row stride = 64 half2
  float2 ti = __half22float2(tp[(size_t)node * 64 + lane]);
  float ax = s * s * ti.x, ay = s * s * ti.y;
  for (int base = start; base < end; base += 64) {
    int m = end - base; if (m > 64) m = 64;
    int cv = 0; float nv = 0.f;
    if (lane < m) {
      int2 ev = edge_s[base + lane];
      cv = ev.x; nv = __int_as_float(ev.y);
    }
    int k = 0;
    for (; k + 8 <= m; k += 8) {
      int c0 = __shfl(cv, k + 0), c1 = __shfl(cv, k + 1);
      int c2 = __shfl(cv, k + 2), c3 = __shfl(cv, k + 3);
      int c4 = __shfl(cv, k + 4), c5 = __shfl(cv, k + 5);
      int c6 = __shfl(cv, k + 6), c7 = __shfl(cv, k + 7);
      float n0 = __shfl(nv, k + 0), n1 = __shfl(nv, k + 1);
      float n2 = __shfl(nv, k + 2), n3 = __shfl(nv, k + 3);
      float n4 = __shfl(nv, k + 4), n5 = __shfl(nv, k + 5);
      float n6 = __shfl(nv, k + 6), n7 = __shfl(nv, k + 7);
      float2 t0 = __half22float2(tp[(size_t)c0 * 64 + lane]);
      float2 t1 = __half22float2(tp[(size_t)c1 * 64 + lane]);
      float2 t2 = __half22float2(tp[(size_t)c2 * 64 + lane]);
      float2 t3 = __half22float2(tp[(size_t)c3 * 64 + lane]);
      float2 t4 = __half22float2(tp[(size_t)c4 * 64 + lane]);
      float2 t5 = __half22float2(tp[(size_t)c5 * 64 + lane]);
      float2 t6 = __half22float2(tp[(size_t)c6 * 64 + lane]);
      float2 t7 = __half22float2(tp[(size_t)c7 * 64 + lane]);
      ax += n0 * t0.x; ay += n0 * t0.y;  ax += n1 * t1.x; ay += n1 * t1.y;
      ax += n2 * t2.x; ay += n2 * t2.y;  ax += n3 * t3.x; ay += n3 * t3.y;
      ax += n4 * t4.x; ay += n4 * t4.y;  ax += n5 * t5.x; ay += n5 * t5.y;
      ax += n6 * t6.x; ay += n6 * t6.y;  ax += n7 * t7.x; ay += n7 * t7.y;
    }
    for (; k < m; k++) {
      int c = __shfl(cv, k);
      float nm = __shfl(nv, k);
      float2 tv = __half22float2(tp[(size_t)c * 64 + lane]);
      ax += nm * tv.x; ay += nm * tv.y;
    }
  }
  float2 bb = ((const float2*)bias)[lane];
  ax += bb.x; ay += bb.y;
  if (relu) { ax = fmaxf(ax, 0.f); ay = fmaxf(ay, 0.f); }
  ((__half2*)outh)[(size_t)node * 64 + lane] = __floats2half2_rn(ax, ay);
}

// ---------- BatchNorm apply (only for logvar head now) ----------

__global__ void bn_apply_kernel(float* __restrict__ x, float* __restrict__ dup,
                                const float* __restrict__ stats,
                                const float* __restrict__ g, const float* __restrict__ beta,
                                int total, int cmask, int C) {
  int i = blockIdx.x * blockDim.x + threadIdx.x;
  if (i >= total) return;
  int c = i & cmask;
  float m = stats[c] * (1.f / Nn);
  float var = stats[C + c] * (1.f / Nn) - m * m;
  float v = (x[i] - m) * rsqrtf(var + BN_EPS) * g[c] + beta[c];
  x[i] = v;
  if (dup) dup[i] = v;
}

// ---------- fused mu-BN + z copy + Student-t cluster assignment (two-pass) ----------

__global__ __launch_bounds__(256)
void q_bn_kernel(const float* __restrict__ mu_raw, const float* __restrict__ stats,
                 const float* __restrict__ g, const float* __restrict__ beta,
                 const float* __restrict__ centers,
                 float* __restrict__ out_mu, float* __restrict__ out_z,
                 float* __restrict__ q) {
  __shared__ float cs[50 * 32];
  __shared__ float cn[50];
  __shared__ float sc[32], sh[32];
  int tid = threadIdx.x;
  for (int i = tid; i < 50 * 32; i += 256) cs[i] = centers[i];
  if (tid < 32) {
    float m = stats[tid] * (1.f / Nn);
    float var = stats[32 + tid] * (1.f / Nn) - m * m;
    float s = rsqrtf(var + BN_EPS) * g[tid];
    sc[tid] = s; sh[tid] = beta[tid] - m * s;
  }
  __syncthreads();
  if (tid < 50) {
    float s = 0.f;
    for (int j = 0; j < 32; j++) { float v = cs[tid * 32 + j]; s += v * v; }
    cn[tid] = s;
  }
  __syncthreads();
  int n = blockIdx.x * blockDim.x + tid;
  if (n >= Nn) return;
  float zr[32];
  float zn = 0.f;
  const float4* zp = (const float4*)(mu_raw + (size_t)n * 32);
  float4* mo = (float4*)(out_mu + (size_t)n * 32);
  float4* zo = (float4*)(out_z + (size_t)n * 32);
#pragma unroll
  for (int j = 0; j < 8; j++) {
    float4 v = zp[j];
    int c = j * 4;
    v.x = v.x * sc[c + 0] + sh[c + 0];
    v.y = v.y * sc[c + 1] + sh[c + 1];
    v.z = v.z * sc[c + 2] + sh[c + 2];
    v.w = v.w * sc[c + 3] + sh[c + 3];
    mo[j] = v; zo[j] = v;
    zr[c + 0] = v.x; zr[c + 1] = v.y; zr[c + 2] = v.z; zr[c + 3] = v.w;
    zn += v.x * v.x + v.y * v.y + v.z * v.z + v.w * v.w;
  }
  float qs = 0.f;
  for (int k = 0; k < 50; k++) {
    float dot = 0.f;
#pragma unroll
    for (int j = 0; j < 32; j++) dot += zr[j] * cs[k * 32 + j];
    float d2 = fmaxf(zn + cn[k] - 2.f * dot, 0.f);
    qs += 1.f / (1.f + d2);
  }
  float inv = 1.f / qs;
  float* qo = q + (size_t)n * 50;
  for (int k = 0; k < 50; k++) {
    float dot = 0.f;
#pragma unroll
    for (int j = 0; j < 32; j++) dot += zr[j] * cs[k * 32 + j];
    float d2 = fmaxf(zn + cn[k] - 2.f * dot, 0.f);
    qo[k] = inv / (1.f + d2);
  }
}

// ---------- launch ----------

extern "C" void kernel_launch(void* const* d_in, const int* in_sizes, int n_in,
                              void* d_out, int out_size, void* d_ws, size_t ws_size,
                              hipStream_t stream) {
  const float* x     = (const float*)d_in[0];
  const int*   ei    = (const int*)d_in[1];
  const float* ew    = (const float*)d_in[2];
  const float* W_g1  = (const float*)d_in[3];
  const float* b_g1  = (const float*)d_in[4];
  const float* W_g2  = (const float*)d_in[5];
  const float* b_g2  = (const float*)d_in[6];
  const float* W_g3  = (const float*)d_in[7];
  const float* b_g3  = (const float*)d_in[8];
  const float* W_mu  = (const float*)d_in[9];
  const float* b_mu  = (const float*)d_in[10];
  const float* W_lv  = (const float*)d_in[11];
  const float* b_lv  = (const float*)d_in[12];
  const float* g_mu  = (const float*)d_in[13];
  const float* be_mu = (const float*)d_in[14];
  const float* g_lv  = (const float*)d_in[15];
  const float* be_lv = (const float*)d_in[16];
  const float* W_d1  = (const float*)d_in[17];
  const float* b_d1  = (const float*)d_in[18];
  const float* g_d1  = (const float*)d_in[19];
  const float* be_d1 = (const float*)d_in[20];
  const float* W_d2  = (const float*)d_in[21];
  const float* b_d2  = (const float*)d_in[22];
  const float* g_d2  = (const float*)d_in[23];
  const float* be_d2 = (const float*)d_in[24];
  const float* W_d3  = (const float*)d_in[25];
  const float* b_d3  = (const float*)d_in[26];
  const float* cent  = (const float*)d_in[27];

  const int* row = ei;
  const int* col = ei + Ne;

  float* out    = (float*)d_out;
  float* out_z  = out;
  float* out_mu = out + (size_t)Nn * 32;
  float* out_lv = out + (size_t)Nn * 64;
  float* out_xr = out + (size_t)Nn * 96;   // [N,256]
  float* out_q  = out + (size_t)Nn * 352;  // [N,50]

  float* ws     = (float*)d_ws;
  float* dinv   = ws;
  float* bufB   = dinv + Nn;                 // Nn*128 floats; reused as fp16 [N,128] x2
  float* stats  = bufB + (size_t)Nn * 128;
  int*   rowptr = (int*)(stats + 512);
  int*   off    = rowptr + Nn + 1;
  int*   bsum   = off + Nn;
  int2*  edge_s = (int2*)(bsum + 128 + 1);
  unsigned long long* pk = (unsigned long long*)bufB;  // aliased; dead before gather128 writes
  float* st_mu = stats, *st_lv = stats + 64, *st_d1 = stats + 128, *st_d2 = stats + 256;

  __half* bufB16 = (__half*)bufB;                       // gather128 out / d2 out [N,128] fp16
  __half* tA   = (__half*)out_xr;                       // L1 t [N,128] fp16; L3 t [N,64] fp16
  __half* tC   = (__half*)(out_xr + (size_t)Nn * 128);  // L2 t [N,64] fp16
  float*  bufC = out_xr + (size_t)Nn * 128;             // L3 gather out [N,64] fp32 (tC dead)
  __half* tD   = (__half*)(out_xr + (size_t)Nn * 192);  // gather64-L2 out / d1 out [N,64] fp16
  float* stats_part = out_xr + (size_t)Nn * 64;         // NCOPY*CSTRIDE floats

  auto cdiv = [](long a, long b) { return (int)((a + b - 1) / b); };
  dim3 blk(256);

  izero_kernel<<<cdiv(2L * Nn, 256), blk, 0, stream>>>((int*)pk, 2 * Nn);
  fill_kernel<<<1, blk, 0, stream>>>(stats, 0.f, 512);
  fill_kernel<<<cdiv(NCOPY * CSTRIDE, 256), blk, 0, stream>>>(stats_part, 0.f, NCOPY * CSTRIDE);
  deg_pack_kernel<<<cdiv(Ne / 4, 256), blk, 0, stream>>>(row, ew, pk);

  scan_phase1<<<SCAN_NB, blk, 0, stream>>>(pk, bsum);
  scan_phase2<<<1, 128, 0, stream>>>(bsum);
  scan_phase3<<<SCAN_NB, blk, 0, stream>>>(pk, bsum, rowptr, off, dinv);
  csr_fill_kernel<<<cdiv(Ne / 4, 256), blk, 0, stream>>>(row, col, ew, dinv, off, edge_s);

  int g128 = cdiv(Nn, 4);   // gather128: 4 nodes/block
  int g64  = cdiv(Nn, 8);   // gather64: 8 nodes/block
  int gy   = cdiv(Nn, 128); // MFMA rows

  // GCN layer 1: 256 -> 128 (MFMA), aggregate+relu -> fp16
  gemm_mfma_kernel<<<dim3(2, gy), blk, 0, stream>>>(
      x, nullptr, W_g1, nullptr, nullptr, tA, nullptr, nullptr, nullptr, nullptr, Nn, 256, 128, 0);
  gather128_kernel<<<g128, blk, 0, stream>>>(tA, rowptr, edge_s, dinv, b_g1, bufB16, 1);

  // GCN layer 2: 128 -> 64 (MFMA, fp16 A), aggregate+relu -> fp16
  gemm_mfma_kernel<<<dim3(1, gy), blk, 0, stream>>>(
      nullptr, bufB16, W_g2, nullptr, nullptr, tC, nullptr, nullptr, nullptr, nullptr, Nn, 128, 64, 0);
  gather64_kernel<<<g64, blk, 0, stream>>>(tC, rowptr, edge_s, dinv, b_g2, nullptr, tD, 1);

  // GCN layer 3: 64 -> 64 (MFMA, fp16 A), aggregate -> fp32 (feeds fp32 heads)
  gemm_mfma_kernel<<<dim3(1, gy), blk, 0, stream>>>(
      nullptr, tD, W_g3, nullptr, nullptr, tA, nullptr, nullptr, nullptr, nullptr, Nn, 64, 64, 0);
  gather64_kernel<<<g64, blk, 0, stream>>>(tA, rowptr, edge_s, dinv, b_g3, bufC, nullptr, 0);

  // VAE heads: 64 -> 32 (fp32 64x64 kernel), stats in epilogue
  gemm_kernel<<<dim3(1, cdiv(Nn, 64)), blk, 0, stream>>>(
      bufC, W_mu, b_mu, out_mu, nullptr, nullptr, nullptr, nullptr, stats_part, Nn, 64, 32, 0);
  gemm_kernel<<<dim3(1, cdiv(Nn, 64)), blk, 0, stream>>>(
      bufC, W_lv, b_lv, out_lv, nullptr, nullptr, nullptr, nullptr, stats_part + 64, Nn, 64, 32, 0);
  fold_stats_kernel<<<1, blk, 0, stream>>>(stats_part, stats, 128);
  bn_apply_kernel<<<cdiv((long)Nn * 32, 256), blk, 0, stream>>>(
      out_lv, nullptr, st_lv, g_lv, be_lv, Nn * 32, 31, 32);

  q_bn_kernel<<<cdiv(Nn, 256), blk, 0, stream>>>(out_mu, st_mu, g_mu, be_mu, cent,
                                                 out_mu, out_z, out_q);

  // decoder 32 -> 64 -> 128 -> 256 (MFMA) with BN folded into A-loads, fp16 mid buffers
  gemm_mfma_kernel<<<dim3(1, gy), blk, 0, stream>>>(
      out_z, nullptr, W_d1, b_d1, nullptr, tD, nullptr, nullptr, nullptr, stats_part + 128, Nn, 32, 64, 1);
  fold_stats_kernel<<<1, blk, 0, stream>>>(stats_part + 128, stats + 128, 128);
  gemm_mfma_kernel<<<dim3(2, gy), blk, 0, stream>>>(
      nullptr, tD, W_d2, b_d2, nullptr, bufB16, st_d1, g_d1, be_d1, stats_part + 256, Nn, 64, 128, 1);
  fold_stats_kernel<<<1, blk, 0, stream>>>(stats_part + 256, stats + 256, 256);
  gemm_mfma_kernel<<<dim3(4, gy), blk, 0, stream>>>(
      nullptr, bufB16, W_d3, b_d3, out_xr, nullptr, st_d2, g_d2, be_d2, nullptr, Nn, 128, 256, 0);
}

// Round 8
// 764.193 us; speedup vs baseline: 1.8034x; 1.0807x over previous
//
#include <hip/hip_runtime.h>
#include <hip/hip_fp16.h>

constexpr int Nn = 100000;
constexpr int Ne = 1600000;
constexpr float BN_EPS = 1e-5f;

constexpr int SCAN_TILE = 1024;                          // elements per block
constexpr int SCAN_NB = (Nn + SCAN_TILE - 1) / SCAN_TILE; // 98

constexpr float FIX_SCALE = 16777216.f;       // 2^24
constexpr float FIX_INV = 1.f / 16777216.f;

constexpr int NCOPY = 32;        // replicated stats slots (anti-contention)
constexpr int CSTRIDE = 512;     // floats per slot

typedef _Float16 f16x8 __attribute__((ext_vector_type(8)));
typedef float f32x4 __attribute__((ext_vector_type(4)));

// ---------- fused init: zero pk + stats_part, build Wcat/bcat for merged heads ----------

__global__ void init_kernel(int* __restrict__ pk2, float* __restrict__ part,
                            const float* __restrict__ W_mu, const float* __restrict__ W_lv,
                            const float* __restrict__ b_mu, const float* __restrict__ b_lv,
                            float* __restrict__ wcat, float* __restrict__ bcat) {
  int i = blockIdx.x * blockDim.x + threadIdx.x;
  if (i < 2 * Nn) pk2[i] = 0;
  if (i < NCOPY * CSTRIDE) part[i] = 0.f;
  if (i < 64 * 64) {
    int k = i >> 6, c = i & 63;
    wcat[i] = (c < 32) ? W_mu[k * 32 + c] : W_lv[k * 32 + (c - 32)];
  }
  if (i < 64) bcat[i] = (i < 32) ? b_mu[i] : b_lv[i - 32];
}

// fused: one u64 atomic per edge packs {cnt:1 << 40 | fix24(w)}; returned old count
// bits give this edge's slot within its node (atomic-free CSR fill later)
__global__ __launch_bounds__(256)
void deg_pack_kernel(const int* __restrict__ row, const float* __restrict__ w,
                     unsigned long long* __restrict__ pk,
                     unsigned short* __restrict__ slot) {
  int e = (blockIdx.x * blockDim.x + threadIdx.x) * 4;
  if (e + 4 <= Ne) {
    int4 r4 = *(const int4*)(row + e);
    float4 w4 = *(const float4*)(w + e);
    unsigned long long o0 = atomicAdd(&pk[r4.x], (1ULL << 40) | (unsigned long long)__float2uint_rn(w4.x * FIX_SCALE));
    unsigned long long o1 = atomicAdd(&pk[r4.y], (1ULL << 40) | (unsigned long long)__float2uint_rn(w4.y * FIX_SCALE));
    unsigned long long o2 = atomicAdd(&pk[r4.z], (1ULL << 40) | (unsigned long long)__float2uint_rn(w4.z * FIX_SCALE));
    unsigned long long o3 = atomicAdd(&pk[r4.w], (1ULL << 40) | (unsigned long long)__float2uint_rn(w4.w * FIX_SCALE));
    ushort4 s4;
    s4.x = (unsigned short)(o0 >> 40); s4.y = (unsigned short)(o1 >> 40);
    s4.z = (unsigned short)(o2 >> 40); s4.w = (unsigned short)(o3 >> 40);
    *(ushort4*)(slot + e) = s4;
  } else {
    for (int i = e; i < Ne; i++) {
      unsigned long long o = atomicAdd(&pk[row[i]], (1ULL << 40) | (unsigned long long)__float2uint_rn(w[i] * FIX_SCALE));
      slot[i] = (unsigned short)(o >> 40);
    }
  }
}

// ---------- multi-block exclusive scan over pk counts -> rowptr + dinv ----------

__global__ __launch_bounds__(256)
void scan_phase1(const unsigned long long* __restrict__ pk, int* __restrict__ bsum) {
  __shared__ int s[256];
  int b = blockIdx.x, tid = threadIdx.x;
  int base = b * SCAN_TILE + tid * 4;
  int t = 0;
#pragma unroll
  for (int i = 0; i < 4; i++) {
    int idx = base + i;
    if (idx < Nn) t += (int)(pk[idx] >> 40);
  }
  s[tid] = t;
  __syncthreads();
  for (int st = 128; st > 0; st >>= 1) {
    if (tid < st) s[tid] += s[tid + st];
    __syncthreads();
  }
  if (tid == 0) bsum[b] = s[0];
}

__global__ __launch_bounds__(128)
void scan_phase2(int* __restrict__ bsum) {  // in-place exclusive scan, SCAN_NB <= 128
  __shared__ int s[128];
  int tid = threadIdx.x;
  int v = (tid < SCAN_NB) ? bsum[tid] : 0;
  s[tid] = v;
  __syncthreads();
  for (int st = 1; st < 128; st <<= 1) {
    int u = (tid >= st) ? s[tid - st] : 0;
    __syncthreads();
    s[tid] += u;
    __syncthreads();
  }
  if (tid < SCAN_NB) bsum[tid] = s[tid] - v;  // exclusive prefix
}

__global__ __launch_bounds__(256)
void scan_phase3(const unsigned long long* __restrict__ pk, const int* __restrict__ bsum,
                 int* __restrict__ rowptr, float* __restrict__ dinv) {
  __shared__ int s[256];
  int b = blockIdx.x, tid = threadIdx.x;
  int base = b * SCAN_TILE + tid * 4;
  int vals[4];
  int t = 0;
#pragma unroll
  for (int i = 0; i < 4; i++) {
    int idx = base + i;
    if (idx < Nn) {
      unsigned long long v = pk[idx];
      vals[i] = (int)(v >> 40);
      float deg = (float)(v & ((1ULL << 40) - 1)) * FIX_INV + 1.0f;  // + self-loop
      dinv[idx] = rsqrtf(fmaxf(deg, 1e-12f));
    } else vals[i] = 0;
    t += vals[i];
  }
  s[tid] = t;
  __syncthreads();
  for (int st = 1; st < 256; st <<= 1) {
    int u = (tid >= st) ? s[tid - st] : 0;
    __syncthreads();
    s[tid] += u;
    __syncthreads();
  }
  int run = bsum[b] + s[tid] - t;  // exclusive prefix for this thread's 4 elems
#pragma unroll
  for (int i = 0; i < 4; i++) {
    int idx = base + i;
    if (idx < Nn) { rowptr[idx] = run; run += vals[i]; }
  }
  if (b == SCAN_NB - 1 && tid == 255) rowptr[Nn] = bsum[b] + s[255];
}

// CSR fill, atomic-free: pos = rowptr[r] + slot[e]; one 8B scattered store per edge
__global__ __launch_bounds__(256)
void csr_fill_kernel(const int* __restrict__ row, const int* __restrict__ col,
                     const float* __restrict__ w, const float* __restrict__ dinv,
                     const int* __restrict__ rowptr, const unsigned short* __restrict__ slot,
                     int2* __restrict__ edge_s) {
  int e = (blockIdx.x * blockDim.x + threadIdx.x) * 4;
  if (e + 4 <= Ne) {
    int4 r4 = *(const int4*)(row + e);
    int4 c4 = *(const int4*)(col + e);
    float4 w4 = *(const float4*)(w + e);
    ushort4 s4 = *(const ushort4*)(slot + e);
    edge_s[rowptr[r4.x] + s4.x] = make_int2(c4.x, __float_as_int(dinv[r4.x] * w4.x * dinv[c4.x]));
    edge_s[rowptr[r4.y] + s4.y] = make_int2(c4.y, __float_as_int(dinv[r4.y] * w4.y * dinv[c4.y]));
    edge_s[rowptr[r4.z] + s4.z] = make_int2(c4.z, __float_as_int(dinv[r4.z] * w4.z * dinv[c4.z]));
    edge_s[rowptr[r4.w] + s4.w] = make_int2(c4.w, __float_as_int(dinv[r4.w] * w4.w * dinv[c4.w]));
  } else {
    for (int i = e; i < Ne; i++) {
      int r = row[i], c = col[i];
      edge_s[rowptr[r] + slot[i]] = make_int2(c, __float_as_int(dinv[r] * w[i] * dinv[c]));
    }
  }
}

// ---------- FP32 tiled GEMM 64x64, merged mu/lv heads (split epilogue) ----------

__global__ __launch_bounds__(256)
void gemm_kernel(const float* __restrict__ A, const float* __restrict__ W,
                 const float* __restrict__ bias, float* __restrict__ C,
                 float* __restrict__ C2, float* __restrict__ out_part,
                 int M, int K, int Nc, int relu) {
  constexpr int BM = 64, BN = 64, BK = 16;
  __shared__ float As[BK][BM + 4];
  __shared__ float Ws[BK][BN];
  int t = threadIdx.x;
  int tx = t & 15, ty = t >> 4;
  int row0 = blockIdx.y * BM, col0 = blockIdx.x * BN;
  float acc[4][4] = {};
  for (int k0 = 0; k0 < K; k0 += BK) {
    {
      int r = t >> 2;
      int kq = (t & 3) << 2;
      int grow = row0 + r;
      float4 a = make_float4(0.f, 0.f, 0.f, 0.f);
      if (grow < M) a = *(const float4*)(A + (size_t)grow * K + (k0 + kq));
      As[kq + 0][r] = a.x; As[kq + 1][r] = a.y;
      As[kq + 2][r] = a.z; As[kq + 3][r] = a.w;
    }
    {
      int r = t >> 4;
      int c = (t & 15) << 2;
      int gc = col0 + c;
      float4 w4 = make_float4(0.f, 0.f, 0.f, 0.f);
      if (gc < Nc) w4 = *(const float4*)(W + (size_t)(k0 + r) * Nc + gc);
      Ws[r][c + 0] = w4.x; Ws[r][c + 1] = w4.y;
      Ws[r][c + 2] = w4.z; Ws[r][c + 3] = w4.w;
    }
    __syncthreads();
#pragma unroll
    for (int kk = 0; kk < BK; kk++) {
      float4 av = *(const float4*)&As[kk][ty << 2];
      float4 wv = *(const float4*)&Ws[kk][tx << 2];
      float a4[4] = {av.x, av.y, av.z, av.w};
      float w4[4] = {wv.x, wv.y, wv.z, wv.w};
#pragma unroll
      for (int i = 0; i < 4; i++)
#pragma unroll
        for (int j = 0; j < 4; j++)
          acc[i][j] += a4[i] * w4[j];
    }
    __syncthreads();
  }
  float cs[4] = {0.f, 0.f, 0.f, 0.f}, cq[4] = {0.f, 0.f, 0.f, 0.f};
#pragma unroll
  for (int i = 0; i < 4; i++) {
    int grow = row0 + (ty << 2) + i;
    if (grow >= M) continue;
#pragma unroll
    for (int j = 0; j < 4; j++) {
      int gc = col0 + (tx << 2) + j;
      if (gc >= Nc) continue;
      float vv = acc[i][j];
      if (bias) vv += bias[gc];
      if (relu) vv = fmaxf(vv, 0.f);
      if (out_part) { cs[j] += vv; cq[j] += vv * vv; }
      if (C2) {  // split: cols 0..31 -> C[r*32+gc], 32..63 -> C2[r*32+gc-32]
        if (gc < 32) C[(size_t)grow * 32 + gc] = vv;
        else         C2[(size_t)grow * 32 + gc - 32] = vv;
      } else {
        C[(size_t)grow * Nc + gc] = vv;
      }
    }
  }
  if (out_part) {
    int cbase = tx << 2;
#pragma unroll
    for (int j = 0; j < 4; j++) { As[ty][cbase + j] = cs[j]; Ws[ty][cbase + j] = cq[j]; }
    __syncthreads();
    for (int st = 8; st > 0; st >>= 1) {
      if (ty < st) {
#pragma unroll
        for (int j = 0; j < 4; j++) {
          As[ty][cbase + j] += As[ty + st][cbase + j];
          Ws[ty][cbase + j] += Ws[ty + st][cbase + j];
        }
      }
      __syncthreads();
    }
    if (ty == 0) {
      float* dst = out_part + (blockIdx.y & (NCOPY - 1)) * CSTRIDE;
#pragma unroll
      for (int j = 0; j < 4; j++) {
        int gc = col0 + cbase + j;
        if (gc < Nc) {
          atomicAdd(&dst[gc], As[0][cbase + j]);
          atomicAdd(&dst[Nc + gc], Ws[0][cbase + j]);
        }
      }
    }
  }
}

// ---------- MFMA f16 GEMM: BM=128 BN=64 BK=32, 4 waves, 2x4 frags of 16x16x32 ----------
// A from fp32 (A) or fp16 (A16). Optional input-BN folded from REPLICATED partials
// (in_part layout: [sum[K], sq[K]] per slot; lives in WORKSPACE, never aliased with
// any output this kernel writes). LDS rows padded to 40 elems.
// C/D layout (m89-verified): col = lane&15, row = (lane>>4)*4 + reg.

__global__ __launch_bounds__(256)
void gemm_mfma_kernel(const float* __restrict__ A, const __half* __restrict__ A16,
                      const float* __restrict__ W,
                      const float* __restrict__ bias, float* __restrict__ C,
                      __half* __restrict__ Ch,
                      const float* __restrict__ in_part, const float* __restrict__ in_g,
                      const float* __restrict__ in_beta, float* __restrict__ out_part,
                      int M, int K, int Nc, int relu) {
  constexpr int BM = 128, BN = 64, BK = 32;
  constexpr int LDA = 40;  // fp16 elems/row incl pad
  __shared__ __half Asm[BM][LDA];
  __shared__ __half Wsm[BN][LDA];     // Wsm[col][k] (transposed tile)
  __shared__ float bnsc[256], bnsh[256];
  __shared__ float sred[2][4][BN];
  int t = threadIdx.x;
  int wid = t >> 6, lane = t & 63;
  int fr = lane & 15, fg = lane >> 4;
  int row0 = blockIdx.y * BM, col0 = blockIdx.x * BN;
  if (in_part) {
    for (int c = t; c < K; c += 256) {
      float s = 0.f, q = 0.f;
#pragma unroll 8
      for (int k = 0; k < NCOPY; k++) {
        s += in_part[k * CSTRIDE + c];
        q += in_part[k * CSTRIDE + K + c];
      }
      float m = s * (1.f / Nn);
      float var = q * (1.f / Nn) - m * m;
      float sc = rsqrtf(var + BN_EPS) * in_g[c];
      bnsc[c] = sc;
      bnsh[c] = in_beta[c] - m * sc;
    }
    __syncthreads();
  }
  f32x4 acc[2][4] = {};
  int ar = t >> 1;             // A stage: row 0..127
  int ac = (t & 1) * 16;       //          k-chunk 0 or 16
  int wc = t >> 2;             // W stage: col 0..63
  int wk = (t & 3) * 8;        //          k-chunk 0/8/16/24
  for (int k0 = 0; k0 < K; k0 += BK) {
    {
      int grow = row0 + ar;
      float v[16];
      if (grow < M) {
        if (A16) {
          union { uint4 u[2]; __half h[16]; } raw;
          const uint4* ap = (const uint4*)(A16 + (size_t)grow * K + k0 + ac);
          raw.u[0] = ap[0]; raw.u[1] = ap[1];
#pragma unroll
          for (int j = 0; j < 16; j++) v[j] = __half2float(raw.h[j]);
        } else {
          const float4* ap = (const float4*)(A + (size_t)grow * K + k0 + ac);
#pragma unroll
          for (int q = 0; q < 4; q++) {
            float4 a = ap[q];
            v[q * 4 + 0] = a.x; v[q * 4 + 1] = a.y;
            v[q * 4 + 2] = a.z; v[q * 4 + 3] = a.w;
          }
        }
        if (in_part) {
#pragma unroll
          for (int j = 0; j < 16; j++)
            v[j] = v[j] * bnsc[k0 + ac + j] + bnsh[k0 + ac + j];
        }
      } else {
#pragma unroll
        for (int j = 0; j < 16; j++) v[j] = 0.f;
      }
      union { __half2 h2[8]; uint4 u4[2]; } pk_;
#pragma unroll
      for (int j = 0; j < 8; j++) pk_.h2[j] = __floats2half2_rn(v[2 * j], v[2 * j + 1]);
      *(uint4*)&Asm[ar][ac] = pk_.u4[0];
      *(uint4*)&Asm[ar][ac + 8] = pk_.u4[1];
    }
    {
      int gc = col0 + wc;
      union { __half2 h2[4]; uint4 u4; } wpk;
#pragma unroll
      for (int j = 0; j < 4; j++) {
        float w0 = W[(size_t)(k0 + wk + 2 * j) * Nc + gc];
        float w1 = W[(size_t)(k0 + wk + 2 * j + 1) * Nc + gc];
        wpk.h2[j] = __floats2half2_rn(w0, w1);
      }
      *(uint4*)&Wsm[wc][wk] = wpk.u4;
    }
    __syncthreads();
    {
      f16x8 a0 = *(const f16x8*)&Asm[wid * 32 + fr][fg * 8];
      f16x8 a1 = *(const f16x8*)&Asm[wid * 32 + 16 + fr][fg * 8];
      f16x8 b0 = *(const f16x8*)&Wsm[fr][fg * 8];
      f16x8 b1 = *(const f16x8*)&Wsm[16 + fr][fg * 8];
      f16x8 b2 = *(const f16x8*)&Wsm[32 + fr][fg * 8];
      f16x8 b3 = *(const f16x8*)&Wsm[48 + fr][fg * 8];
      acc[0][0] = __builtin_amdgcn_mfma_f32_16x16x32_f16(a0, b0, acc[0][0], 0, 0, 0);
      acc[0][1] = __builtin_amdgcn_mfma_f32_16x16x32_f16(a0, b1, acc[0][1], 0, 0, 0);
      acc[0][2] = __builtin_amdgcn_mfma_f32_16x16x32_f16(a0, b2, acc[0][2], 0, 0, 0);
      acc[0][3] = __builtin_amdgcn_mfma_f32_16x16x32_f16(a0, b3, acc[0][3], 0, 0, 0);
      acc[1][0] = __builtin_amdgcn_mfma_f32_16x16x32_f16(a1, b0, acc[1][0], 0, 0, 0);
      acc[1][1] = __builtin_amdgcn_mfma_f32_16x16x32_f16(a1, b1, acc[1][1], 0, 0, 0);
      acc[1][2] = __builtin_amdgcn_mfma_f32_16x16x32_f16(a1, b2, acc[1][2], 0, 0, 0);
      acc[1][3] = __builtin_amdgcn_mfma_f32_16x16x32_f16(a1, b3, acc[1][3], 0, 0, 0);
    }
    __syncthreads();
  }
  // epilogue
  float csum[4] = {}, cssq[4] = {};
  float bv[4];
#pragma unroll
  for (int ni = 0; ni < 4; ni++) bv[ni] = bias ? bias[col0 + ni * 16 + fr] : 0.f;
#pragma unroll
  for (int mi = 0; mi < 2; mi++) {
#pragma unroll
    for (int ni = 0; ni < 4; ni++) {
      int col = col0 + ni * 16 + fr;
      f32x4 d = acc[mi][ni];
#pragma unroll
      for (int j = 0; j < 4; j++) {
        int r = row0 + wid * 32 + mi * 16 + fg * 4 + j;
        if (r >= M) continue;
        float vv = d[j] + bv[ni];
        if (relu) vv = fmaxf(vv, 0.f);
        if (out_part) { csum[ni] += vv; cssq[ni] += vv * vv; }
        if (Ch) Ch[(size_t)r * Nc + col] = __float2half(vv);
        else    C[(size_t)r * Nc + col] = vv;
      }
    }
  }
  if (out_part) {
#pragma unroll
    for (int ni = 0; ni < 4; ni++) {
      csum[ni] += __shfl_xor(csum[ni], 16); csum[ni] += __shfl_xor(csum[ni], 32);
      cssq[ni] += __shfl_xor(cssq[ni], 16); cssq[ni] += __shfl_xor(cssq[ni], 32);
    }
    if (fg == 0) {
#pragma unroll
      for (int ni = 0; ni < 4; ni++) {
        sred[0][wid][ni * 16 + fr] = csum[ni];
        sred[1][wid][ni * 16 + fr] = cssq[ni];
      }
    }
    __syncthreads();
    if (t < BN) {
      float s = sred[0][0][t] + sred[0][1][t] + sred[0][2][t] + sred[0][3][t];
      float q = sred[1][0][t] + sred[1][1][t] + sred[1][2][t] + sred[1][3][t];
      float* dst = out_part + (blockIdx.y & (NCOPY - 1)) * CSTRIDE;
      atomicAdd(&dst[col0 + t], s);
      atomicAdd(&dst[Nc + col0 + t], q);
    }
  }
}

// ---------- gather SpMM (fp16 features, fp32 accumulate) ----------

// 64-dim: 32 lanes per node (half2/lane), 2 nodes per wave, 8 loads in flight
__global__ __launch_bounds__(256)
void gather64_kernel(const __half* __restrict__ t, const int* __restrict__ rowptr,
                     const int2* __restrict__ edge_s,
                     const float* __restrict__ dinv, const float* __restrict__ bias,
                     float* __restrict__ out, __half* __restrict__ outh, int relu) {
  int sub = threadIdx.x >> 5;       // 8 sub-groups of 32 lanes
  int lane = threadIdx.x & 31;
  int node = blockIdx.x * 8 + sub;
  if (node >= Nn) return;
  int start = rowptr[node], end = rowptr[node + 1];
  float s = dinv[node];
  const __half2* tp = (const __half2*)t;  // row stride = 32 half2
  float2 ti = __half22float2(tp[(size_t)node * 32 + lane]);
  float ax = s * s * ti.x, ay = s * s * ti.y;
  for (int base = start; base < end; base += 32) {
    int m = end - base; if (m > 32) m = 32;
    int cv = 0; float nv = 0.f;
    if (lane < m) {
      int2 ev = edge_s[base + lane];
      cv = ev.x; nv = __int_as_float(ev.y);
    }
    int k = 0;
    for (; k + 8 <= m; k += 8) {
      int c0 = __shfl(cv, k + 0, 32), c1 = __shfl(cv, k + 1, 32);
      int c2 = __shfl(cv, k + 2, 32), c3 = __shfl(cv, k + 3, 32);
      int c4 = __shfl(cv, k + 4, 32), c5 = __shfl(cv, k + 5, 32);
      int c6 = __shfl(cv, k + 6, 32), c7 = __shfl(cv, k + 7, 32);
      float n0 = __shfl(nv, k + 0, 32), n1 = __shfl(nv, k + 1, 32);
      float n2 = __shfl(nv, k + 2, 32), n3 = __shfl(nv, k + 3, 32);
      float n4 = __shfl(nv, k + 4, 32), n5 = __shfl(nv, k + 5, 32);
      float n6 = __shfl(nv, k + 6, 32), n7 = __shfl(nv, k + 7, 32);
      float2 t0 = __half22float2(tp[(size_t)c0 * 32 + lane]);
      float2 t1 = __half22float2(tp[(size_t)c1 * 32 + lane]);
      float2 t2 = __half22float2(tp[(size_t)c2 * 32 + lane]);
      float2 t3 = __half22float2(tp[(size_t)c3 * 32 + lane]);
      float2 t4 = __half22float2(tp[(size_t)c4 * 32 + lane]);
      float2 t5 = __half22float2(tp[(size_t)c5 * 32 + lane]);
      float2 t6 = __half22float2(tp[(size_t)c6 * 32 + lane]);
      float2 t7 = __half22float2(tp[(size_t)c7 * 32 + lane]);
      ax += n0 * t0.x; ay += n0 * t0.y;  ax += n1 * t1.x; ay += n1 * t1.y;
      ax += n2 * t2.x; ay += n2 * t2.y;  ax += n3 * t3.x; ay += n3 * t3.y;
      ax += n4 * t4.x; ay += n4 * t4.y;  ax += n5 * t5.x; ay += n5 * t5.y;
      ax += n6 * t6.x; ay += n6 * t6.y;  ax += n7 * t7.x; ay += n7 * t7.y;
    }
    for (; k < m; k++) {
      int c = __shfl(cv, k, 32);
      float nm = __shfl(nv, k, 32);
      float2 tv = __half22float2(tp[(size_t)c * 32 + lane]);
      ax += nm * tv.x; ay += nm * tv.y;
    }
  }
  float2 bb = ((const float2*)bias)[lane];
  ax += bb.x; ay += bb.y;
  if (relu) { ax = fmaxf(ax, 0.f); ay = fmaxf(ay, 0.f); }
  if (outh) ((__half2*)outh)[(size_t)node * 32 + lane] = __floats2half2_rn(ax, ay);
  else      ((float2*)out)[(size_t)node * 32 + lane] = make_float2(ax, ay);
}

// 128-dim: 64 lanes per node (half2/lane), 8 loads in flight, fp16 out
__global__ __launch_bounds__(256)
void gather128_kernel(const __half* __restrict__ t, const int* __restrict__ rowptr,
                      const int2* __restrict__ edge_s,
                      const float* __restrict__ dinv, const float* __restrict__ bias,
                      __half* __restrict__ outh, int relu) {
  int wave = threadIdx.x >> 6;
  int lane = threadIdx.x & 63;
  int node = blockIdx.x * 4 + wave;
  if (node >= Nn) return;
  int start = rowptr[node], end = rowptr[node + 1];
  float s = dinv[node];
  const __half2* tp = (const __half2*)t;  // row stride = 64 half2
  float2 ti = __half22float2(tp[(size_t)node * 64 + lane]);
  float ax = s * s * ti.x, ay = s * s * ti.y;
  for (int base = start; base < end; base += 64) {
    int m = end - base; if (m > 64) m = 64;
    int cv = 0; float nv = 0.f;
    if (lane < m) {
      int2 ev = edge_s[base + lane];
      cv = ev.x; nv = __int_as_float(ev.y);
    }
    int k = 0;
    for (; k + 8 <= m; k += 8) {
      int c0 = __shfl(cv, k + 0), c1 = __shfl(cv, k + 1);
      int c2 = __shfl(cv, k + 2), c3 = __shfl(cv, k + 3);
      int c4 = __shfl(cv, k + 4), c5 = __shfl(cv, k + 5);
      int c6 = __shfl(cv, k + 6), c7 = __shfl(cv, k + 7);
      float n0 = __shfl(nv, k + 0), n1 = __shfl(nv, k + 1);
      float n2 = __shfl(nv, k + 2), n3 = __shfl(nv, k + 3);
      float n4 = __shfl(nv, k + 4), n5 = __shfl(nv, k + 5);
      float n6 = __shfl(nv, k + 6), n7 = __shfl(nv, k + 7);
      float2 t0 = __half22float2(tp[(size_t)c0 * 64 + lane]);
      float2 t1 = __half22float2(tp[(size_t)c1 * 64 + lane]);
      float2 t2 = __half22float2(tp[(size_t)c2 * 64 + lane]);
      float2 t3 = __half22float2(tp[(size_t)c3 * 64 + lane]);
      float2 t4 = __half22float2(tp[(size_t)c4 * 64 + lane]);
      float2 t5 = __half22float2(tp[(size_t)c5 * 64 + lane]);
      float2 t6 = __half22float2(tp[(size_t)c6 * 64 + lane]);
      float2 t7 = __half22float2(tp[(size_t)c7 * 64 + lane]);
      ax += n0 * t0.x; ay += n0 * t0.y;  ax += n1 * t1.x; ay += n1 * t1.y;
      ax += n2 * t2.x; ay += n2 * t2.y;  ax += n3 * t3.x; ay += n3 * t3.y;
      ax += n4 * t4.x; ay += n4 * t4.y;  ax += n5 * t5.x; ay += n5 * t5.y;
      ax += n6 * t6.x; ay += n6 * t6.y;  ax += n7 * t7.x; ay += n7 * t7.y;
    }
    for (; k < m; k++) {
      int c = __shfl(cv, k);
      float nm = __shfl(nv, k);
      float2 tv = __half22float2(tp[(size_t)c * 64 + lane]);
      ax += nm * tv.x; ay += nm * tv.y;
    }
  }
  float2 bb = ((const float2*)bias)[lane];
  ax += bb.x; ay += bb.y;
  if (relu) { ax = fmaxf(ax, 0.f); ay = fmaxf(ay, 0.f); }
  ((__half2*)outh)[(size_t)node * 64 + lane] = __floats2half2_rn(ax, ay);
}

// ---------- fused: mu-BN + z + Student-t q + lv-BN (all stats from partials) ----------

__global__ __launch_bounds__(256)
void q_bn_kernel(const float* __restrict__ mu_raw, const float* __restrict__ part,
                 const float* __restrict__ g_mu, const float* __restrict__ be_mu,
                 const float* __restrict__ g_lv, const float* __restrict__ be_lv,
                 const float* __restrict__ centers,
                 float* __restrict__ out_mu, float* __restrict__ out_z,
                 float* __restrict__ out_lv, float* __restrict__ q) {
  __shared__ float cs[50 * 32];
  __shared__ float cn[50];
  __shared__ float sc[32], sh[32], sc2[32], sh2[32];
  int tid = threadIdx.x;
  for (int i = tid; i < 50 * 32; i += 256) cs[i] = centers[i];
  if (tid < 32) {
    // merged-head stats layout: sums[0..63], sq[64..127]; mu = cols 0..31, lv = 32..63
    float s = 0.f, qq = 0.f, s2 = 0.f, q2 = 0.f;
#pragma unroll 8
    for (int k = 0; k < NCOPY; k++) {
      const float* p = part + k * CSTRIDE;
      s  += p[tid];       qq += p[64 + tid];
      s2 += p[32 + tid];  q2 += p[96 + tid];
    }
    float m = s * (1.f / Nn);
    float var = qq * (1.f / Nn) - m * m;
    float f = rsqrtf(var + BN_EPS) * g_mu[tid];
    sc[tid] = f; sh[tid] = be_mu[tid] - m * f;
    float m2 = s2 * (1.f / Nn);
    float var2 = q2 * (1.f / Nn) - m2 * m2;
    float f2 = rsqrtf(var2 + BN_EPS) * g_lv[tid];
    sc2[tid] = f2; sh2[tid] = be_lv[tid] - m2 * f2;
  }
  __syncthreads();
  if (tid < 50) {
    float s = 0.f;
    for (int j = 0; j < 32; j++) { float v = cs[tid * 32 + j]; s += v * v; }
    cn[tid] = s;
  }
  __syncthreads();
  int n = blockIdx.x * blockDim.x + tid;
  if (n >= Nn) return;
  // lv BN in-place
  {
    float4* lp = (float4*)(out_lv + (size_t)n * 32);
#pragma unroll
    for (int j = 0; j < 8; j++) {
      float4 v = lp[j];
      int c = j * 4;
      v.x = v.x * sc2[c + 0] + sh2[c + 0];
      v.y = v.y * sc2[c + 1] + sh2[c + 1];
      v.z = v.z * sc2[c + 2] + sh2[c + 2];
      v.w = v.w * sc2[c + 3] + sh2[c + 3];
      lp[j] = v;
    }
  }
  float zr[32];
  float zn = 0.f;
  const float4* zp = (const float4*)(mu_raw + (size_t)n * 32);
  float4* mo = (float4*)(out_mu + (size_t)n * 32);
  float4* zo = (float4*)(out_z + (size_t)n * 32);
#pragma unroll
  for (int j = 0; j < 8; j++) {
    float4 v = zp[j];
    int c = j * 4;
    v.x = v.x * sc[c + 0] + sh[c + 0];
    v.y = v.y * sc[c + 1] + sh[c + 1];
    v.z = v.z * sc[c + 2] + sh[c + 2];
    v.w = v.w * sc[c + 3] + sh[c + 3];
    mo[j] = v; zo[j] = v;
    zr[c + 0] = v.x; zr[c + 1] = v.y; zr[c + 2] = v.z; zr[c + 3] = v.w;
    zn += v.x * v.x + v.y * v.y + v.z * v.z + v.w * v.w;
  }
  float qs = 0.f;
  for (int k = 0; k < 50; k++) {
    float dot = 0.f;
#pragma unroll
    for (int j = 0; j < 32; j++) dot += zr[j] * cs[k * 32 + j];
    float d2 = fmaxf(zn + cn[k] - 2.f * dot, 0.f);
    qs += 1.f / (1.f + d2);
  }
  float inv = 1.f / qs;
  float* qo = q + (size_t)n * 50;
  for (int k = 0; k < 50; k++) {
    float dot = 0.f;
#pragma unroll
    for (int j = 0; j < 32; j++) dot += zr[j] * cs[k * 32 + j];
    float d2 = fmaxf(zn + cn[k] - 2.f * dot, 0.f);
    qo[k] = inv / (1.f + d2);
  }
}

// ---------- launch ----------

extern "C" void kernel_launch(void* const* d_in, const int* in_sizes, int n_in,
                              void* d_out, int out_size, void* d_ws, size_t ws_size,
                              hipStream_t stream) {
  const float* x     = (const float*)d_in[0];
  const int*   ei    = (const int*)d_in[1];
  const float* ew    = (const float*)d_in[2];
  const float* W_g1  = (const float*)d_in[3];
  const float* b_g1  = (const float*)d_in[4];
  const float* W_g2  = (const float*)d_in[5];
  const float* b_g2  = (const float*)d_in[6];
  const float* W_g3  = (const float*)d_in[7];
  const float* b_g3  = (const float*)d_in[8];
  const float* W_mu  = (const float*)d_in[9];
  const float* b_mu  = (const float*)d_in[10];
  const float* W_lv  = (const float*)d_in[11];
  const float* b_lv  = (const float*)d_in[12];
  const float* g_mu  = (const float*)d_in[13];
  const float* be_mu = (const float*)d_in[14];
  const float* g_lv  = (const float*)d_in[15];
  const float* be_lv = (const float*)d_in[16];
  const float* W_d1  = (const float*)d_in[17];
  const float* b_d1  = (const float*)d_in[18];
  const float* g_d1  = (const float*)d_in[19];
  const float* be_d1 = (const float*)d_in[20];
  const float* W_d2  = (const float*)d_in[21];
  const float* b_d2  = (const float*)d_in[22];
  const float* g_d2  = (const float*)d_in[23];
  const float* be_d2 = (const float*)d_in[24];
  const float* W_d3  = (const float*)d_in[25];
  const float* b_d3  = (const float*)d_in[26];
  const float* cent  = (const float*)d_in[27];

  const int* row = ei;
  const int* col = ei + Ne;

  float* out    = (float*)d_out;
  float* out_z  = out;
  float* out_mu = out + (size_t)Nn * 32;
  float* out_lv = out + (size_t)Nn * 64;
  float* out_xr = out + (size_t)Nn * 96;   // [N,256]
  float* out_q  = out + (size_t)Nn * 352;  // [N,50]

  // workspace: dinv[N] | bufB[N*128] | wcat[4096] | bcat[64] | stats_part[16K] |
  //            rowptr[N+1] | bsum[129] | edge_s[E int2]   (~64.9 MB)
  float* ws     = (float*)d_ws;
  float* dinv   = ws;
  float* bufB   = dinv + Nn;
  float* wcat   = bufB + (size_t)Nn * 128;
  float* bcat   = wcat + 4096;
  float* stats_part = bcat + 64;                        // NCOPY*CSTRIDE floats, in WS
  int*   rowptr = (int*)(stats_part + NCOPY * CSTRIDE);
  int*   bsum   = rowptr + Nn + 1;
  int2*  edge_s = (int2*)(bsum + 128 + 1);
  unsigned long long* pk = (unsigned long long*)bufB;   // aliased; dead before gather128 writes

  __half* bufB16 = (__half*)bufB;                       // gather128 out / d2 out [N,128] fp16
  __half* tA   = (__half*)out_xr;                       // L1 t [N,128] fp16; L3 t [N,64] fp16
  __half* tC   = (__half*)(out_xr + (size_t)Nn * 128);  // L2 t [N,64] fp16
  float*  bufC = out_xr + (size_t)Nn * 128;             // L3 gather out [N,64] fp32 (tC dead)
  __half* tD   = (__half*)(out_xr + (size_t)Nn * 192);  // gather64-L2 out / d1 out [N,64] fp16
  unsigned short* slot = (unsigned short*)out_q;        // [Ne] u16; dead before q write

  auto cdiv = [](long a, long b) { return (int)((a + b - 1) / b); };
  dim3 blk(256);

  init_kernel<<<cdiv(2L * Nn, 256), blk, 0, stream>>>(
      (int*)pk, stats_part, W_mu, W_lv, b_mu, b_lv, wcat, bcat);
  deg_pack_kernel<<<cdiv(Ne / 4, 256), blk, 0, stream>>>(row, ew, pk, slot);

  scan_phase1<<<SCAN_NB, blk, 0, stream>>>(pk, bsum);
  scan_phase2<<<1, 128, 0, stream>>>(bsum);
  scan_phase3<<<SCAN_NB, blk, 0, stream>>>(pk, bsum, rowptr, dinv);
  csr_fill_kernel<<<cdiv(Ne / 4, 256), blk, 0, stream>>>(row, col, ew, dinv, rowptr, slot, edge_s);

  int g128 = cdiv(Nn, 4);   // gather128: 4 nodes/block
  int g64  = cdiv(Nn, 8);   // gather64: 8 nodes/block
  int gy   = cdiv(Nn, 128); // MFMA rows

  // GCN layer 1: 256 -> 128 (MFMA), aggregate+relu -> fp16
  gemm_mfma_kernel<<<dim3(2, gy), blk, 0, stream>>>(
      x, nullptr, W_g1, nullptr, nullptr, tA, nullptr, nullptr, nullptr, nullptr, Nn, 256, 128, 0);
  gather128_kernel<<<g128, blk, 0, stream>>>(tA, rowptr, edge_s, dinv, b_g1, bufB16, 1);

  // GCN layer 2: 128 -> 64 (MFMA, fp16 A), aggregate+relu -> fp16
  gemm_mfma_kernel<<<dim3(1, gy), blk, 0, stream>>>(
      nullptr, bufB16, W_g2, nullptr, nullptr, tC, nullptr, nullptr, nullptr, nullptr, Nn, 128, 64, 0);
  gather64_kernel<<<g64, blk, 0, stream>>>(tC, rowptr, edge_s, dinv, b_g2, nullptr, tD, 1);

  // GCN layer 3: 64 -> 64 (MFMA, fp16 A), aggregate -> fp32 (feeds fp32 heads)
  gemm_mfma_kernel<<<dim3(1, gy), blk, 0, stream>>>(
      nullptr, tD, W_g3, nullptr, nullptr, tA, nullptr, nullptr, nullptr, nullptr, Nn, 64, 64, 0);
  gather64_kernel<<<g64, blk, 0, stream>>>(tA, rowptr, edge_s, dinv, b_g3, bufC, nullptr, 0);

  // merged VAE heads: 64 -> 64 (cols 0..31 = mu, 32..63 = lv), stats in epilogue
  gemm_kernel<<<dim3(1, cdiv(Nn, 64)), blk, 0, stream>>>(
      bufC, wcat, bcat, out_mu, out_lv, stats_part, Nn, 64, 64, 0);

  // fused mu-BN + z + q + lv-BN (stats folded from partials inline)
  q_bn_kernel<<<cdiv(Nn, 256), blk, 0, stream>>>(out_mu, stats_part, g_mu, be_mu, g_lv, be_lv,
                                                 cent, out_mu, out_z, out_lv, out_q);

  // decoder 32 -> 64 -> 128 -> 256 (MFMA) with BN folded from partials into A-loads
  gemm_mfma_kernel<<<dim3(1, gy), blk, 0, stream>>>(
      out_z, nullptr, W_d1, b_d1, nullptr, tD, nullptr, nullptr, nullptr, stats_part + 128, Nn, 32, 64, 1);
  gemm_mfma_kernel<<<dim3(2, gy), blk, 0, stream>>>(
      nullptr, tD, W_d2, b_d2, nullptr, bufB16, stats_part + 128, g_d1, be_d1, stats_part + 256, Nn, 64, 128, 1);
  gemm_mfma_kernel<<<dim3(4, gy), blk, 0, stream>>>(
      nullptr, bufB16, W_d3, b_d3, out_xr, nullptr, stats_part + 256, g_d2, be_d2, nullptr, Nn, 128, 256, 0);
}